// Round 1
// baseline (3614.301 us; speedup 1.0000x reference)
//
#include <hip/hip_runtime.h>
#include <cstdint>
#include <cstddef>

#define NN   6720      // nodes
#define NE   33600     // edges
#define KDIM 2048      // DIN == HC1
#define HC1  2048
#define EDN  64

// ------------------------------------------------------------------
// Generic tiled fp32 GEMM: C[M,N] = A[M,K] @ B[K,N] (+bias) (+=C)
// Requires M%64==0, N%64==0, K%16==0 (all shapes here satisfy this).
// flags bit0: add bias[col]; bit1: accumulate into existing C.
// ------------------------------------------------------------------
__global__ __launch_bounds__(256) void gemm_tile(
    const float* __restrict__ A, const float* __restrict__ B,
    const float* __restrict__ bias, float* __restrict__ C,
    int M, int N, int K, int flags)
{
    __shared__ float As[16][68];   // [k][row], padded
    __shared__ float Bs[16][64];   // [k][col]
    const int tid = threadIdx.x;
    const int bx = blockIdx.x, by = blockIdx.y;
    const int tx = tid & 15, ty = tid >> 4;
    const int arow = tid >> 2, acol = (tid & 3) << 2;
    const int brow = tid >> 4, bcol = (tid & 15) << 2;
    const float* Ag = A + (size_t)(by * 64 + arow) * K + acol;
    const float* Bg = B + (size_t)brow * N + bx * 64 + bcol;
    float acc[4][4] = {};
    for (int k0 = 0; k0 < K; k0 += 16) {
        const float4 av = *(const float4*)(Ag + k0);
        const float4 bv = *(const float4*)(Bg + (size_t)k0 * N);
        __syncthreads();
        As[acol + 0][arow] = av.x;
        As[acol + 1][arow] = av.y;
        As[acol + 2][arow] = av.z;
        As[acol + 3][arow] = av.w;
        *(float4*)&Bs[brow][bcol] = bv;
        __syncthreads();
        #pragma unroll
        for (int kk = 0; kk < 16; ++kk) {
            const float4 a4 = *(const float4*)&As[kk][ty << 2];
            const float4 b4 = *(const float4*)&Bs[kk][tx << 2];
            const float a[4] = {a4.x, a4.y, a4.z, a4.w};
            const float b[4] = {b4.x, b4.y, b4.z, b4.w};
            #pragma unroll
            for (int i = 0; i < 4; ++i)
                #pragma unroll
                for (int j = 0; j < 4; ++j)
                    acc[i][j] += a[i] * b[j];
        }
    }
    const int crow = by * 64 + (ty << 2);
    const int ccol = bx * 64 + (tx << 2);
    float4 b4 = make_float4(0.f, 0.f, 0.f, 0.f);
    if (flags & 1) b4 = *(const float4*)(bias + ccol);
    #pragma unroll
    for (int i = 0; i < 4; ++i) {
        float* cp = C + (size_t)(crow + i) * N + ccol;
        float4 v;
        v.x = acc[i][0] + b4.x; v.y = acc[i][1] + b4.y;
        v.z = acc[i][2] + b4.z; v.w = acc[i][3] + b4.w;
        if (flags & 2) {
            const float4 o = *(const float4*)cp;
            v.x += o.x; v.y += o.y; v.z += o.z; v.w += o.w;
        }
        *(float4*)cp = v;
    }
}

// ------------------------------------------------------------------
// CSR build (incoming edges per dst node)
// ------------------------------------------------------------------
__global__ void count_deg(const int* __restrict__ ei, int* __restrict__ deg)
{
    int e = blockIdx.x * 256 + threadIdx.x;
    if (e < NE) atomicAdd(&deg[ei[NE + e]], 1);
}

__global__ __launch_bounds__(1024) void scan_kernel(const int* __restrict__ deg,
                                                    int* __restrict__ rowptr)
{
    __shared__ int s[1024];
    const int t = threadIdx.x;
    const int base = t * 7;
    int loc[7];
    int sum = 0;
    #pragma unroll
    for (int i = 0; i < 7; ++i) {
        int idx = base + i;
        int v = (idx < NN) ? deg[idx] : 0;
        loc[i] = v; sum += v;
    }
    s[t] = sum;
    __syncthreads();
    for (int off = 1; off < 1024; off <<= 1) {
        int v = (t >= off) ? s[t - off] : 0;
        __syncthreads();
        s[t] += v;
        __syncthreads();
    }
    int running = s[t] - sum;   // exclusive prefix
    #pragma unroll
    for (int i = 0; i < 7; ++i) {
        int idx = base + i;
        if (idx <= NN) rowptr[idx] = running;
        if (idx < NN) running += loc[i];
    }
}

__global__ void fill_csr(const int* __restrict__ ei, const int* __restrict__ rowptr,
                         int* __restrict__ fillctr, int* __restrict__ elist)
{
    int e = blockIdx.x * 256 + threadIdx.x;
    if (e >= NE) return;
    int d = ei[NE + e];
    int pos = atomicAdd(&fillctr[d], 1);
    elist[rowptr[d] + pos] = e;
}

__global__ void sort_csr(const int* __restrict__ rowptr, int* __restrict__ elist)
{
    int n = blockIdx.x * 256 + threadIdx.x;
    if (n >= NN) return;
    int s0 = rowptr[n], s1 = rowptr[n + 1];
    for (int i = s0 + 1; i < s1; ++i) {
        int v = elist[i];
        int j = i - 1;
        while (j >= s0 && elist[j] > v) { elist[j + 1] = elist[j]; --j; }
        elist[j + 1] = v;
    }
}

// ------------------------------------------------------------------
// e1_w rearrangements (block-diagonal by head)
// W1p [2048 x 128]:  W1p[d][h*64+j] = (d in head h) ? e1_w[j][d] : 0
// W1pp[128 x 2048]:  W1pp[h*64+j][d] = (d in head h) ? e1_w[j][d] : 0
// ------------------------------------------------------------------
__global__ void build_w1p(const float* __restrict__ e1w, float* __restrict__ W1p)
{
    int idx = blockIdx.x * 256 + threadIdx.x;
    if (idx >= KDIM * 128) return;
    int d = idx >> 7, p = idx & 127;
    int h = p >> 6, j = p & 63;
    W1p[idx] = ((d >> 10) == h) ? e1w[(size_t)j * KDIM + d] : 0.f;
}

__global__ void build_w1pp(const float* __restrict__ e1w, float* __restrict__ W1pp)
{
    int idx = blockIdx.x * 256 + threadIdx.x;
    if (idx >= 128 * KDIM) return;
    int p = idx >> 11, d = idx & 2047;
    W1pp[idx] = ((d >> 10) == (p >> 6)) ? e1w[(size_t)(p & 63) * KDIM + d] : 0.f;
}

// Concatenate layer-2 projection weights: W2cat [2048 x 256], b2cat[256]
__global__ void build_w2cat(const float* __restrict__ qw, const float* __restrict__ kw,
                            const float* __restrict__ vw, const float* __restrict__ sw,
                            const float* __restrict__ qb, const float* __restrict__ kb,
                            const float* __restrict__ vb, const float* __restrict__ sb,
                            float* __restrict__ W, float* __restrict__ bcat)
{
    int idx = blockIdx.x * 256 + threadIdx.x;
    if (idx >= KDIM * 256) return;
    int d = idx >> 8, c = idx & 255;
    int g = c >> 6, j = c & 63;
    const float* w = (g == 0) ? qw : (g == 1) ? kw : (g == 2) ? vw : sw;
    W[idx] = w[(size_t)d * 64 + j];
    if (d == 0) {
        const float* b = (g == 0) ? qb : (g == 1) ? kb : (g == 2) ? vb : sb;
        bcat[c] = b[j];
    }
}

// ------------------------------------------------------------------
// Edge attention, layer 1.  One 64-lane wave per edge.
// alpha[e][h] = ( q1[dst]·k1[src] |_head h  +  ea[e]·P1[dst]|_head h ) / 32
// ------------------------------------------------------------------
__global__ __launch_bounds__(256) void alpha1_kernel(
    const float* __restrict__ q1, const float* __restrict__ k1,
    const float* __restrict__ P1, const float* __restrict__ ea,
    const int* __restrict__ ei, float* __restrict__ alpha)
{
    int e = blockIdx.x * 4 + (threadIdx.x >> 6);
    int lane = threadIdx.x & 63;
    if (e >= NE) return;
    int src = ei[e], dst = ei[NE + e];
    const float* qr = q1 + (size_t)dst * HC1;
    const float* kr = k1 + (size_t)src * HC1;
    float eaj = ea[(size_t)e * 64 + lane];
    #pragma unroll
    for (int h = 0; h < 2; ++h) {
        const float* qh = qr + h * 1024;
        const float* kh = kr + h * 1024;
        float s = 0.f;
        #pragma unroll 4
        for (int c = lane; c < 1024; c += 64) s += qh[c] * kh[c];
        s += eaj * P1[(size_t)dst * 128 + h * 64 + lane];
        #pragma unroll
        for (int off = 32; off; off >>= 1) s += __shfl_xor(s, off);
        if (lane == 0) alpha[(size_t)e * 2 + h] = s * 0.03125f;  // 1/sqrt(1024)
    }
}

// scatter-softmax over incoming edges (thread per node); attn written in place
__global__ void softmax_kernel(const int* __restrict__ rowptr, const int* __restrict__ elist,
                               float* __restrict__ alpha, int H)
{
    int n = blockIdx.x * 256 + threadIdx.x;
    if (n >= NN) return;
    int s0 = rowptr[n], s1 = rowptr[n + 1];
    for (int h = 0; h < H; ++h) {
        float m = -1e30f;
        for (int i = s0; i < s1; ++i)
            m = fmaxf(m, alpha[(size_t)elist[i] * H + h]);
        float ssum = 0.f;
        for (int i = s0; i < s1; ++i) {
            float ex = __expf(alpha[(size_t)elist[i] * H + h] - m);
            alpha[(size_t)elist[i] * H + h] = ex;
            ssum += ex;
        }
        float inv = 1.f / (ssum + 1e-16f);
        for (int i = s0; i < s1; ++i)
            alpha[(size_t)elist[i] * H + h] *= inv;
    }
}

// R1[n][h*64+j] = sum_{e in in(n)} attn[e][h] * ea[e][j]
__global__ __launch_bounds__(128) void r1_kernel(
    const int* __restrict__ rowptr, const int* __restrict__ elist,
    const float* __restrict__ attn, const float* __restrict__ ea,
    float* __restrict__ R1)
{
    int n = blockIdx.x;
    int p = threadIdx.x;          // 0..127
    int h = p >> 6, j = p & 63;
    int s0 = rowptr[n], s1 = rowptr[n + 1];
    float r = 0.f;
    for (int i = s0; i < s1; ++i) {
        int e = elist[i];
        r += attn[(size_t)e * 2 + h] * ea[(size_t)e * 64 + j];
    }
    R1[(size_t)n * 128 + p] = r;
}

// h1[n][c] += sum_{e in in(n)} attn[e][h(c)] * v1[src_e][c]
__global__ __launch_bounds__(256) void agg1_kernel(
    const int* __restrict__ rowptr, const int* __restrict__ elist,
    const int* __restrict__ ei, const float* __restrict__ attn,
    const float* __restrict__ v1, float* __restrict__ h1)
{
    int n = blockIdx.x;
    int s0 = rowptr[n], s1 = rowptr[n + 1];
    int tid = threadIdx.x;
    #pragma unroll
    for (int it = 0; it < 8; ++it) {
        int c = it * 256 + tid;
        int h = c >> 10;
        float acc = h1[(size_t)n * HC1 + c];
        for (int i = s0; i < s1; ++i) {
            int e = elist[i];
            acc += attn[(size_t)e * 2 + h] * v1[(size_t)ei[e] * HC1 + c];
        }
        h1[(size_t)n * HC1 + c] = acc;
    }
}

__global__ void relu_kernel(float* __restrict__ x, int n)
{
    int i = blockIdx.x * 256 + threadIdx.x;
    if (i < n) x[i] = fmaxf(x[i], 0.f);
}

// ------------------------------------------------------------------
// Layer 2 edge kernels. qkvs2 row layout: [q(64) | k(64) | v(64) | skip(64)]
// ------------------------------------------------------------------
__global__ __launch_bounds__(256) void alpha2_kernel(
    const float* __restrict__ qkvs2, const float* __restrict__ E2,
    const int* __restrict__ ei, float* __restrict__ alpha2)
{
    int e = blockIdx.x * 4 + (threadIdx.x >> 6);
    int lane = threadIdx.x & 63;
    if (e >= NE) return;
    int src = ei[e], dst = ei[NE + e];
    float q = qkvs2[(size_t)dst * 256 + lane];
    float k = qkvs2[(size_t)src * 256 + 64 + lane];
    float s = q * (k + E2[(size_t)e * 64 + lane]);
    #pragma unroll
    for (int off = 32; off; off >>= 1) s += __shfl_xor(s, off);
    if (lane == 0) alpha2[e] = s * 0.125f;   // 1/sqrt(64)
}

__global__ __launch_bounds__(64) void agg2_kernel(
    const int* __restrict__ rowptr, const int* __restrict__ elist,
    const int* __restrict__ ei, const float* __restrict__ attn2,
    const float* __restrict__ qkvs2, const float* __restrict__ E2,
    float* __restrict__ out)
{
    int n = blockIdx.x;
    int c = threadIdx.x;
    int s0 = rowptr[n], s1 = rowptr[n + 1];
    float acc = qkvs2[(size_t)n * 256 + 192 + c];   // skip connection
    for (int i = s0; i < s1; ++i) {
        int e = elist[i];
        acc += attn2[e] * (qkvs2[(size_t)ei[e] * 256 + 128 + c] + E2[(size_t)e * 64 + c]);
    }
    out[(size_t)n * 64 + c] = fmaxf(acc, 0.f);
}

// ------------------------------------------------------------------
extern "C" void kernel_launch(void* const* d_in, const int* in_sizes, int n_in,
                              void* d_out, int out_size, void* d_ws, size_t ws_size,
                              hipStream_t stream)
{
    const float* x   = (const float*)d_in[0];
    const int*   ei  = (const int*)d_in[1];
    const float* ea  = (const float*)d_in[2];
    const float* q1w = (const float*)d_in[3];
    const float* q1b = (const float*)d_in[4];
    const float* k1w = (const float*)d_in[5];
    const float* k1b = (const float*)d_in[6];
    const float* v1w = (const float*)d_in[7];
    const float* v1b = (const float*)d_in[8];
    const float* e1w = (const float*)d_in[9];
    const float* s1w = (const float*)d_in[10];
    const float* s1b = (const float*)d_in[11];
    const float* q2w = (const float*)d_in[12];
    const float* q2b = (const float*)d_in[13];
    const float* k2w = (const float*)d_in[14];
    const float* k2b = (const float*)d_in[15];
    const float* v2w = (const float*)d_in[16];
    const float* v2b = (const float*)d_in[17];
    const float* e2w = (const float*)d_in[18];
    const float* s2w = (const float*)d_in[19];
    const float* s2b = (const float*)d_in[20];
    float* out = (float*)d_out;

    float* ws = (float*)d_ws;
    size_t off = 0;
    auto alloc = [&](size_t nf) { size_t o = off; off += (nf + 63) & ~(size_t)63; return o; };
    const size_t o_q1    = alloc((size_t)NN * HC1);
    const size_t o_k1    = alloc((size_t)NN * HC1);
    const size_t o_v1    = alloc((size_t)NN * HC1);
    const size_t o_h1    = alloc((size_t)NN * HC1);
    const size_t o_P1    = alloc((size_t)NN * 128);
    const size_t o_R1    = alloc((size_t)NN * 128);
    const size_t o_W1p   = alloc((size_t)KDIM * 128);
    const size_t o_W1pp  = alloc((size_t)128 * KDIM);
    const size_t o_at1   = alloc((size_t)NE * 2);
    const size_t o_qkvs2 = alloc((size_t)NN * 256);
    const size_t o_W2    = alloc((size_t)KDIM * 256);
    const size_t o_b2    = alloc(256);
    const size_t o_E2    = alloc((size_t)NE * 64);
    const size_t o_at2   = alloc((size_t)NE);

    int* ibase  = (int*)(ws + off);
    int* deg    = ibase;                 // NN
    int* fill   = ibase + NN;            // NN
    int* rowptr = ibase + 2 * NN;        // NN+1
    int* elist  = ibase + 2 * NN + NN + 1; // NE

    // --- CSR build ---
    hipMemsetAsync(deg, 0, sizeof(int) * NN * 2, stream);
    count_deg<<<(NE + 255) / 256, 256, 0, stream>>>(ei, deg);
    scan_kernel<<<1, 1024, 0, stream>>>(deg, rowptr);
    fill_csr<<<(NE + 255) / 256, 256, 0, stream>>>(ei, rowptr, fill, elist);
    sort_csr<<<(NN + 255) / 256, 256, 0, stream>>>(rowptr, elist);

    // --- Layer 1 projections ---
    gemm_tile<<<dim3(HC1 / 64, NN / 64), 256, 0, stream>>>(x, q1w, q1b, ws + o_q1, NN, HC1, KDIM, 1);
    gemm_tile<<<dim3(HC1 / 64, NN / 64), 256, 0, stream>>>(x, k1w, k1b, ws + o_k1, NN, HC1, KDIM, 1);
    gemm_tile<<<dim3(HC1 / 64, NN / 64), 256, 0, stream>>>(x, v1w, v1b, ws + o_v1, NN, HC1, KDIM, 1);
    gemm_tile<<<dim3(HC1 / 64, NN / 64), 256, 0, stream>>>(x, s1w, s1b, ws + o_h1, NN, HC1, KDIM, 1);

    // --- P1 = q1 @ W1p ---
    build_w1p<<<(KDIM * 128) / 256, 256, 0, stream>>>(e1w, ws + o_W1p);
    gemm_tile<<<dim3(128 / 64, NN / 64), 256, 0, stream>>>(ws + o_q1, ws + o_W1p, nullptr, ws + o_P1, NN, 128, KDIM, 0);

    // --- attention layer 1 ---
    alpha1_kernel<<<NE / 4, 256, 0, stream>>>(ws + o_q1, ws + o_k1, ws + o_P1, ea, ei, ws + o_at1);
    softmax_kernel<<<(NN + 255) / 256, 256, 0, stream>>>(rowptr, elist, ws + o_at1, 2);
    r1_kernel<<<NN, 128, 0, stream>>>(rowptr, elist, ws + o_at1, ea, ws + o_R1);
    agg1_kernel<<<NN, 256, 0, stream>>>(rowptr, elist, ei, ws + o_at1, ws + o_v1, ws + o_h1);
    build_w1pp<<<(128 * KDIM) / 256, 256, 0, stream>>>(e1w, ws + o_W1pp);
    gemm_tile<<<dim3(HC1 / 64, NN / 64), 256, 0, stream>>>(ws + o_R1, ws + o_W1pp, nullptr, ws + o_h1, NN, HC1, 128, 2);
    relu_kernel<<<(NN * HC1 + 255) / 256, 256, 0, stream>>>(ws + o_h1, NN * HC1);

    // --- Layer 2 projections (concatenated) ---
    build_w2cat<<<(KDIM * 256) / 256, 256, 0, stream>>>(q2w, k2w, v2w, s2w, q2b, k2b, v2b, s2b,
                                                        ws + o_W2, ws + o_b2);
    gemm_tile<<<dim3(256 / 64, NN / 64), 256, 0, stream>>>(ws + o_h1, ws + o_W2, ws + o_b2, ws + o_qkvs2, NN, 256, KDIM, 1);
    gemm_tile<<<dim3(64 / 64, NE / 64), 256, 0, stream>>>(ea, e2w, nullptr, ws + o_E2, NE, 64, 64, 0);

    // --- attention layer 2 ---
    alpha2_kernel<<<NE / 4, 256, 0, stream>>>(ws + o_qkvs2, ws + o_E2, ei, ws + o_at2);
    softmax_kernel<<<(NN + 255) / 256, 256, 0, stream>>>(rowptr, elist, ws + o_at2, 1);
    agg2_kernel<<<NN, 64, 0, stream>>>(rowptr, elist, ei, ws + o_at2, ws + o_qkvs2, ws + o_E2, out);

    (void)in_sizes; (void)n_in; (void)out_size; (void)ws_size;
}

// Round 2
// 715.639 us; speedup vs baseline: 5.0505x; 5.0505x over previous
//
#include <hip/hip_runtime.h>
#include <hip/hip_bf16.h>
#include <cstdint>
#include <cstddef>

#define NN    6720     // nodes
#define MPAD  6784     // 53 * 128
#define NE    33600    // edges
#define KDIM  2048
#define HC1   2048

typedef __attribute__((ext_vector_type(8))) short bhalf8;
typedef __attribute__((ext_vector_type(4))) float fx4;

__device__ __forceinline__ float bf2f(short s) {
    union { unsigned int u; float f; } c;
    c.u = ((unsigned int)(unsigned short)s) << 16;
    return c.f;
}

__device__ __forceinline__ void gload16(const __hip_bfloat16* g, void* lds)
{
    __builtin_amdgcn_global_load_lds(
        (const __attribute__((address_space(1))) unsigned int*)g,
        (__attribute__((address_space(3))) unsigned int*)lds,
        16, 0, 0);
}

// ------------------------------------------------------------------
// bf16 MFMA GEMM: C[M,N] = A[M,K] @ Bt[N,K]^T (+bias)(+=C)
// M%128==0, N%128==0, K%64==0. 128x128 tile, BK=64, 4 waves (2x2),
// 16x16x32 MFMA, global_load_lds staging, XOR-swizzled LDS.
// flags bit0: +bias[col]; bit1: accumulate into C.
// C (fp32) and/or Cb (bf16) written if non-null.
// ------------------------------------------------------------------
__global__ __launch_bounds__(256) void gemm_bf16(
    const __hip_bfloat16* __restrict__ A,
    const __hip_bfloat16* __restrict__ Bt,
    const float* __restrict__ bias,
    float* __restrict__ C,
    __hip_bfloat16* __restrict__ Cb,
    int M, int N, int K, int flags)
{
    __shared__ alignas(16) __hip_bfloat16 Asm[128 * 64];
    __shared__ alignas(16) __hip_bfloat16 Bsm[128 * 64];
    const int tid  = threadIdx.x;
    const int w    = tid >> 6;
    const int lane = tid & 63;
    const int wr = w >> 1, wc = w & 1;
    const int rowA = blockIdx.y * 128;
    const int rowB = blockIdx.x * 128;

    // staging: wave w stages rows [w*32, w*32+32) in 4 issues of 8 rows.
    // LDS linear [row][64] bf16 (128B rows); global source pre-swizzled:
    // LDS(row, unit u) gets global unit u ^ (row&7); row&7 == lane>>3.
    const int srow = w * 32 + (lane >> 3);
    const int ug8  = ((lane & 7) ^ (lane >> 3)) << 3;   // element offset
    const __hip_bfloat16* Ag = A  + (size_t)(rowA + srow) * K + ug8;
    const __hip_bfloat16* Bg = Bt + (size_t)(rowB + srow) * K + ug8;
    char* AsBase = (char*)Asm + w * 4096;
    char* BsBase = (char*)Bsm + w * 4096;

    fx4 acc[4][4] = {};

    const int fra = wr * 64 + (lane & 15);   // + mi*16
    const int frb = wc * 64 + (lane & 15);   // + nj*16
    const int kb  = (lane >> 4) << 4;        // byte col offset for this lane group
    const int swz = (lane & 7) << 4;         // row&7 == lane&7 for fragment rows

    for (int k0 = 0; k0 < K; k0 += 64) {
        __syncthreads();
        #pragma unroll
        for (int j = 0; j < 4; ++j) {
            gload16(Ag + (size_t)j * 8 * K + k0, AsBase + j * 1024);
            gload16(Bg + (size_t)j * 8 * K + k0, BsBase + j * 1024);
        }
        __syncthreads();
        #pragma unroll
        for (int kk = 0; kk < 2; ++kk) {
            const int cb = kk * 64 + kb;
            bhalf8 af[4], bfr[4];
            #pragma unroll
            for (int mi = 0; mi < 4; ++mi)
                af[mi] = *(const bhalf8*)((const char*)Asm + (fra + mi * 16) * 128 + (cb ^ swz));
            #pragma unroll
            for (int nj = 0; nj < 4; ++nj)
                bfr[nj] = *(const bhalf8*)((const char*)Bsm + (frb + nj * 16) * 128 + (cb ^ swz));
            #pragma unroll
            for (int mi = 0; mi < 4; ++mi)
                #pragma unroll
                for (int nj = 0; nj < 4; ++nj)
                    acc[mi][nj] = __builtin_amdgcn_mfma_f32_16x16x32_bf16(
                        af[mi], bfr[nj], acc[mi][nj], 0, 0, 0);
        }
    }

    #pragma unroll
    for (int nj = 0; nj < 4; ++nj) {
        const int ccol = rowB + wc * 64 + nj * 16 + (lane & 15);
        const float bv = (flags & 1) ? bias[ccol] : 0.f;
        #pragma unroll
        for (int mi = 0; mi < 4; ++mi) {
            const int crow0 = rowA + wr * 64 + mi * 16 + ((lane >> 4) << 2);
            #pragma unroll
            for (int i = 0; i < 4; ++i) {
                size_t idx = (size_t)(crow0 + i) * N + ccol;
                float v = acc[mi][nj][i] + bv;
                if (flags & 2) v += C[idx];
                if (C)  C[idx]  = v;
                if (Cb) Cb[idx] = __float2bfloat16(v);
            }
        }
    }
    (void)M;
}

// ------------------------------------------------------------------
// fp32 tiled GEMM (kept for tiny E2 = ea @ e2w)
// ------------------------------------------------------------------
__global__ __launch_bounds__(256) void gemm_tile(
    const float* __restrict__ A, const float* __restrict__ B,
    const float* __restrict__ bias, float* __restrict__ C,
    int M, int N, int K, int flags)
{
    __shared__ float As[16][68];
    __shared__ float Bs[16][64];
    const int tid = threadIdx.x;
    const int bx = blockIdx.x, by = blockIdx.y;
    const int tx = tid & 15, ty = tid >> 4;
    const int arow = tid >> 2, acol = (tid & 3) << 2;
    const int brow = tid >> 4, bcol = (tid & 15) << 2;
    const float* Ag = A + (size_t)(by * 64 + arow) * K + acol;
    const float* Bg = B + (size_t)brow * N + bx * 64 + bcol;
    float acc[4][4] = {};
    for (int k0 = 0; k0 < K; k0 += 16) {
        const float4 av = *(const float4*)(Ag + k0);
        const float4 bv = *(const float4*)(Bg + (size_t)k0 * N);
        __syncthreads();
        As[acol + 0][arow] = av.x;
        As[acol + 1][arow] = av.y;
        As[acol + 2][arow] = av.z;
        As[acol + 3][arow] = av.w;
        *(float4*)&Bs[brow][bcol] = bv;
        __syncthreads();
        #pragma unroll
        for (int kk = 0; kk < 16; ++kk) {
            const float4 a4 = *(const float4*)&As[kk][ty << 2];
            const float4 b4 = *(const float4*)&Bs[kk][tx << 2];
            const float a[4] = {a4.x, a4.y, a4.z, a4.w};
            const float b[4] = {b4.x, b4.y, b4.z, b4.w};
            #pragma unroll
            for (int i = 0; i < 4; ++i)
                #pragma unroll
                for (int j = 0; j < 4; ++j)
                    acc[i][j] += a[i] * b[j];
        }
    }
    const int crow = by * 64 + (ty << 2);
    const int ccol = bx * 64 + (tx << 2);
    float4 b4 = make_float4(0.f, 0.f, 0.f, 0.f);
    if (flags & 1) b4 = *(const float4*)(bias + ccol);
    #pragma unroll
    for (int i = 0; i < 4; ++i) {
        float* cp = C + (size_t)(crow + i) * N + ccol;
        float4 v;
        v.x = acc[i][0] + b4.x; v.y = acc[i][1] + b4.y;
        v.z = acc[i][2] + b4.z; v.w = acc[i][3] + b4.w;
        if (flags & 2) {
            const float4 o = *(const float4*)cp;
            v.x += o.x; v.y += o.y; v.z += o.z; v.w += o.w;
        }
        *(float4*)cp = v;
    }
}

// ------------------------------------------------------------------
// CSR build
// ------------------------------------------------------------------
__global__ void count_deg(const int* __restrict__ ei, int* __restrict__ deg)
{
    int e = blockIdx.x * 256 + threadIdx.x;
    if (e < NE) atomicAdd(&deg[ei[NE + e]], 1);
}

__global__ __launch_bounds__(1024) void scan_kernel(const int* __restrict__ deg,
                                                    int* __restrict__ rowptr)
{
    __shared__ int s[1024];
    const int t = threadIdx.x;
    const int base = t * 7;
    int loc[7];
    int sum = 0;
    #pragma unroll
    for (int i = 0; i < 7; ++i) {
        int idx = base + i;
        int v = (idx < NN) ? deg[idx] : 0;
        loc[i] = v; sum += v;
    }
    s[t] = sum;
    __syncthreads();
    for (int off = 1; off < 1024; off <<= 1) {
        int v = (t >= off) ? s[t - off] : 0;
        __syncthreads();
        s[t] += v;
        __syncthreads();
    }
    int running = s[t] - sum;
    #pragma unroll
    for (int i = 0; i < 7; ++i) {
        int idx = base + i;
        if (idx <= NN) rowptr[idx] = running;
        if (idx < NN) running += loc[i];
    }
}

__global__ void fill_csr(const int* __restrict__ ei, const int* __restrict__ rowptr,
                         int* __restrict__ fillctr, int* __restrict__ elist)
{
    int e = blockIdx.x * 256 + threadIdx.x;
    if (e >= NE) return;
    int d = ei[NE + e];
    int pos = atomicAdd(&fillctr[d], 1);
    elist[rowptr[d] + pos] = e;
}

__global__ void sort_csr(const int* __restrict__ rowptr, int* __restrict__ elist)
{
    int n = blockIdx.x * 256 + threadIdx.x;
    if (n >= NN) return;
    int s0 = rowptr[n], s1 = rowptr[n + 1];
    for (int i = s0 + 1; i < s1; ++i) {
        int v = elist[i];
        int j = i - 1;
        while (j >= s0 && elist[j] > v) { elist[j + 1] = elist[j]; --j; }
        elist[j + 1] = v;
    }
}

// ------------------------------------------------------------------
// conversions / weight prep
// ------------------------------------------------------------------
__global__ void cvt_pad_bf16(const float* __restrict__ src, __hip_bfloat16* __restrict__ dst,
                             int relu)   // [MPAD x 2048], zero pad rows, optional relu
{
    size_t i = (size_t)(blockIdx.x * 256 + threadIdx.x) * 4;
    int row = (int)(i >> 11);
    float4 v = make_float4(0.f, 0.f, 0.f, 0.f);
    if (row < NN) v = *(const float4*)&src[i];
    if (relu) {
        v.x = fmaxf(v.x, 0.f); v.y = fmaxf(v.y, 0.f);
        v.z = fmaxf(v.z, 0.f); v.w = fmaxf(v.w, 0.f);
    }
    dst[i + 0] = __float2bfloat16(v.x);
    dst[i + 1] = __float2bfloat16(v.y);
    dst[i + 2] = __float2bfloat16(v.z);
    dst[i + 3] = __float2bfloat16(v.w);
}

// Bt[n][k] = bf16(W[k][n]); K,N multiples of 32
__global__ __launch_bounds__(256) void transpose_cvt(const float* __restrict__ W,
                                                     __hip_bfloat16* __restrict__ Bt,
                                                     int K, int N)
{
    __shared__ float t[32][33];
    int kb = blockIdx.y * 32, nb = blockIdx.x * 32;
    int tx = threadIdx.x & 31, ty = threadIdx.x >> 5;   // 32x8
    #pragma unroll
    for (int i = 0; i < 32; i += 8)
        t[ty + i][tx] = W[(size_t)(kb + ty + i) * N + nb + tx];
    __syncthreads();
    #pragma unroll
    for (int i = 0; i < 32; i += 8)
        Bt[(size_t)(nb + ty + i) * K + kb + tx] = __float2bfloat16(t[tx][ty + i]);
}

// w1pp[p][j] = W1p[j][p] = ((j>>10)==(p>>6)) ? e1w[(p&63)*2048 + j] : 0   [128 x 2048]
__global__ void build_w1pp(const float* __restrict__ e1w, __hip_bfloat16* __restrict__ w1pp)
{
    int idx = blockIdx.x * 256 + threadIdx.x;
    int p = idx >> 11, j = idx & 2047;
    float v = ((j >> 10) == (p >> 6)) ? e1w[(size_t)(p & 63) * KDIM + j] : 0.f;
    w1pp[idx] = __float2bfloat16(v);
}

// w1ppT[n][k] = W1pp[k][n] = ((n>>10)==(k>>6)) ? e1w[(k&63)*2048 + n] : 0  [2048 x 128]
__global__ void build_w1ppT(const float* __restrict__ e1w, __hip_bfloat16* __restrict__ w1ppT)
{
    int idx = blockIdx.x * 256 + threadIdx.x;
    int n = idx >> 7, k = idx & 127;
    float v = ((n >> 10) == (k >> 6)) ? e1w[(size_t)(k & 63) * KDIM + n] : 0.f;
    w1ppT[idx] = __float2bfloat16(v);
}

// w2t[c][d] = w_g[d][c&63]  (g = c>>6 over {q,k,v,s}), b2[c]
__global__ void build_w2t(const float* __restrict__ qw, const float* __restrict__ kw,
                          const float* __restrict__ vw, const float* __restrict__ sw,
                          const float* __restrict__ qb, const float* __restrict__ kb,
                          const float* __restrict__ vb, const float* __restrict__ sb,
                          __hip_bfloat16* __restrict__ w2t, float* __restrict__ b2)
{
    int idx = blockIdx.x * 256 + threadIdx.x;
    int c = idx >> 11, d = idx & 2047;
    int g = c >> 6, j = c & 63;
    const float* w = (g == 0) ? qw : (g == 1) ? kw : (g == 2) ? vw : sw;
    w2t[idx] = __float2bfloat16(w[(size_t)d * 64 + j]);
    if (d == 0) {
        const float* b = (g == 0) ? qb : (g == 1) ? kb : (g == 2) ? vb : sb;
        b2[c] = b[j];
    }
}

// ------------------------------------------------------------------
// edge kernels, layer 1
// ------------------------------------------------------------------
__global__ __launch_bounds__(256) void alpha1_kernel(
    const __hip_bfloat16* __restrict__ q1b, const __hip_bfloat16* __restrict__ k1b,
    const float* __restrict__ P1, const float* __restrict__ ea,
    const int* __restrict__ ei, float* __restrict__ alpha)
{
    int e = blockIdx.x * 4 + (threadIdx.x >> 6);
    int lane = threadIdx.x & 63;
    int src = ei[e], dst = ei[NE + e];
    float eaj = ea[(size_t)e * 64 + lane];
    #pragma unroll
    for (int h = 0; h < 2; ++h) {
        const __hip_bfloat16* qh = q1b + (size_t)dst * HC1 + h * 1024 + lane * 16;
        const __hip_bfloat16* kh = k1b + (size_t)src * HC1 + h * 1024 + lane * 16;
        bhalf8 qa = *(const bhalf8*)qh, qc = *(const bhalf8*)(qh + 8);
        bhalf8 ka = *(const bhalf8*)kh, kc = *(const bhalf8*)(kh + 8);
        float s = 0.f;
        #pragma unroll
        for (int j = 0; j < 8; ++j) s += bf2f(qa[j]) * bf2f(ka[j]);
        #pragma unroll
        for (int j = 0; j < 8; ++j) s += bf2f(qc[j]) * bf2f(kc[j]);
        s += eaj * P1[(size_t)dst * 128 + h * 64 + lane];
        #pragma unroll
        for (int off = 32; off; off >>= 1) s += __shfl_xor(s, off);
        if (lane == 0) alpha[(size_t)e * 2 + h] = s * 0.03125f;
    }
}

__global__ void softmax_kernel(const int* __restrict__ rowptr, const int* __restrict__ elist,
                               float* __restrict__ alpha, int H)
{
    int n = blockIdx.x * 256 + threadIdx.x;
    if (n >= NN) return;
    int s0 = rowptr[n], s1 = rowptr[n + 1];
    for (int h = 0; h < H; ++h) {
        float m = -1e30f;
        for (int i = s0; i < s1; ++i)
            m = fmaxf(m, alpha[(size_t)elist[i] * H + h]);
        float ssum = 0.f;
        for (int i = s0; i < s1; ++i) {
            float ex = __expf(alpha[(size_t)elist[i] * H + h] - m);
            alpha[(size_t)elist[i] * H + h] = ex;
            ssum += ex;
        }
        float inv = 1.f / (ssum + 1e-16f);
        for (int i = s0; i < s1; ++i)
            alpha[(size_t)elist[i] * H + h] *= inv;
    }
}

// R1[n][p] = sum_{e in in(n)} attn[e][p>>6] * ea[e][p&63]  (bf16 out)
__global__ __launch_bounds__(128) void r1_kernel(
    const int* __restrict__ rowptr, const int* __restrict__ elist,
    const float* __restrict__ attn, const float* __restrict__ ea,
    __hip_bfloat16* __restrict__ R1)
{
    int n = blockIdx.x;
    int p = threadIdx.x;
    int h = p >> 6, j = p & 63;
    int s0 = rowptr[n], s1 = rowptr[n + 1];
    float r = 0.f;
    for (int i = s0; i < s1; ++i) {
        int e = elist[i];
        r += attn[(size_t)e * 2 + h] * ea[(size_t)e * 64 + j];
    }
    R1[(size_t)n * 128 + p] = __float2bfloat16(r);
}

// h1[n][c] += sum_e attn[e][h] * v1b[src][c]
__global__ __launch_bounds__(256) void agg1_kernel(
    const int* __restrict__ rowptr, const int* __restrict__ elist,
    const int* __restrict__ ei, const float* __restrict__ attn,
    const __hip_bfloat16* __restrict__ v1b, float* __restrict__ h1)
{
    int n = blockIdx.x;
    int c0 = threadIdx.x * 8;
    int h = c0 >> 10;
    int s0 = rowptr[n], s1 = rowptr[n + 1];
    float acc[8];
    const float4 p0 = *(const float4*)&h1[(size_t)n * HC1 + c0];
    const float4 p1 = *(const float4*)&h1[(size_t)n * HC1 + c0 + 4];
    acc[0] = p0.x; acc[1] = p0.y; acc[2] = p0.z; acc[3] = p0.w;
    acc[4] = p1.x; acc[5] = p1.y; acc[6] = p1.z; acc[7] = p1.w;
    for (int i = s0; i < s1; ++i) {
        int e = elist[i];
        float at = attn[(size_t)e * 2 + h];
        bhalf8 v = *(const bhalf8*)&v1b[(size_t)ei[e] * HC1 + c0];
        #pragma unroll
        for (int j = 0; j < 8; ++j) acc[j] += at * bf2f(v[j]);
    }
    float4 o0 = make_float4(acc[0], acc[1], acc[2], acc[3]);
    float4 o1 = make_float4(acc[4], acc[5], acc[6], acc[7]);
    *(float4*)&h1[(size_t)n * HC1 + c0] = o0;
    *(float4*)&h1[(size_t)n * HC1 + c0 + 4] = o1;
}

// ------------------------------------------------------------------
// layer 2 edge kernels (qkvs2 fp32: [q|k|v|skip] x 64)
// ------------------------------------------------------------------
__global__ __launch_bounds__(256) void alpha2_kernel(
    const float* __restrict__ qkvs2, const float* __restrict__ E2,
    const int* __restrict__ ei, float* __restrict__ alpha2)
{
    int e = blockIdx.x * 4 + (threadIdx.x >> 6);
    int lane = threadIdx.x & 63;
    int src = ei[e], dst = ei[NE + e];
    float q = qkvs2[(size_t)dst * 256 + lane];
    float k = qkvs2[(size_t)src * 256 + 64 + lane];
    float s = q * (k + E2[(size_t)e * 64 + lane]);
    #pragma unroll
    for (int off = 32; off; off >>= 1) s += __shfl_xor(s, off);
    if (lane == 0) alpha2[e] = s * 0.125f;
}

__global__ __launch_bounds__(64) void agg2_kernel(
    const int* __restrict__ rowptr, const int* __restrict__ elist,
    const int* __restrict__ ei, const float* __restrict__ attn2,
    const float* __restrict__ qkvs2, const float* __restrict__ E2,
    float* __restrict__ out)
{
    int n = blockIdx.x;
    int c = threadIdx.x;
    int s0 = rowptr[n], s1 = rowptr[n + 1];
    float acc = qkvs2[(size_t)n * 256 + 192 + c];
    for (int i = s0; i < s1; ++i) {
        int e = elist[i];
        acc += attn2[e] * (qkvs2[(size_t)ei[e] * 256 + 128 + c] + E2[(size_t)e * 64 + c]);
    }
    out[(size_t)n * 64 + c] = fmaxf(acc, 0.f);
}

// ------------------------------------------------------------------
extern "C" void kernel_launch(void* const* d_in, const int* in_sizes, int n_in,
                              void* d_out, int out_size, void* d_ws, size_t ws_size,
                              hipStream_t stream)
{
    const float* x   = (const float*)d_in[0];
    const int*   ei  = (const int*)d_in[1];
    const float* ea  = (const float*)d_in[2];
    const float* q1w = (const float*)d_in[3];
    const float* q1b = (const float*)d_in[4];
    const float* k1w = (const float*)d_in[5];
    const float* k1b = (const float*)d_in[6];
    const float* v1w = (const float*)d_in[7];
    const float* v1b = (const float*)d_in[8];
    const float* e1w = (const float*)d_in[9];
    const float* s1w = (const float*)d_in[10];
    const float* s1b = (const float*)d_in[11];
    const float* q2w = (const float*)d_in[12];
    const float* q2b = (const float*)d_in[13];
    const float* k2w = (const float*)d_in[14];
    const float* k2b = (const float*)d_in[15];
    const float* v2w = (const float*)d_in[16];
    const float* v2b = (const float*)d_in[17];
    const float* e2w = (const float*)d_in[18];
    const float* s2w = (const float*)d_in[19];
    const float* s2b = (const float*)d_in[20];
    float* out = (float*)d_out;

    char* base = (char*)d_ws;
    size_t off = 0;
    auto alloc = [&](size_t nbytes) {
        size_t o = off; off += (nbytes + 255) & ~(size_t)255; return o;
    };
    __hip_bfloat16* xb    = (__hip_bfloat16*)(base + alloc((size_t)MPAD * KDIM * 2));
    __hip_bfloat16* wt    = (__hip_bfloat16*)(base + alloc((size_t)KDIM * KDIM * 2));
    __hip_bfloat16* q1bb  = (__hip_bfloat16*)(base + alloc((size_t)MPAD * HC1 * 2));
    __hip_bfloat16* k1bb  = (__hip_bfloat16*)(base + alloc((size_t)MPAD * HC1 * 2));
    __hip_bfloat16* v1bb  = (__hip_bfloat16*)(base + alloc((size_t)MPAD * HC1 * 2));
    float*          h1    = (float*)(base + alloc((size_t)MPAD * HC1 * 4));
    __hip_bfloat16* h1b   = (__hip_bfloat16*)(base + alloc((size_t)MPAD * HC1 * 2));
    float*          P1    = (float*)(base + alloc((size_t)MPAD * 128 * 4));
    __hip_bfloat16* R1b   = (__hip_bfloat16*)(base + alloc((size_t)MPAD * 128 * 2));
    __hip_bfloat16* w1pp  = (__hip_bfloat16*)(base + alloc((size_t)128 * KDIM * 2));
    __hip_bfloat16* w1ppT = (__hip_bfloat16*)(base + alloc((size_t)KDIM * 128 * 2));
    __hip_bfloat16* w2t   = (__hip_bfloat16*)(base + alloc((size_t)256 * KDIM * 2));
    float*          b2    = (float*)(base + alloc(256 * 4));
    float*          qkvs2 = (float*)(base + alloc((size_t)MPAD * 256 * 4));
    float*          E2    = (float*)(base + alloc((size_t)NE * 64 * 4));
    float*          at1   = (float*)(base + alloc((size_t)NE * 2 * 4));
    float*          at2   = (float*)(base + alloc((size_t)NE * 4));
    int* deg    = (int*)(base + alloc((size_t)NN * 4));
    int* fill   = (int*)(base + alloc((size_t)NN * 4));
    int* rowptr = (int*)(base + alloc((size_t)(NN + 1) * 4));
    int* elist  = (int*)(base + alloc((size_t)NE * 4));

    // --- CSR build ---
    hipMemsetAsync(deg, 0, ((size_t)(fill + NN) - (size_t)deg), stream);
    count_deg<<<(NE + 255) / 256, 256, 0, stream>>>(ei, deg);
    scan_kernel<<<1, 1024, 0, stream>>>(deg, rowptr);
    fill_csr<<<(NE + 255) / 256, 256, 0, stream>>>(ei, rowptr, fill, elist);
    sort_csr<<<(NN + 255) / 256, 256, 0, stream>>>(rowptr, elist);

    // --- input conversion ---
    const int cvblk = (MPAD * KDIM / 4) / 256;
    cvt_pad_bf16<<<cvblk, 256, 0, stream>>>(x, xb, 0);

    const dim3 tgrid(KDIM / 32, KDIM / 32);
    const dim3 ggrid(KDIM / 128, MPAD / 128);

    // --- layer 1 projections (bf16 MFMA) ---
    transpose_cvt<<<tgrid, 256, 0, stream>>>(q1w, wt, KDIM, HC1);
    gemm_bf16<<<ggrid, 256, 0, stream>>>(xb, wt, q1b, nullptr, q1bb, MPAD, HC1, KDIM, 1);
    transpose_cvt<<<tgrid, 256, 0, stream>>>(k1w, wt, KDIM, HC1);
    gemm_bf16<<<ggrid, 256, 0, stream>>>(xb, wt, k1b, nullptr, k1bb, MPAD, HC1, KDIM, 1);
    transpose_cvt<<<tgrid, 256, 0, stream>>>(v1w, wt, KDIM, HC1);
    gemm_bf16<<<ggrid, 256, 0, stream>>>(xb, wt, v1b, nullptr, v1bb, MPAD, HC1, KDIM, 1);
    transpose_cvt<<<tgrid, 256, 0, stream>>>(s1w, wt, KDIM, HC1);
    gemm_bf16<<<ggrid, 256, 0, stream>>>(xb, wt, s1b, h1, nullptr, MPAD, HC1, KDIM, 1);

    // --- P1 = q1 @ W1p ---
    build_w1pp<<<(128 * KDIM) / 256, 256, 0, stream>>>(e1w, w1pp);
    build_w1ppT<<<(KDIM * 128) / 256, 256, 0, stream>>>(e1w, w1ppT);
    gemm_bf16<<<dim3(1, MPAD / 128), 256, 0, stream>>>(q1bb, w1pp, nullptr, P1, nullptr,
                                                       MPAD, 128, KDIM, 0);

    // --- attention layer 1 ---
    alpha1_kernel<<<NE / 4, 256, 0, stream>>>(q1bb, k1bb, P1, ea, ei, at1);
    softmax_kernel<<<(NN + 255) / 256, 256, 0, stream>>>(rowptr, elist, at1, 2);
    r1_kernel<<<NN, 128, 0, stream>>>(rowptr, elist, at1, ea, R1b);
    agg1_kernel<<<NN, 256, 0, stream>>>(rowptr, elist, ei, at1, v1bb, h1);
    gemm_bf16<<<dim3(HC1 / 128, MPAD / 128), 256, 0, stream>>>(R1b, w1ppT, nullptr, h1, nullptr,
                                                               MPAD, HC1, 128, 2);
    cvt_pad_bf16<<<cvblk, 256, 0, stream>>>(h1, h1b, 1);   // relu + bf16

    // --- layer 2 projections ---
    build_w2t<<<(256 * KDIM) / 256, 256, 0, stream>>>(q2w, k2w, v2w, s2w, q2b, k2b, v2b, s2b,
                                                      w2t, b2);
    gemm_bf16<<<dim3(256 / 128, MPAD / 128), 256, 0, stream>>>(h1b, w2t, b2, qkvs2, nullptr,
                                                               MPAD, 256, KDIM, 1);
    gemm_tile<<<dim3(1, NE / 64), 256, 0, stream>>>(ea, e2w, nullptr, E2, NE, 64, 64, 0);

    // --- attention layer 2 ---
    alpha2_kernel<<<NE / 4, 256, 0, stream>>>(qkvs2, E2, ei, at2);
    softmax_kernel<<<(NN + 255) / 256, 256, 0, stream>>>(rowptr, elist, at2, 1);
    agg2_kernel<<<NN, 64, 0, stream>>>(rowptr, elist, ei, at2, qkvs2, E2, out);

    (void)in_sizes; (void)n_in; (void)out_size; (void)ws_size;
}

// Round 3
// 639.466 us; speedup vs baseline: 5.6521x; 1.1191x over previous
//
#include <hip/hip_runtime.h>
#include <hip/hip_bf16.h>
#include <cstdint>
#include <cstddef>

#define NN    6720     // nodes
#define MPAD  6912     // 27 * 256 = 54 * 128
#define NE    33600    // edges
#define KDIM  2048
#define HC1   2048

typedef __attribute__((ext_vector_type(8))) short bhalf8;
typedef __attribute__((ext_vector_type(4))) float fx4;

__device__ __forceinline__ float bf2f(short s) {
    union { unsigned int u; float f; } c;
    c.u = ((unsigned int)(unsigned short)s) << 16;
    return c.f;
}

__device__ __forceinline__ void gload16(const __hip_bfloat16* g, void* lds)
{
    __builtin_amdgcn_global_load_lds(
        (const __attribute__((address_space(1))) unsigned int*)g,
        (__attribute__((address_space(3))) unsigned int*)lds,
        16, 0, 0);
}

#define CFENCE asm volatile("" ::: "memory")

// ------------------------------------------------------------------
// 256x256-tile 8-wave fused projection GEMM.
// A [MPAD x 2048] bf16, Bt [8192 x 2048] bf16 (rows = out cols of q|k|v|s).
// Per 64-K tile: burst-stage next tile (8 gload_lds/thread), 4 phases of
// {ds_read quadrant frags; setprio(1); 16 MFMA; setprio(0); s_barrier},
// single vmcnt(0)+barrier at tile end (loads had 4 phases to fly).
// Epilogue segments cols: [0,2048)->oq bf16, ->ok, ->ov, [6144,8192)->oh fp32.
// ------------------------------------------------------------------
__global__ __launch_bounds__(512, 2) void gemm256_fused(
    const __hip_bfloat16* __restrict__ A,
    const __hip_bfloat16* __restrict__ Bt,
    const float* __restrict__ bcat,
    __hip_bfloat16* __restrict__ oq,
    __hip_bfloat16* __restrict__ ok,
    __hip_bfloat16* __restrict__ ov,
    float* __restrict__ oh)
{
    __shared__ alignas(16) __hip_bfloat16 As[2][256 * 64];
    __shared__ alignas(16) __hip_bfloat16 Bs[2][256 * 64];

    // XCD-aware bijective swizzle: 864 blocks = 8 XCD * 108
    const int bid = blockIdx.x;
    const int wg  = (bid & 7) * 108 + (bid >> 3);
    const int bx  = wg & 31;        // N: 32 tiles of 256
    const int by  = wg >> 5;        // M: 27 tiles of 256

    const int tid  = threadIdx.x;
    const int w    = tid >> 6;       // 0..7
    const int lane = tid & 63;
    const int wr = w >> 2, wc = w & 3;   // 2 x 4 wave grid; wave tile 128x64
    const int rowA = by * 256;
    const int rowB = bx * 256;

    // staging geometry (identical pattern to verified 128^2 kernel)
    const int srow = w * 32 + (lane >> 3);
    const int ug8  = ((lane & 7) ^ (lane >> 3)) << 3;
    const __hip_bfloat16* Ag = A  + (size_t)(rowA + srow) * KDIM + ug8;
    const __hip_bfloat16* Bg = Bt + (size_t)(rowB + srow) * KDIM + ug8;

    const int fra = wr * 128 + (lane & 15);
    const int frb = wc * 64  + (lane & 15);
    const int kb  = (lane >> 4) << 4;
    const int swz = (lane & 7) << 4;

    fx4 acc[8][4] = {};

    auto STAGE = [&](int kt, int bsel) {
        const int k0 = kt * 64;
        char* asb = (char*)&As[bsel][0] + w * 4096;
        char* bsb = (char*)&Bs[bsel][0] + w * 4096;
        #pragma unroll
        for (int j = 0; j < 4; ++j) {
            gload16(Ag + (size_t)j * 8 * KDIM + k0, asb + j * 1024);
            gload16(Bg + (size_t)j * 8 * KDIM + k0, bsb + j * 1024);
        }
    };

    const int NT = KDIM / 64;   // 32
    STAGE(0, 0);
    asm volatile("s_waitcnt vmcnt(0)" ::: "memory");
    __builtin_amdgcn_s_barrier();
    CFENCE;

    for (int t = 0; t < NT; ++t) {
        const int cur = t & 1;
        if (t + 1 < NT) STAGE(t + 1, cur ^ 1);
        const char* asw = (const char*)&As[cur][0];
        const char* bsw = (const char*)&Bs[cur][0];
        #pragma unroll
        for (int q = 0; q < 4; ++q) {
            const int msub = q & 1, nsub = q >> 1;
            bhalf8 af[4][2], bq[2][2];
            #pragma unroll
            for (int im = 0; im < 4; ++im) {
                const int row = fra + (msub * 4 + im) * 16;
                #pragma unroll
                for (int kk = 0; kk < 2; ++kk)
                    af[im][kk] = *(const bhalf8*)(asw + row * 128 + ((kk * 64 + kb) ^ swz));
            }
            #pragma unroll
            for (int jn = 0; jn < 2; ++jn) {
                const int row = frb + (nsub * 2 + jn) * 16;
                #pragma unroll
                for (int kk = 0; kk < 2; ++kk)
                    bq[jn][kk] = *(const bhalf8*)(bsw + row * 128 + ((kk * 64 + kb) ^ swz));
            }
            __builtin_amdgcn_s_setprio(1);
            #pragma unroll
            for (int im = 0; im < 4; ++im)
                #pragma unroll
                for (int jn = 0; jn < 2; ++jn)
                    #pragma unroll
                    for (int kk = 0; kk < 2; ++kk)
                        acc[msub * 4 + im][nsub * 2 + jn] =
                            __builtin_amdgcn_mfma_f32_16x16x32_bf16(
                                af[im][kk], bq[jn][kk],
                                acc[msub * 4 + im][nsub * 2 + jn], 0, 0, 0);
            __builtin_amdgcn_s_setprio(0);
            CFENCE;
            if (q < 3) { __builtin_amdgcn_s_barrier(); CFENCE; }
        }
        asm volatile("s_waitcnt vmcnt(0)" ::: "memory");
        __builtin_amdgcn_s_barrier();
        CFENCE;
    }

    // epilogue: segment by global column
    const int seg = bx >> 3;   // 0:q 1:k 2:v 3:skip(fp32)
    #pragma unroll
    for (int nj = 0; nj < 4; ++nj) {
        const int ccol = rowB + wc * 64 + nj * 16 + (lane & 15);
        const int lcol = ccol & 2047;
        const float bv = bcat[ccol];
        #pragma unroll
        for (int mi = 0; mi < 8; ++mi) {
            const int crow0 = rowA + wr * 128 + mi * 16 + ((lane >> 4) << 2);
            #pragma unroll
            for (int i = 0; i < 4; ++i) {
                const float v = acc[mi][nj][i] + bv;
                const size_t idx = (size_t)(crow0 + i) * 2048 + lcol;
                if (seg == 0)      oq[idx] = __float2bfloat16(v);
                else if (seg == 1) ok[idx] = __float2bfloat16(v);
                else if (seg == 2) ov[idx] = __float2bfloat16(v);
                else               oh[idx] = v;
            }
        }
    }
}

// ------------------------------------------------------------------
// 128x128 bf16 MFMA GEMM (4 waves), optional split-K via blockIdx.z.
// C[M,N] = A[M,K] @ Bt[N,K]^T (+bias)(+=C). z>0 writes C + z*M*N.
// ------------------------------------------------------------------
__global__ __launch_bounds__(256) void gemm_bf16(
    const __hip_bfloat16* __restrict__ A,
    const __hip_bfloat16* __restrict__ Bt,
    const float* __restrict__ bias,
    float* __restrict__ C,
    __hip_bfloat16* __restrict__ Cb,
    int M, int N, int K, int flags)
{
    __shared__ alignas(16) __hip_bfloat16 Asm[128 * 64];
    __shared__ alignas(16) __hip_bfloat16 Bsm[128 * 64];
    const int tid  = threadIdx.x;
    const int w    = tid >> 6;
    const int lane = tid & 63;
    const int wr = w >> 1, wc = w & 1;
    const int rowA = blockIdx.y * 128;
    const int rowB = blockIdx.x * 128;
    const int klen = K / gridDim.z;
    const int kbeg = blockIdx.z * klen;

    const int srow = w * 32 + (lane >> 3);
    const int ug8  = ((lane & 7) ^ (lane >> 3)) << 3;
    const __hip_bfloat16* Ag = A  + (size_t)(rowA + srow) * K + ug8;
    const __hip_bfloat16* Bg = Bt + (size_t)(rowB + srow) * K + ug8;
    char* AsBase = (char*)Asm + w * 4096;
    char* BsBase = (char*)Bsm + w * 4096;

    fx4 acc[4][4] = {};

    const int fra = wr * 64 + (lane & 15);
    const int frb = wc * 64 + (lane & 15);
    const int kb  = (lane >> 4) << 4;
    const int swz = (lane & 7) << 4;

    for (int k0 = kbeg; k0 < kbeg + klen; k0 += 64) {
        __syncthreads();
        #pragma unroll
        for (int j = 0; j < 4; ++j) {
            gload16(Ag + (size_t)j * 8 * K + k0, AsBase + j * 1024);
            gload16(Bg + (size_t)j * 8 * K + k0, BsBase + j * 1024);
        }
        __syncthreads();
        #pragma unroll
        for (int kk = 0; kk < 2; ++kk) {
            const int cb = kk * 64 + kb;
            bhalf8 af[4], bfr[4];
            #pragma unroll
            for (int mi = 0; mi < 4; ++mi)
                af[mi] = *(const bhalf8*)((const char*)Asm + (fra + mi * 16) * 128 + (cb ^ swz));
            #pragma unroll
            for (int nj = 0; nj < 4; ++nj)
                bfr[nj] = *(const bhalf8*)((const char*)Bsm + (frb + nj * 16) * 128 + (cb ^ swz));
            #pragma unroll
            for (int mi = 0; mi < 4; ++mi)
                #pragma unroll
                for (int nj = 0; nj < 4; ++nj)
                    acc[mi][nj] = __builtin_amdgcn_mfma_f32_16x16x32_bf16(
                        af[mi], bfr[nj], acc[mi][nj], 0, 0, 0);
        }
    }

    float* Cz = C ? C + (size_t)blockIdx.z * ((size_t)M * N) : nullptr;
    #pragma unroll
    for (int nj = 0; nj < 4; ++nj) {
        const int ccol = rowB + wc * 64 + nj * 16 + (lane & 15);
        const float bv = (flags & 1) ? bias[ccol] : 0.f;
        #pragma unroll
        for (int mi = 0; mi < 4; ++mi) {
            const int crow0 = rowA + wr * 64 + mi * 16 + ((lane >> 4) << 2);
            #pragma unroll
            for (int i = 0; i < 4; ++i) {
                size_t idx = (size_t)(crow0 + i) * N + ccol;
                float v = acc[mi][nj][i] + bv;
                if (flags & 2) v += Cz[idx];
                if (Cz) Cz[idx] = v;
                if (Cb) Cb[idx] = __float2bfloat16(v);
            }
        }
    }
}

// dst[i] = sum_z parts[z*stride + i] (+ bias[i & colmask])
__global__ void reduce4(const float* __restrict__ parts, size_t stride,
                        const float* __restrict__ bias, int colmask,
                        float* __restrict__ dst, int n)
{
    int i = blockIdx.x * 256 + threadIdx.x;
    if (i >= n) return;
    float v = parts[i] + parts[stride + i] + parts[2 * stride + i] + parts[3 * stride + i];
    if (bias) v += bias[i & colmask];
    dst[i] = v;
}

// ------------------------------------------------------------------
// fp32 tiled GEMM (kept for tiny E2 = ea @ e2w)
// ------------------------------------------------------------------
__global__ __launch_bounds__(256) void gemm_tile(
    const float* __restrict__ A, const float* __restrict__ B,
    const float* __restrict__ bias, float* __restrict__ C,
    int M, int N, int K, int flags)
{
    __shared__ float As[16][68];
    __shared__ float Bs[16][64];
    const int tid = threadIdx.x;
    const int bx = blockIdx.x, by = blockIdx.y;
    const int tx = tid & 15, ty = tid >> 4;
    const int arow = tid >> 2, acol = (tid & 3) << 2;
    const int brow = tid >> 4, bcol = (tid & 15) << 2;
    const float* Ag = A + (size_t)(by * 64 + arow) * K + acol;
    const float* Bg = B + (size_t)brow * N + bx * 64 + bcol;
    float acc[4][4] = {};
    for (int k0 = 0; k0 < K; k0 += 16) {
        const float4 av = *(const float4*)(Ag + k0);
        const float4 bv = *(const float4*)(Bg + (size_t)k0 * N);
        __syncthreads();
        As[acol + 0][arow] = av.x;
        As[acol + 1][arow] = av.y;
        As[acol + 2][arow] = av.z;
        As[acol + 3][arow] = av.w;
        *(float4*)&Bs[brow][bcol] = bv;
        __syncthreads();
        #pragma unroll
        for (int kk = 0; kk < 16; ++kk) {
            const float4 a4 = *(const float4*)&As[kk][ty << 2];
            const float4 b4 = *(const float4*)&Bs[kk][tx << 2];
            const float a[4] = {a4.x, a4.y, a4.z, a4.w};
            const float b[4] = {b4.x, b4.y, b4.z, b4.w};
            #pragma unroll
            for (int i = 0; i < 4; ++i)
                #pragma unroll
                for (int j = 0; j < 4; ++j)
                    acc[i][j] += a[i] * b[j];
        }
    }
    const int crow = by * 64 + (ty << 2);
    const int ccol = bx * 64 + (tx << 2);
    float4 b4 = make_float4(0.f, 0.f, 0.f, 0.f);
    if (flags & 1) b4 = *(const float4*)(bias + ccol);
    #pragma unroll
    for (int i = 0; i < 4; ++i) {
        float* cp = C + (size_t)(crow + i) * N + ccol;
        float4 v;
        v.x = acc[i][0] + b4.x; v.y = acc[i][1] + b4.y;
        v.z = acc[i][2] + b4.z; v.w = acc[i][3] + b4.w;
        if (flags & 2) {
            const float4 o = *(const float4*)cp;
            v.x += o.x; v.y += o.y; v.z += o.z; v.w += o.w;
        }
        *(float4*)cp = v;
    }
}

// ------------------------------------------------------------------
// CSR build
// ------------------------------------------------------------------
__global__ void count_deg(const int* __restrict__ ei, int* __restrict__ deg)
{
    int e = blockIdx.x * 256 + threadIdx.x;
    if (e < NE) atomicAdd(&deg[ei[NE + e]], 1);
}

__global__ __launch_bounds__(1024) void scan_kernel(const int* __restrict__ deg,
                                                    int* __restrict__ rowptr)
{
    __shared__ int s[1024];
    const int t = threadIdx.x;
    const int base = t * 7;
    int loc[7];
    int sum = 0;
    #pragma unroll
    for (int i = 0; i < 7; ++i) {
        int idx = base + i;
        int v = (idx < NN) ? deg[idx] : 0;
        loc[i] = v; sum += v;
    }
    s[t] = sum;
    __syncthreads();
    for (int off = 1; off < 1024; off <<= 1) {
        int v = (t >= off) ? s[t - off] : 0;
        __syncthreads();
        s[t] += v;
        __syncthreads();
    }
    int running = s[t] - sum;
    #pragma unroll
    for (int i = 0; i < 7; ++i) {
        int idx = base + i;
        if (idx <= NN) rowptr[idx] = running;
        if (idx < NN) running += loc[i];
    }
}

__global__ void fill_csr(const int* __restrict__ ei, const int* __restrict__ rowptr,
                         int* __restrict__ fillctr, int* __restrict__ elist)
{
    int e = blockIdx.x * 256 + threadIdx.x;
    if (e >= NE) return;
    int d = ei[NE + e];
    int pos = atomicAdd(&fillctr[d], 1);
    elist[rowptr[d] + pos] = e;
}

__global__ void sort_csr(const int* __restrict__ rowptr, int* __restrict__ elist)
{
    int n = blockIdx.x * 256 + threadIdx.x;
    if (n >= NN) return;
    int s0 = rowptr[n], s1 = rowptr[n + 1];
    for (int i = s0 + 1; i < s1; ++i) {
        int v = elist[i];
        int j = i - 1;
        while (j >= s0 && elist[j] > v) { elist[j + 1] = elist[j]; --j; }
        elist[j + 1] = v;
    }
}

// ------------------------------------------------------------------
// conversions / weight prep
// ------------------------------------------------------------------
__global__ void cvt_pad_bf16(const float* __restrict__ src, __hip_bfloat16* __restrict__ dst,
                             int relu)
{
    size_t i = (size_t)(blockIdx.x * 256 + threadIdx.x) * 4;
    int row = (int)(i >> 11);
    float4 v = make_float4(0.f, 0.f, 0.f, 0.f);
    if (row < NN) v = *(const float4*)&src[i];
    if (relu) {
        v.x = fmaxf(v.x, 0.f); v.y = fmaxf(v.y, 0.f);
        v.z = fmaxf(v.z, 0.f); v.w = fmaxf(v.w, 0.f);
    }
    dst[i + 0] = __float2bfloat16(v.x);
    dst[i + 1] = __float2bfloat16(v.y);
    dst[i + 2] = __float2bfloat16(v.z);
    dst[i + 3] = __float2bfloat16(v.w);
}

__global__ __launch_bounds__(256) void transpose_cvt(const float* __restrict__ W,
                                                     __hip_bfloat16* __restrict__ Bt,
                                                     int K, int N)
{
    __shared__ float t[32][33];
    int kb = blockIdx.y * 32, nb = blockIdx.x * 32;
    int tx = threadIdx.x & 31, ty = threadIdx.x >> 5;
    #pragma unroll
    for (int i = 0; i < 32; i += 8)
        t[ty + i][tx] = W[(size_t)(kb + ty + i) * N + nb + tx];
    __syncthreads();
    #pragma unroll
    for (int i = 0; i < 32; i += 8)
        Bt[(size_t)(nb + ty + i) * K + kb + tx] = __float2bfloat16(t[tx][ty + i]);
}

__global__ void build_bcat(const float* __restrict__ q1b, const float* __restrict__ k1b,
                           const float* __restrict__ v1b, const float* __restrict__ s1b,
                           float* __restrict__ bcat)
{
    int i = blockIdx.x * 256 + threadIdx.x;
    if (i >= 4 * KDIM) return;
    int seg = i >> 11, j = i & 2047;
    const float* b = (seg == 0) ? q1b : (seg == 1) ? k1b : (seg == 2) ? v1b : s1b;
    bcat[i] = b[j];
}

__global__ void build_w1pp(const float* __restrict__ e1w, __hip_bfloat16* __restrict__ w1pp)
{
    int idx = blockIdx.x * 256 + threadIdx.x;
    int p = idx >> 11, j = idx & 2047;
    float v = ((j >> 10) == (p >> 6)) ? e1w[(size_t)(p & 63) * KDIM + j] : 0.f;
    w1pp[idx] = __float2bfloat16(v);
}

__global__ void build_w1ppT(const float* __restrict__ e1w, __hip_bfloat16* __restrict__ w1ppT)
{
    int idx = blockIdx.x * 256 + threadIdx.x;
    int n = idx >> 7, k = idx & 127;
    float v = ((n >> 10) == (k >> 6)) ? e1w[(size_t)(k & 63) * KDIM + n] : 0.f;
    w1ppT[idx] = __float2bfloat16(v);
}

__global__ void build_w2t(const float* __restrict__ qw, const float* __restrict__ kw,
                          const float* __restrict__ vw, const float* __restrict__ sw,
                          const float* __restrict__ qb, const float* __restrict__ kb,
                          const float* __restrict__ vb, const float* __restrict__ sb,
                          __hip_bfloat16* __restrict__ w2t, float* __restrict__ b2)
{
    int idx = blockIdx.x * 256 + threadIdx.x;
    int c = idx >> 11, d = idx & 2047;
    int g = c >> 6, j = c & 63;
    const float* w = (g == 0) ? qw : (g == 1) ? kw : (g == 2) ? vw : sw;
    w2t[idx] = __float2bfloat16(w[(size_t)d * 64 + j]);
    if (d == 0) {
        const float* b = (g == 0) ? qb : (g == 1) ? kb : (g == 2) ? vb : sb;
        b2[c] = b[j];
    }
}

// ------------------------------------------------------------------
// edge kernels (CSR slot order: alpha arrays indexed by slot i)
// ------------------------------------------------------------------
__global__ __launch_bounds__(256) void alpha1_kernel(
    const __hip_bfloat16* __restrict__ q1b, const __hip_bfloat16* __restrict__ k1b,
    const float* __restrict__ P1, const float* __restrict__ ea,
    const int* __restrict__ ei, const int* __restrict__ elist,
    float* __restrict__ alpha)
{
    int i = blockIdx.x * 4 + (threadIdx.x >> 6);
    int lane = threadIdx.x & 63;
    int e = elist[i];
    int src = ei[e], dst = ei[NE + e];
    float eaj = ea[(size_t)e * 64 + lane];
    #pragma unroll
    for (int h = 0; h < 2; ++h) {
        const __hip_bfloat16* qh = q1b + (size_t)dst * HC1 + h * 1024 + lane * 16;
        const __hip_bfloat16* kh = k1b + (size_t)src * HC1 + h * 1024 + lane * 16;
        bhalf8 qa = *(const bhalf8*)qh, qc = *(const bhalf8*)(qh + 8);
        bhalf8 ka = *(const bhalf8*)kh, kc = *(const bhalf8*)(kh + 8);
        float s = 0.f;
        #pragma unroll
        for (int j = 0; j < 8; ++j) s += bf2f(qa[j]) * bf2f(ka[j]);
        #pragma unroll
        for (int j = 0; j < 8; ++j) s += bf2f(qc[j]) * bf2f(kc[j]);
        s += eaj * P1[(size_t)dst * 128 + h * 64 + lane];
        #pragma unroll
        for (int off = 32; off; off >>= 1) s += __shfl_xor(s, off);
        if (lane == 0) alpha[(size_t)i * 2 + h] = s * 0.03125f;
    }
}

__global__ void softmax_kernel(const int* __restrict__ rowptr,
                               float* __restrict__ alpha, int H)
{
    int n = blockIdx.x * 256 + threadIdx.x;
    if (n >= NN) return;
    int s0 = rowptr[n], s1 = rowptr[n + 1];
    for (int h = 0; h < H; ++h) {
        float m = -1e30f;
        for (int i = s0; i < s1; ++i)
            m = fmaxf(m, alpha[(size_t)i * H + h]);
        float ssum = 0.f;
        for (int i = s0; i < s1; ++i) {
            float ex = __expf(alpha[(size_t)i * H + h] - m);
            alpha[(size_t)i * H + h] = ex;
            ssum += ex;
        }
        float inv = 1.f / (ssum + 1e-16f);
        for (int i = s0; i < s1; ++i)
            alpha[(size_t)i * H + h] *= inv;
    }
}

__global__ __launch_bounds__(128) void r1_kernel(
    const int* __restrict__ rowptr, const int* __restrict__ elist,
    const float* __restrict__ attn, const float* __restrict__ ea,
    __hip_bfloat16* __restrict__ R1)
{
    int n = blockIdx.x;
    int p = threadIdx.x;
    int h = p >> 6, j = p & 63;
    int s0 = rowptr[n], s1 = rowptr[n + 1];
    float r = 0.f;
    for (int i = s0; i < s1; ++i) {
        int e = elist[i];
        r += attn[(size_t)i * 2 + h] * ea[(size_t)e * 64 + j];
    }
    R1[(size_t)n * 128 + p] = __float2bfloat16(r);
}

__global__ __launch_bounds__(256) void agg1_kernel(
    const int* __restrict__ rowptr, const int* __restrict__ elist,
    const int* __restrict__ ei, const float* __restrict__ attn,
    const __hip_bfloat16* __restrict__ v1b, float* __restrict__ h1)
{
    int n = blockIdx.x;
    int c0 = threadIdx.x * 8;
    int h = c0 >> 10;
    int s0 = rowptr[n], s1 = rowptr[n + 1];
    float acc[8];
    const float4 p0 = *(const float4*)&h1[(size_t)n * HC1 + c0];
    const float4 p1 = *(const float4*)&h1[(size_t)n * HC1 + c0 + 4];
    acc[0] = p0.x; acc[1] = p0.y; acc[2] = p0.z; acc[3] = p0.w;
    acc[4] = p1.x; acc[5] = p1.y; acc[6] = p1.z; acc[7] = p1.w;
    for (int i = s0; i < s1; ++i) {
        float at = attn[(size_t)i * 2 + h];
        bhalf8 v = *(const bhalf8*)&v1b[(size_t)ei[elist[i]] * HC1 + c0];
        #pragma unroll
        for (int j = 0; j < 8; ++j) acc[j] += at * bf2f(v[j]);
    }
    float4 o0 = make_float4(acc[0], acc[1], acc[2], acc[3]);
    float4 o1 = make_float4(acc[4], acc[5], acc[6], acc[7]);
    *(float4*)&h1[(size_t)n * HC1 + c0] = o0;
    *(float4*)&h1[(size_t)n * HC1 + c0 + 4] = o1;
}

__global__ __launch_bounds__(256) void alpha2_kernel(
    const float* __restrict__ qkvs2, const float* __restrict__ E2,
    const int* __restrict__ ei, const int* __restrict__ elist,
    float* __restrict__ alpha2)
{
    int i = blockIdx.x * 4 + (threadIdx.x >> 6);
    int lane = threadIdx.x & 63;
    int e = elist[i];
    int src = ei[e], dst = ei[NE + e];
    float q = qkvs2[(size_t)dst * 256 + lane];
    float k = qkvs2[(size_t)src * 256 + 64 + lane];
    float s = q * (k + E2[(size_t)e * 64 + lane]);
    #pragma unroll
    for (int off = 32; off; off >>= 1) s += __shfl_xor(s, off);
    if (lane == 0) alpha2[i] = s * 0.125f;
}

__global__ __launch_bounds__(64) void agg2_kernel(
    const int* __restrict__ rowptr, const int* __restrict__ elist,
    const int* __restrict__ ei, const float* __restrict__ attn2,
    const float* __restrict__ qkvs2, const float* __restrict__ E2,
    float* __restrict__ out)
{
    int n = blockIdx.x;
    int c = threadIdx.x;
    int s0 = rowptr[n], s1 = rowptr[n + 1];
    float acc = qkvs2[(size_t)n * 256 + 192 + c];
    for (int i = s0; i < s1; ++i) {
        int e = elist[i];
        acc += attn2[i] * (qkvs2[(size_t)ei[e] * 256 + 128 + c] + E2[(size_t)e * 64 + c]);
    }
    out[(size_t)n * 64 + c] = fmaxf(acc, 0.f);
}

// ------------------------------------------------------------------
extern "C" void kernel_launch(void* const* d_in, const int* in_sizes, int n_in,
                              void* d_out, int out_size, void* d_ws, size_t ws_size,
                              hipStream_t stream)
{
    const float* x   = (const float*)d_in[0];
    const int*   ei  = (const int*)d_in[1];
    const float* ea  = (const float*)d_in[2];
    const float* q1w = (const float*)d_in[3];
    const float* q1b = (const float*)d_in[4];
    const float* k1w = (const float*)d_in[5];
    const float* k1b = (const float*)d_in[6];
    const float* v1w = (const float*)d_in[7];
    const float* v1b = (const float*)d_in[8];
    const float* e1w = (const float*)d_in[9];
    const float* s1w = (const float*)d_in[10];
    const float* s1b = (const float*)d_in[11];
    const float* q2w = (const float*)d_in[12];
    const float* q2b = (const float*)d_in[13];
    const float* k2w = (const float*)d_in[14];
    const float* k2b = (const float*)d_in[15];
    const float* v2w = (const float*)d_in[16];
    const float* v2b = (const float*)d_in[17];
    const float* e2w = (const float*)d_in[18];
    const float* s2w = (const float*)d_in[19];
    const float* s2b = (const float*)d_in[20];
    float* out = (float*)d_out;

    char* base = (char*)d_ws;
    size_t off = 0;
    auto alloc = [&](size_t nbytes) {
        size_t o = off; off += (nbytes + 255) & ~(size_t)255; return o;
    };
    const size_t xb_off   = alloc((size_t)MPAD * KDIM * 2);      // bf16 input (reused as h1b)
    const size_t wcat_off = alloc((size_t)4 * KDIM * KDIM * 2);  // fused weights (reused: Cpart+w2t)
    __hip_bfloat16* xb    = (__hip_bfloat16*)(base + xb_off);
    __hip_bfloat16* wcat  = (__hip_bfloat16*)(base + wcat_off);
    __hip_bfloat16* h1b   = xb;                                   // alias (xb dead after gemm256)
    float*          Cpart = (float*)(base + wcat_off);            // alias (wcat dead after gemm256)
    __hip_bfloat16* w2t   = (__hip_bfloat16*)(base + wcat_off + (size_t)29 * 1024 * 1024);

    __hip_bfloat16* q1bb  = (__hip_bfloat16*)(base + alloc((size_t)MPAD * HC1 * 2));
    __hip_bfloat16* k1bb  = (__hip_bfloat16*)(base + alloc((size_t)MPAD * HC1 * 2));
    __hip_bfloat16* v1bb  = (__hip_bfloat16*)(base + alloc((size_t)MPAD * HC1 * 2));
    float*          h1    = (float*)(base + alloc((size_t)MPAD * HC1 * 4));
    float*          bcat  = (float*)(base + alloc((size_t)4 * KDIM * 4));
    float*          P1    = (float*)(base + alloc((size_t)MPAD * 128 * 4));
    __hip_bfloat16* R1b   = (__hip_bfloat16*)(base + alloc((size_t)MPAD * 128 * 2));
    __hip_bfloat16* w1pp  = (__hip_bfloat16*)(base + alloc((size_t)128 * KDIM * 2));
    __hip_bfloat16* w1ppT = (__hip_bfloat16*)(base + alloc((size_t)KDIM * 128 * 2));
    float*          b2    = (float*)(base + alloc(256 * 4));
    float*          qkvs2 = (float*)(base + alloc((size_t)MPAD * 256 * 4));
    float*          E2    = (float*)(base + alloc((size_t)NE * 64 * 4));
    float*          at1   = (float*)(base + alloc((size_t)NE * 2 * 4));
    float*          at2   = (float*)(base + alloc((size_t)NE * 4));
    int* deg    = (int*)(base + alloc((size_t)NN * 4));
    int* fill   = (int*)(base + alloc((size_t)NN * 4));
    int* rowptr = (int*)(base + alloc((size_t)(NN + 1) * 4));
    int* elist  = (int*)(base + alloc((size_t)NE * 4));

    // --- CSR build ---
    hipMemsetAsync(deg, 0, sizeof(int) * 2 * NN, stream);
    count_deg<<<(NE + 255) / 256, 256, 0, stream>>>(ei, deg);
    scan_kernel<<<1, 1024, 0, stream>>>(deg, rowptr);
    fill_csr<<<(NE + 255) / 256, 256, 0, stream>>>(ei, rowptr, fill, elist);
    sort_csr<<<(NN + 255) / 256, 256, 0, stream>>>(rowptr, elist);

    // --- input conversion + fused weight prep ---
    const int cvblk = (MPAD * KDIM / 4) / 256;
    cvt_pad_bf16<<<cvblk, 256, 0, stream>>>(x, xb, 0);
    const dim3 tgrid(KDIM / 32, KDIM / 32);
    transpose_cvt<<<tgrid, 256, 0, stream>>>(q1w, wcat + (size_t)0 * KDIM * KDIM, KDIM, HC1);
    transpose_cvt<<<tgrid, 256, 0, stream>>>(k1w, wcat + (size_t)1 * KDIM * KDIM, KDIM, HC1);
    transpose_cvt<<<tgrid, 256, 0, stream>>>(v1w, wcat + (size_t)2 * KDIM * KDIM, KDIM, HC1);
    transpose_cvt<<<tgrid, 256, 0, stream>>>(s1w, wcat + (size_t)3 * KDIM * KDIM, KDIM, HC1);
    build_bcat<<<(4 * KDIM) / 256, 256, 0, stream>>>(q1b, k1b, v1b, s1b, bcat);

    // --- fused layer-1 projections: one 864-block 256^2 dispatch ---
    gemm256_fused<<<864, 512, 0, stream>>>(xb, wcat, bcat, q1bb, k1bb, v1bb, h1);

    // --- P1 = q1 @ W1p (split-K 4) ---
    build_w1pp<<<(128 * KDIM) / 256, 256, 0, stream>>>(e1w, w1pp);
    build_w1ppT<<<(KDIM * 128) / 256, 256, 0, stream>>>(e1w, w1ppT);
    gemm_bf16<<<dim3(1, MPAD / 128, 4), 256, 0, stream>>>(q1bb, w1pp, nullptr, Cpart, nullptr,
                                                          MPAD, 128, KDIM, 0);
    reduce4<<<(MPAD * 128) / 256, 256, 0, stream>>>(Cpart, (size_t)MPAD * 128, nullptr, 0,
                                                    P1, MPAD * 128);

    // --- attention layer 1 (slot-ordered) ---
    alpha1_kernel<<<NE / 4, 256, 0, stream>>>(q1bb, k1bb, P1, ea, ei, elist, at1);
    softmax_kernel<<<(NN + 255) / 256, 256, 0, stream>>>(rowptr, at1, 2);
    r1_kernel<<<NN, 128, 0, stream>>>(rowptr, elist, at1, ea, R1b);
    agg1_kernel<<<NN, 256, 0, stream>>>(rowptr, elist, ei, at1, v1bb, h1);
    gemm_bf16<<<dim3(HC1 / 128, MPAD / 128), 256, 0, stream>>>(R1b, w1ppT, nullptr, h1, nullptr,
                                                               MPAD, HC1, 128, 2);
    cvt_pad_bf16<<<cvblk, 256, 0, stream>>>(h1, h1b, 1);   // relu + bf16 (into xb alias)

    // --- layer 2 projections (split-K 4) ---
    build_w2t<<<(256 * KDIM) / 256, 256, 0, stream>>>(q2w, k2w, v2w, s2w, q2b, k2b, v2b, s2b,
                                                      w2t, b2);
    gemm_bf16<<<dim3(2, MPAD / 128, 4), 256, 0, stream>>>(h1b, w2t, nullptr, Cpart, nullptr,
                                                          MPAD, 256, KDIM, 0);
    reduce4<<<(MPAD * 256) / 256, 256, 0, stream>>>(Cpart, (size_t)MPAD * 256, b2, 255,
                                                    qkvs2, MPAD * 256);
    gemm_tile<<<dim3(1, NE / 64), 256, 0, stream>>>(ea, e2w, nullptr, E2, NE, 64, 64, 0);

    // --- attention layer 2 (slot-ordered) ---
    alpha2_kernel<<<NE / 4, 256, 0, stream>>>(qkvs2, E2, ei, elist, at2);
    softmax_kernel<<<(NN + 255) / 256, 256, 0, stream>>>(rowptr, at2, 1);
    agg2_kernel<<<NN, 64, 0, stream>>>(rowptr, elist, ei, at2, qkvs2, E2, out);

    (void)in_sizes; (void)n_in; (void)out_size; (void)ws_size;
}

// Round 4
// 627.054 us; speedup vs baseline: 5.7639x; 1.0198x over previous
//
#include <hip/hip_runtime.h>
#include <hip/hip_bf16.h>
#include <cstdint>
#include <cstddef>

#define NN    6720     // nodes
#define MPAD  6912     // 27 * 256 = 54 * 128
#define NE    33600    // edges
#define KDIM  2048
#define HC1   2048

typedef __attribute__((ext_vector_type(8))) short bhalf8;
typedef __attribute__((ext_vector_type(4))) float fx4;

__device__ __forceinline__ float bf2f(short s) {
    union { unsigned int u; float f; } c;
    c.u = ((unsigned int)(unsigned short)s) << 16;
    return c.f;
}

__device__ __forceinline__ void gload16(const __hip_bfloat16* g, void* lds)
{
    __builtin_amdgcn_global_load_lds(
        (const __attribute__((address_space(1))) unsigned int*)g,
        (__attribute__((address_space(3))) unsigned int*)lds,
        16, 0, 0);
}

#define CFENCE asm volatile("" ::: "memory")

// ------------------------------------------------------------------
// 256x256-tile 8-wave fused projection GEMM, BK=32, 4-deep LDS ring,
// counted vmcnt (T3+T4), setprio (T5), XOR-swizzled LDS (T2),
// XCD-swizzled blockIdx (T1).
// A [MPAD x 2048] bf16, Bt [8192 x 2048] bf16 (rows = out cols of q|k|v|s).
// Ring schedule: during tile t (2 phases) stage tile t+3's A then B plane
// (slot (t+3)&3 = (t-1)&3, freed one barrier earlier). Flight ~6 phases.
// Per-tile wait: vmcnt(10) = 5 newer stage-groups in flight; tail 8/4/0.
// LDS plane [256][32] bf16 (64B rows), swizzle: unit ^= (row>>1)&3
// (uniform 8x per 16B chunk = 2 lanes/bank, free).
// ------------------------------------------------------------------
__global__ __launch_bounds__(512, 2) void gemm256_fused(
    const __hip_bfloat16* __restrict__ A,
    const __hip_bfloat16* __restrict__ Bt,
    const float* __restrict__ bcat,
    __hip_bfloat16* __restrict__ oq,
    __hip_bfloat16* __restrict__ ok,
    __hip_bfloat16* __restrict__ ov,
    float* __restrict__ oh)
{
    __shared__ alignas(16) __hip_bfloat16 As[4][256 * 32];
    __shared__ alignas(16) __hip_bfloat16 Bs[4][256 * 32];

    // XCD-aware bijective swizzle: 864 blocks = 8 XCD * 108
    const int bid = blockIdx.x;
    const int wg  = (bid & 7) * 108 + (bid >> 3);
    const int bx  = wg & 31;        // N: 32 tiles of 256
    const int by  = wg >> 5;        // M: 27 tiles of 256

    const int tid  = threadIdx.x;
    const int w    = tid >> 6;       // 0..7
    const int lane = tid & 63;
    const int wr = w >> 2, wc = w & 3;   // 2 x 4 wave grid; wave tile 128x64
    const int rowA = by * 256;
    const int rowB = bx * 256;

    // ---- staging geometry: one gload16 covers 16 rows (64 lanes x 16B).
    // lane writes phys (row = base + lane>>2, unit = lane&3); logical unit
    // = phys ^ ((row>>1)&3) = (lane&3) ^ ((lane>>3)&3) -> pre-swizzled src.
    const int srow = w * 32 + (lane >> 2);
    const int sug  = (((lane & 3) ^ ((lane >> 3) & 3)) << 3);
    const __hip_bfloat16* Ag0 = A  + (size_t)(rowA + srow) * KDIM + sug;
    const __hip_bfloat16* Bg0 = Bt + (size_t)(rowB + srow) * KDIM + sug;

    // ---- fragment read addressing (bytes within a 16KB plane)
    const int ub    = ((((lane >> 4) ^ (lane >> 1)) & 3) << 4);
    const int abyte = ((wr * 128 + (lane & 15)) << 6) + ub;   // + p*4096 + mi*1024
    const int bbyte = ((wc * 64  + (lane & 15)) << 6) + ub;   // + nj*1024

    fx4 acc[8][4] = {};

#define STAGE_A(T)                                                        \
    { char* d_ = (char*)&As[(T) & 3][0] + w * 2048;                       \
      gload16(Ag0 + (size_t)(T) * 32, d_);                                \
      gload16(Ag0 + (size_t)(T) * 32 + 16 * KDIM, d_ + 1024); }
#define STAGE_B(T)                                                        \
    { char* d_ = (char*)&Bs[(T) & 3][0] + w * 2048;                       \
      gload16(Bg0 + (size_t)(T) * 32, d_);                                \
      gload16(Bg0 + (size_t)(T) * 32 + 16 * KDIM, d_ + 1024); }

#define TILE_BODY(T, VMIMM, DOSTAGE)                                      \
    {                                                                     \
        const int slot_ = (T) & 3;                                        \
        if (DOSTAGE) { STAGE_A((T) + 3); }                                \
        asm volatile("s_waitcnt vmcnt(" VMIMM ")" ::: "memory");          \
        __builtin_amdgcn_s_barrier();                                     \
        CFENCE;                                                           \
        const char* ap_ = (const char*)&As[slot_][0];                     \
        const char* bp_ = (const char*)&Bs[slot_][0];                     \
        bhalf8 bq_[4], af_[4];                                            \
        _Pragma("unroll")                                                 \
        for (int nj = 0; nj < 4; ++nj)                                    \
            bq_[nj] = *(const bhalf8*)(bp_ + bbyte + nj * 1024);          \
        _Pragma("unroll")                                                 \
        for (int mi = 0; mi < 4; ++mi)                                    \
            af_[mi] = *(const bhalf8*)(ap_ + abyte + mi * 1024);          \
        __builtin_amdgcn_s_setprio(1);                                    \
        _Pragma("unroll")                                                 \
        for (int mi = 0; mi < 4; ++mi)                                    \
            _Pragma("unroll")                                             \
            for (int nj = 0; nj < 4; ++nj)                                \
                acc[mi][nj] = __builtin_amdgcn_mfma_f32_16x16x32_bf16(    \
                    af_[mi], bq_[nj], acc[mi][nj], 0, 0, 0);              \
        __builtin_amdgcn_s_setprio(0);                                    \
        if (DOSTAGE) { STAGE_B((T) + 3); }                                \
        _Pragma("unroll")                                                 \
        for (int mi = 0; mi < 4; ++mi)                                    \
            af_[mi] = *(const bhalf8*)(ap_ + abyte + 4096 + mi * 1024);   \
        __builtin_amdgcn_s_setprio(1);                                    \
        _Pragma("unroll")                                                 \
        for (int mi = 0; mi < 4; ++mi)                                    \
            _Pragma("unroll")                                             \
            for (int nj = 0; nj < 4; ++nj)                                \
                acc[4 + mi][nj] = __builtin_amdgcn_mfma_f32_16x16x32_bf16(\
                    af_[mi], bq_[nj], acc[4 + mi][nj], 0, 0, 0);          \
        __builtin_amdgcn_s_setprio(0);                                    \
        CFENCE;                                                           \
        __builtin_amdgcn_s_barrier();                                     \
        CFENCE;                                                           \
    }

    const int NT = KDIM / 32;   // 64
    // prologue: stage tiles 0,1,2 (A+B each)
    STAGE_A(0); STAGE_B(0);
    STAGE_A(1); STAGE_B(1);
    STAGE_A(2); STAGE_B(2);

    for (int t = 0; t < NT - 3; ++t) {
        TILE_BODY(t, "10", true);
    }
    TILE_BODY(NT - 3, "8", false);
    TILE_BODY(NT - 2, "4", false);
    TILE_BODY(NT - 1, "0", false);

#undef TILE_BODY
#undef STAGE_A
#undef STAGE_B

    // epilogue: segment by global column
    const int seg = bx >> 3;   // 0:q 1:k 2:v 3:skip(fp32)
    #pragma unroll
    for (int nj = 0; nj < 4; ++nj) {
        const int ccol = rowB + wc * 64 + nj * 16 + (lane & 15);
        const int lcol = ccol & 2047;
        const float bv = bcat[ccol];
        #pragma unroll
        for (int mi = 0; mi < 8; ++mi) {
            const int crow0 = rowA + wr * 128 + mi * 16 + ((lane >> 4) << 2);
            #pragma unroll
            for (int i = 0; i < 4; ++i) {
                const float v = acc[mi][nj][i] + bv;
                const size_t idx = (size_t)(crow0 + i) * 2048 + lcol;
                if (seg == 0)      oq[idx] = __float2bfloat16(v);
                else if (seg == 1) ok[idx] = __float2bfloat16(v);
                else if (seg == 2) ov[idx] = __float2bfloat16(v);
                else               oh[idx] = v;
            }
        }
    }
}

// ------------------------------------------------------------------
// 128x128 bf16 MFMA GEMM (4 waves), optional split-K via blockIdx.z.
// C[M,N] = A[M,K] @ Bt[N,K]^T (+bias)(+=C). z>0 writes C + z*M*N.
// ------------------------------------------------------------------
__global__ __launch_bounds__(256) void gemm_bf16(
    const __hip_bfloat16* __restrict__ A,
    const __hip_bfloat16* __restrict__ Bt,
    const float* __restrict__ bias,
    float* __restrict__ C,
    __hip_bfloat16* __restrict__ Cb,
    int M, int N, int K, int flags)
{
    __shared__ alignas(16) __hip_bfloat16 Asm[128 * 64];
    __shared__ alignas(16) __hip_bfloat16 Bsm[128 * 64];
    const int tid  = threadIdx.x;
    const int w    = tid >> 6;
    const int lane = tid & 63;
    const int wr = w >> 1, wc = w & 1;
    const int rowA = blockIdx.y * 128;
    const int rowB = blockIdx.x * 128;
    const int klen = K / gridDim.z;
    const int kbeg = blockIdx.z * klen;

    const int srow = w * 32 + (lane >> 3);
    const int ug8  = ((lane & 7) ^ (lane >> 3)) << 3;
    const __hip_bfloat16* Ag = A  + (size_t)(rowA + srow) * K + ug8;
    const __hip_bfloat16* Bg = Bt + (size_t)(rowB + srow) * K + ug8;
    char* AsBase = (char*)Asm + w * 4096;
    char* BsBase = (char*)Bsm + w * 4096;

    fx4 acc[4][4] = {};

    const int fra = wr * 64 + (lane & 15);
    const int frb = wc * 64 + (lane & 15);
    const int kb  = (lane >> 4) << 4;
    const int swz = (lane & 7) << 4;

    for (int k0 = kbeg; k0 < kbeg + klen; k0 += 64) {
        __syncthreads();
        #pragma unroll
        for (int j = 0; j < 4; ++j) {
            gload16(Ag + (size_t)j * 8 * K + k0, AsBase + j * 1024);
            gload16(Bg + (size_t)j * 8 * K + k0, BsBase + j * 1024);
        }
        __syncthreads();
        #pragma unroll
        for (int kk = 0; kk < 2; ++kk) {
            const int cb = kk * 64 + kb;
            bhalf8 af[4], bfr[4];
            #pragma unroll
            for (int mi = 0; mi < 4; ++mi)
                af[mi] = *(const bhalf8*)((const char*)Asm + (fra + mi * 16) * 128 + (cb ^ swz));
            #pragma unroll
            for (int nj = 0; nj < 4; ++nj)
                bfr[nj] = *(const bhalf8*)((const char*)Bsm + (frb + nj * 16) * 128 + (cb ^ swz));
            #pragma unroll
            for (int mi = 0; mi < 4; ++mi)
                #pragma unroll
                for (int nj = 0; nj < 4; ++nj)
                    acc[mi][nj] = __builtin_amdgcn_mfma_f32_16x16x32_bf16(
                        af[mi], bfr[nj], acc[mi][nj], 0, 0, 0);
        }
    }

    float* Cz = C ? C + (size_t)blockIdx.z * ((size_t)M * N) : nullptr;
    #pragma unroll
    for (int nj = 0; nj < 4; ++nj) {
        const int ccol = rowB + wc * 64 + nj * 16 + (lane & 15);
        const float bv = (flags & 1) ? bias[ccol] : 0.f;
        #pragma unroll
        for (int mi = 0; mi < 4; ++mi) {
            const int crow0 = rowA + wr * 64 + mi * 16 + ((lane >> 4) << 2);
            #pragma unroll
            for (int i = 0; i < 4; ++i) {
                size_t idx = (size_t)(crow0 + i) * N + ccol;
                float v = acc[mi][nj][i] + bv;
                if (flags & 2) v += Cz[idx];
                if (Cz) Cz[idx] = v;
                if (Cb) Cb[idx] = __float2bfloat16(v);
            }
        }
    }
}

// dst[i] = sum_z parts[z*stride + i] (+ bias[i & colmask])
__global__ void reduce4(const float* __restrict__ parts, size_t stride,
                        const float* __restrict__ bias, int colmask,
                        float* __restrict__ dst, int n)
{
    int i = blockIdx.x * 256 + threadIdx.x;
    if (i >= n) return;
    float v = parts[i] + parts[stride + i] + parts[2 * stride + i] + parts[3 * stride + i];
    if (bias) v += bias[i & colmask];
    dst[i] = v;
}

// ------------------------------------------------------------------
// fp32 tiled GEMM (kept for tiny E2 = ea @ e2w)
// ------------------------------------------------------------------
__global__ __launch_bounds__(256) void gemm_tile(
    const float* __restrict__ A, const float* __restrict__ B,
    const float* __restrict__ bias, float* __restrict__ C,
    int M, int N, int K, int flags)
{
    __shared__ float As[16][68];
    __shared__ float Bs[16][64];
    const int tid = threadIdx.x;
    const int bx = blockIdx.x, by = blockIdx.y;
    const int tx = tid & 15, ty = tid >> 4;
    const int arow = tid >> 2, acol = (tid & 3) << 2;
    const int brow = tid >> 4, bcol = (tid & 15) << 2;
    const float* Ag = A + (size_t)(by * 64 + arow) * K + acol;
    const float* Bg = B + (size_t)brow * N + bx * 64 + bcol;
    float acc[4][4] = {};
    for (int k0 = 0; k0 < K; k0 += 16) {
        const float4 av = *(const float4*)(Ag + k0);
        const float4 bv = *(const float4*)(Bg + (size_t)k0 * N);
        __syncthreads();
        As[acol + 0][arow] = av.x;
        As[acol + 1][arow] = av.y;
        As[acol + 2][arow] = av.z;
        As[acol + 3][arow] = av.w;
        *(float4*)&Bs[brow][bcol] = bv;
        __syncthreads();
        #pragma unroll
        for (int kk = 0; kk < 16; ++kk) {
            const float4 a4 = *(const float4*)&As[kk][ty << 2];
            const float4 b4 = *(const float4*)&Bs[kk][tx << 2];
            const float a[4] = {a4.x, a4.y, a4.z, a4.w};
            const float b[4] = {b4.x, b4.y, b4.z, b4.w};
            #pragma unroll
            for (int i = 0; i < 4; ++i)
                #pragma unroll
                for (int j = 0; j < 4; ++j)
                    acc[i][j] += a[i] * b[j];
        }
    }
    const int crow = by * 64 + (ty << 2);
    const int ccol = bx * 64 + (tx << 2);
    float4 b4 = make_float4(0.f, 0.f, 0.f, 0.f);
    if (flags & 1) b4 = *(const float4*)(bias + ccol);
    #pragma unroll
    for (int i = 0; i < 4; ++i) {
        float* cp = C + (size_t)(crow + i) * N + ccol;
        float4 v;
        v.x = acc[i][0] + b4.x; v.y = acc[i][1] + b4.y;
        v.z = acc[i][2] + b4.z; v.w = acc[i][3] + b4.w;
        if (flags & 2) {
            const float4 o = *(const float4*)cp;
            v.x += o.x; v.y += o.y; v.z += o.z; v.w += o.w;
        }
        *(float4*)cp = v;
    }
}

// ------------------------------------------------------------------
// CSR build
// ------------------------------------------------------------------
__global__ void count_deg(const int* __restrict__ ei, int* __restrict__ deg)
{
    int e = blockIdx.x * 256 + threadIdx.x;
    if (e < NE) atomicAdd(&deg[ei[NE + e]], 1);
}

__global__ __launch_bounds__(1024) void scan_kernel(const int* __restrict__ deg,
                                                    int* __restrict__ rowptr)
{
    __shared__ int s[1024];
    const int t = threadIdx.x;
    const int base = t * 7;
    int loc[7];
    int sum = 0;
    #pragma unroll
    for (int i = 0; i < 7; ++i) {
        int idx = base + i;
        int v = (idx < NN) ? deg[idx] : 0;
        loc[i] = v; sum += v;
    }
    s[t] = sum;
    __syncthreads();
    for (int off = 1; off < 1024; off <<= 1) {
        int v = (t >= off) ? s[t - off] : 0;
        __syncthreads();
        s[t] += v;
        __syncthreads();
    }
    int running = s[t] - sum;
    #pragma unroll
    for (int i = 0; i < 7; ++i) {
        int idx = base + i;
        if (idx <= NN) rowptr[idx] = running;
        if (idx < NN) running += loc[i];
    }
}

__global__ void fill_csr(const int* __restrict__ ei, const int* __restrict__ rowptr,
                         int* __restrict__ fillctr, int* __restrict__ elist)
{
    int e = blockIdx.x * 256 + threadIdx.x;
    if (e >= NE) return;
    int d = ei[NE + e];
    int pos = atomicAdd(&fillctr[d], 1);
    elist[rowptr[d] + pos] = e;
}

__global__ void sort_csr(const int* __restrict__ rowptr, int* __restrict__ elist)
{
    int n = blockIdx.x * 256 + threadIdx.x;
    if (n >= NN) return;
    int s0 = rowptr[n], s1 = rowptr[n + 1];
    for (int i = s0 + 1; i < s1; ++i) {
        int v = elist[i];
        int j = i - 1;
        while (j >= s0 && elist[j] > v) { elist[j + 1] = elist[j]; --j; }
        elist[j + 1] = v;
    }
}

// ------------------------------------------------------------------
// conversions / weight prep
// ------------------------------------------------------------------
__global__ void cvt_pad_bf16(const float* __restrict__ src, __hip_bfloat16* __restrict__ dst,
                             int relu)
{
    size_t i = (size_t)(blockIdx.x * 256 + threadIdx.x) * 4;
    int row = (int)(i >> 11);
    float4 v = make_float4(0.f, 0.f, 0.f, 0.f);
    if (row < NN) v = *(const float4*)&src[i];
    if (relu) {
        v.x = fmaxf(v.x, 0.f); v.y = fmaxf(v.y, 0.f);
        v.z = fmaxf(v.z, 0.f); v.w = fmaxf(v.w, 0.f);
    }
    dst[i + 0] = __float2bfloat16(v.x);
    dst[i + 1] = __float2bfloat16(v.y);
    dst[i + 2] = __float2bfloat16(v.z);
    dst[i + 3] = __float2bfloat16(v.w);
}

__global__ __launch_bounds__(256) void transpose_cvt(const float* __restrict__ W,
                                                     __hip_bfloat16* __restrict__ Bt,
                                                     int K, int N)
{
    __shared__ float t[32][33];
    int kb = blockIdx.y * 32, nb = blockIdx.x * 32;
    int tx = threadIdx.x & 31, ty = threadIdx.x >> 5;
    #pragma unroll
    for (int i = 0; i < 32; i += 8)
        t[ty + i][tx] = W[(size_t)(kb + ty + i) * N + nb + tx];
    __syncthreads();
    #pragma unroll
    for (int i = 0; i < 32; i += 8)
        Bt[(size_t)(nb + ty + i) * K + kb + tx] = __float2bfloat16(t[tx][ty + i]);
}

__global__ void build_bcat(const float* __restrict__ q1b, const float* __restrict__ k1b,
                           const float* __restrict__ v1b, const float* __restrict__ s1b,
                           float* __restrict__ bcat)
{
    int i = blockIdx.x * 256 + threadIdx.x;
    if (i >= 4 * KDIM) return;
    int seg = i >> 11, j = i & 2047;
    const float* b = (seg == 0) ? q1b : (seg == 1) ? k1b : (seg == 2) ? v1b : s1b;
    bcat[i] = b[j];
}

__global__ void build_w1pp(const float* __restrict__ e1w, __hip_bfloat16* __restrict__ w1pp)
{
    int idx = blockIdx.x * 256 + threadIdx.x;
    int p = idx >> 11, j = idx & 2047;
    float v = ((j >> 10) == (p >> 6)) ? e1w[(size_t)(p & 63) * KDIM + j] : 0.f;
    w1pp[idx] = __float2bfloat16(v);
}

__global__ void build_w1ppT(const float* __restrict__ e1w, __hip_bfloat16* __restrict__ w1ppT)
{
    int idx = blockIdx.x * 256 + threadIdx.x;
    int n = idx >> 7, k = idx & 127;
    float v = ((n >> 10) == (k >> 6)) ? e1w[(size_t)(k & 63) * KDIM + n] : 0.f;
    w1ppT[idx] = __float2bfloat16(v);
}

__global__ void build_w2t(const float* __restrict__ qw, const float* __restrict__ kw,
                          const float* __restrict__ vw, const float* __restrict__ sw,
                          const float* __restrict__ qb, const float* __restrict__ kb,
                          const float* __restrict__ vb, const float* __restrict__ sb,
                          __hip_bfloat16* __restrict__ w2t, float* __restrict__ b2)
{
    int idx = blockIdx.x * 256 + threadIdx.x;
    int c = idx >> 11, d = idx & 2047;
    int g = c >> 6, j = c & 63;
    const float* w = (g == 0) ? qw : (g == 1) ? kw : (g == 2) ? vw : sw;
    w2t[idx] = __float2bfloat16(w[(size_t)d * 64 + j]);
    if (d == 0) {
        const float* b = (g == 0) ? qb : (g == 1) ? kb : (g == 2) ? vb : sb;
        b2[c] = b[j];
    }
}

// ------------------------------------------------------------------
// edge kernels (CSR slot order: alpha arrays indexed by slot i)
// ------------------------------------------------------------------
__global__ __launch_bounds__(256) void alpha1_kernel(
    const __hip_bfloat16* __restrict__ q1b, const __hip_bfloat16* __restrict__ k1b,
    const float* __restrict__ P1, const float* __restrict__ ea,
    const int* __restrict__ ei, const int* __restrict__ elist,
    float* __restrict__ alpha)
{
    int i = blockIdx.x * 4 + (threadIdx.x >> 6);
    int lane = threadIdx.x & 63;
    int e = elist[i];
    int src = ei[e], dst = ei[NE + e];
    float eaj = ea[(size_t)e * 64 + lane];
    #pragma unroll
    for (int h = 0; h < 2; ++h) {
        const __hip_bfloat16* qh = q1b + (size_t)dst * HC1 + h * 1024 + lane * 16;
        const __hip_bfloat16* kh = k1b + (size_t)src * HC1 + h * 1024 + lane * 16;
        bhalf8 qa = *(const bhalf8*)qh, qc = *(const bhalf8*)(qh + 8);
        bhalf8 ka = *(const bhalf8*)kh, kc = *(const bhalf8*)(kh + 8);
        float s = 0.f;
        #pragma unroll
        for (int j = 0; j < 8; ++j) s += bf2f(qa[j]) * bf2f(ka[j]);
        #pragma unroll
        for (int j = 0; j < 8; ++j) s += bf2f(qc[j]) * bf2f(kc[j]);
        s += eaj * P1[(size_t)dst * 128 + h * 64 + lane];
        #pragma unroll
        for (int off = 32; off; off >>= 1) s += __shfl_xor(s, off);
        if (lane == 0) alpha[(size_t)i * 2 + h] = s * 0.03125f;
    }
}

__global__ void softmax_kernel(const int* __restrict__ rowptr,
                               float* __restrict__ alpha, int H)
{
    int n = blockIdx.x * 256 + threadIdx.x;
    if (n >= NN) return;
    int s0 = rowptr[n], s1 = rowptr[n + 1];
    for (int h = 0; h < H; ++h) {
        float m = -1e30f;
        for (int i = s0; i < s1; ++i)
            m = fmaxf(m, alpha[(size_t)i * H + h]);
        float ssum = 0.f;
        for (int i = s0; i < s1; ++i) {
            float ex = __expf(alpha[(size_t)i * H + h] - m);
            alpha[(size_t)i * H + h] = ex;
            ssum += ex;
        }
        float inv = 1.f / (ssum + 1e-16f);
        for (int i = s0; i < s1; ++i)
            alpha[(size_t)i * H + h] *= inv;
    }
}

__global__ __launch_bounds__(128) void r1_kernel(
    const int* __restrict__ rowptr, const int* __restrict__ elist,
    const float* __restrict__ attn, const float* __restrict__ ea,
    __hip_bfloat16* __restrict__ R1)
{
    int n = blockIdx.x;
    int p = threadIdx.x;
    int h = p >> 6, j = p & 63;
    int s0 = rowptr[n], s1 = rowptr[n + 1];
    float r = 0.f;
    for (int i = s0; i < s1; ++i) {
        int e = elist[i];
        r += attn[(size_t)i * 2 + h] * ea[(size_t)e * 64 + j];
    }
    R1[(size_t)n * 128 + p] = __float2bfloat16(r);
}

__global__ __launch_bounds__(256) void agg1_kernel(
    const int* __restrict__ rowptr, const int* __restrict__ elist,
    const int* __restrict__ ei, const float* __restrict__ attn,
    const __hip_bfloat16* __restrict__ v1b, float* __restrict__ h1)
{
    int n = blockIdx.x;
    int c0 = threadIdx.x * 8;
    int h = c0 >> 10;
    int s0 = rowptr[n], s1 = rowptr[n + 1];
    float acc[8];
    const float4 p0 = *(const float4*)&h1[(size_t)n * HC1 + c0];
    const float4 p1 = *(const float4*)&h1[(size_t)n * HC1 + c0 + 4];
    acc[0] = p0.x; acc[1] = p0.y; acc[2] = p0.z; acc[3] = p0.w;
    acc[4] = p1.x; acc[5] = p1.y; acc[6] = p1.z; acc[7] = p1.w;
    for (int i = s0; i < s1; ++i) {
        float at = attn[(size_t)i * 2 + h];
        bhalf8 v = *(const bhalf8*)&v1b[(size_t)ei[elist[i]] * HC1 + c0];
        #pragma unroll
        for (int j = 0; j < 8; ++j) acc[j] += at * bf2f(v[j]);
    }
    float4 o0 = make_float4(acc[0], acc[1], acc[2], acc[3]);
    float4 o1 = make_float4(acc[4], acc[5], acc[6], acc[7]);
    *(float4*)&h1[(size_t)n * HC1 + c0] = o0;
    *(float4*)&h1[(size_t)n * HC1 + c0 + 4] = o1;
}

__global__ __launch_bounds__(256) void alpha2_kernel(
    const float* __restrict__ qkvs2, const float* __restrict__ E2,
    const int* __restrict__ ei, const int* __restrict__ elist,
    float* __restrict__ alpha2)
{
    int i = blockIdx.x * 4 + (threadIdx.x >> 6);
    int lane = threadIdx.x & 63;
    int e = elist[i];
    int src = ei[e], dst = ei[NE + e];
    float q = qkvs2[(size_t)dst * 256 + lane];
    float k = qkvs2[(size_t)src * 256 + 64 + lane];
    float s = q * (k + E2[(size_t)e * 64 + lane]);
    #pragma unroll
    for (int off = 32; off; off >>= 1) s += __shfl_xor(s, off);
    if (lane == 0) alpha2[i] = s * 0.125f;
}

__global__ __launch_bounds__(64) void agg2_kernel(
    const int* __restrict__ rowptr, const int* __restrict__ elist,
    const int* __restrict__ ei, const float* __restrict__ attn2,
    const float* __restrict__ qkvs2, const float* __restrict__ E2,
    float* __restrict__ out)
{
    int n = blockIdx.x;
    int c = threadIdx.x;
    int s0 = rowptr[n], s1 = rowptr[n + 1];
    float acc = qkvs2[(size_t)n * 256 + 192 + c];
    for (int i = s0; i < s1; ++i) {
        int e = elist[i];
        acc += attn2[i] * (qkvs2[(size_t)ei[e] * 256 + 128 + c] + E2[(size_t)e * 64 + c]);
    }
    out[(size_t)n * 64 + c] = fmaxf(acc, 0.f);
}

// ------------------------------------------------------------------
extern "C" void kernel_launch(void* const* d_in, const int* in_sizes, int n_in,
                              void* d_out, int out_size, void* d_ws, size_t ws_size,
                              hipStream_t stream)
{
    const float* x   = (const float*)d_in[0];
    const int*   ei  = (const int*)d_in[1];
    const float* ea  = (const float*)d_in[2];
    const float* q1w = (const float*)d_in[3];
    const float* q1b = (const float*)d_in[4];
    const float* k1w = (const float*)d_in[5];
    const float* k1b = (const float*)d_in[6];
    const float* v1w = (const float*)d_in[7];
    const float* v1b = (const float*)d_in[8];
    const float* e1w = (const float*)d_in[9];
    const float* s1w = (const float*)d_in[10];
    const float* s1b = (const float*)d_in[11];
    const float* q2w = (const float*)d_in[12];
    const float* q2b = (const float*)d_in[13];
    const float* k2w = (const float*)d_in[14];
    const float* k2b = (const float*)d_in[15];
    const float* v2w = (const float*)d_in[16];
    const float* v2b = (const float*)d_in[17];
    const float* e2w = (const float*)d_in[18];
    const float* s2w = (const float*)d_in[19];
    const float* s2b = (const float*)d_in[20];
    float* out = (float*)d_out;

    char* base = (char*)d_ws;
    size_t off = 0;
    auto alloc = [&](size_t nbytes) {
        size_t o = off; off += (nbytes + 255) & ~(size_t)255; return o;
    };
    const size_t xb_off   = alloc((size_t)MPAD * KDIM * 2);      // bf16 input (reused as h1b)
    const size_t wcat_off = alloc((size_t)4 * KDIM * KDIM * 2);  // fused weights (reused: Cpart+w2t)
    __hip_bfloat16* xb    = (__hip_bfloat16*)(base + xb_off);
    __hip_bfloat16* wcat  = (__hip_bfloat16*)(base + wcat_off);
    __hip_bfloat16* h1b   = xb;                                   // alias (xb dead after gemm256)
    float*          Cpart = (float*)(base + wcat_off);            // alias (wcat dead after gemm256)
    __hip_bfloat16* w2t   = (__hip_bfloat16*)(base + wcat_off + (size_t)29 * 1024 * 1024);

    __hip_bfloat16* q1bb  = (__hip_bfloat16*)(base + alloc((size_t)MPAD * HC1 * 2));
    __hip_bfloat16* k1bb  = (__hip_bfloat16*)(base + alloc((size_t)MPAD * HC1 * 2));
    __hip_bfloat16* v1bb  = (__hip_bfloat16*)(base + alloc((size_t)MPAD * HC1 * 2));
    float*          h1    = (float*)(base + alloc((size_t)MPAD * HC1 * 4));
    float*          bcat  = (float*)(base + alloc((size_t)4 * KDIM * 4));
    float*          P1    = (float*)(base + alloc((size_t)MPAD * 128 * 4));
    __hip_bfloat16* R1b   = (__hip_bfloat16*)(base + alloc((size_t)MPAD * 128 * 2));
    __hip_bfloat16* w1pp  = (__hip_bfloat16*)(base + alloc((size_t)128 * KDIM * 2));
    __hip_bfloat16* w1ppT = (__hip_bfloat16*)(base + alloc((size_t)KDIM * 128 * 2));
    float*          b2    = (float*)(base + alloc(256 * 4));
    float*          qkvs2 = (float*)(base + alloc((size_t)MPAD * 256 * 4));
    float*          E2    = (float*)(base + alloc((size_t)NE * 64 * 4));
    float*          at1   = (float*)(base + alloc((size_t)NE * 2 * 4));
    float*          at2   = (float*)(base + alloc((size_t)NE * 4));
    int* deg    = (int*)(base + alloc((size_t)NN * 4));
    int* fill   = (int*)(base + alloc((size_t)NN * 4));
    int* rowptr = (int*)(base + alloc((size_t)(NN + 1) * 4));
    int* elist  = (int*)(base + alloc((size_t)NE * 4));

    // --- CSR build ---
    hipMemsetAsync(deg, 0, sizeof(int) * 2 * NN, stream);
    count_deg<<<(NE + 255) / 256, 256, 0, stream>>>(ei, deg);
    scan_kernel<<<1, 1024, 0, stream>>>(deg, rowptr);
    fill_csr<<<(NE + 255) / 256, 256, 0, stream>>>(ei, rowptr, fill, elist);
    sort_csr<<<(NN + 255) / 256, 256, 0, stream>>>(rowptr, elist);

    // --- input conversion + fused weight prep ---
    const int cvblk = (MPAD * KDIM / 4) / 256;
    cvt_pad_bf16<<<cvblk, 256, 0, stream>>>(x, xb, 0);
    const dim3 tgrid(KDIM / 32, KDIM / 32);
    transpose_cvt<<<tgrid, 256, 0, stream>>>(q1w, wcat + (size_t)0 * KDIM * KDIM, KDIM, HC1);
    transpose_cvt<<<tgrid, 256, 0, stream>>>(k1w, wcat + (size_t)1 * KDIM * KDIM, KDIM, HC1);
    transpose_cvt<<<tgrid, 256, 0, stream>>>(v1w, wcat + (size_t)2 * KDIM * KDIM, KDIM, HC1);
    transpose_cvt<<<tgrid, 256, 0, stream>>>(s1w, wcat + (size_t)3 * KDIM * KDIM, KDIM, HC1);
    build_bcat<<<(4 * KDIM) / 256, 256, 0, stream>>>(q1b, k1b, v1b, s1b, bcat);

    // --- fused layer-1 projections: one 864-block 256^2 dispatch ---
    gemm256_fused<<<864, 512, 0, stream>>>(xb, wcat, bcat, q1bb, k1bb, v1bb, h1);

    // --- P1 = q1 @ W1p (split-K 4) ---
    build_w1pp<<<(128 * KDIM) / 256, 256, 0, stream>>>(e1w, w1pp);
    build_w1ppT<<<(KDIM * 128) / 256, 256, 0, stream>>>(e1w, w1ppT);
    gemm_bf16<<<dim3(1, MPAD / 128, 4), 256, 0, stream>>>(q1bb, w1pp, nullptr, Cpart, nullptr,
                                                          MPAD, 128, KDIM, 0);
    reduce4<<<(MPAD * 128) / 256, 256, 0, stream>>>(Cpart, (size_t)MPAD * 128, nullptr, 0,
                                                    P1, MPAD * 128);

    // --- attention layer 1 (slot-ordered) ---
    alpha1_kernel<<<NE / 4, 256, 0, stream>>>(q1bb, k1bb, P1, ea, ei, elist, at1);
    softmax_kernel<<<(NN + 255) / 256, 256, 0, stream>>>(rowptr, at1, 2);
    r1_kernel<<<NN, 128, 0, stream>>>(rowptr, elist, at1, ea, R1b);
    agg1_kernel<<<NN, 256, 0, stream>>>(rowptr, elist, ei, at1, v1bb, h1);
    gemm_bf16<<<dim3(HC1 / 128, MPAD / 128), 256, 0, stream>>>(R1b, w1ppT, nullptr, h1, nullptr,
                                                               MPAD, HC1, 128, 2);
    cvt_pad_bf16<<<cvblk, 256, 0, stream>>>(h1, h1b, 1);   // relu + bf16 (into xb alias)

    // --- layer 2 projections (split-K 4) ---
    build_w2t<<<(256 * KDIM) / 256, 256, 0, stream>>>(q2w, k2w, v2w, s2w, q2b, k2b, v2b, s2b,
                                                      w2t, b2);
    gemm_bf16<<<dim3(2, MPAD / 128, 4), 256, 0, stream>>>(h1b, w2t, nullptr, Cpart, nullptr,
                                                          MPAD, 256, KDIM, 0);
    reduce4<<<(MPAD * 256) / 256, 256, 0, stream>>>(Cpart, (size_t)MPAD * 256, b2, 255,
                                                    qkvs2, MPAD * 256);
    gemm_tile<<<dim3(1, NE / 64), 256, 0, stream>>>(ea, e2w, nullptr, E2, NE, 64, 64, 0);

    // --- attention layer 2 (slot-ordered) ---
    alpha2_kernel<<<NE / 4, 256, 0, stream>>>(qkvs2, E2, ei, elist, at2);
    softmax_kernel<<<(NN + 255) / 256, 256, 0, stream>>>(rowptr, at2, 1);
    agg2_kernel<<<NN, 64, 0, stream>>>(rowptr, elist, ei, at2, qkvs2, E2, out);

    (void)in_sizes; (void)n_in; (void)out_size; (void)ws_size;
}

// Round 5
// 584.256 us; speedup vs baseline: 6.1862x; 1.0733x over previous
//
#include <hip/hip_runtime.h>
#include <hip/hip_bf16.h>
#include <cstdint>
#include <cstddef>

#define NN    6720     // nodes
#define MPAD  6912     // 54 * 128
#define NE    33600    // edges
#define KDIM  2048
#define HC1   2048

typedef __attribute__((ext_vector_type(8))) short bhalf8;
typedef __attribute__((ext_vector_type(4))) float fx4;

__device__ __forceinline__ float bf2f(short s) {
    union { unsigned int u; float f; } c;
    c.u = ((unsigned int)(unsigned short)s) << 16;
    return c.f;
}

__device__ __forceinline__ void gload16(const __hip_bfloat16* g, void* lds)
{
    __builtin_amdgcn_global_load_lds(
        (const __attribute__((address_space(1))) unsigned int*)g,
        (__attribute__((address_space(3))) unsigned int*)lds,
        16, 0, 0);
}

#define CFENCE asm volatile("" ::: "memory")

// ------------------------------------------------------------------
// 128x128-tile 4-wave fused projection GEMM. BK=32, 3-deep LDS ring,
// counted vmcnt, 48KB LDS -> 3 blocks/CU (12 waves/CU TLP).
// A [MPAD x 2048] bf16, Bt [8192 x 2048] bf16 (rows = out cols q|k|v|s).
// Per tile t: stage tile t+2 (4 gload_lds/thread), vmcnt(8), barrier,
// 8 ds_read_b128, 16 MFMA (setprio), barrier. Tail vmcnt 4/0.
// LDS rows are 64B; XOR swizzle unit^=(row>>1)&3 keeps quarter-wave
// ds_read groups conflict-free. Epilogue stages C through LDS so all
// global stores are full 128B lines.
// ------------------------------------------------------------------
__global__ __launch_bounds__(256, 3) void gemm128_fused(
    const __hip_bfloat16* __restrict__ A,
    const __hip_bfloat16* __restrict__ Bt,
    const float* __restrict__ bcat,
    __hip_bfloat16* __restrict__ oq,
    __hip_bfloat16* __restrict__ ok,
    __hip_bfloat16* __restrict__ ov,
    float* __restrict__ oh)
{
    __shared__ alignas(16) char Lds[49152];   // A ring 3x8KB | B ring 3x8KB

    // XCD-aware bijective swizzle: 3456 = 8 XCD * 432; bx fast within XCD
    const int bid = blockIdx.x;
    const int wg  = (bid & 7) * 432 + (bid >> 3);
    const int bx  = wg & 63;    // N: 64 tiles of 128
    const int by  = wg >> 6;    // M: 54 tiles of 128

    const int tid  = threadIdx.x;
    const int w    = tid >> 6;        // 0..3
    const int lane = tid & 63;
    const int wm = w >> 1, wn = w & 1;    // 2x2 waves, wave tile 64x64
    const int rowA = by * 128;
    const int rowB = bx * 128;

    // staging: wave w covers rows w*32..+31 of each 128x32 plane,
    // 2 gloads per operand (16 rows = 1KB each). Pre-swizzled source:
    // LDS(row, phys u) = global unit u ^ ((row>>1)&3).
    const int sug = ((lane & 3) ^ ((lane >> 3) & 3)) << 3;
    const __hip_bfloat16* Ag0 = A  + (size_t)(rowA + w * 32 + (lane >> 2)) * KDIM + sug;
    const __hip_bfloat16* Bg0 = Bt + (size_t)(rowB + w * 32 + (lane >> 2)) * KDIM + sug;

    // fragment read: row = base16 + (lane&15); byte = row*64 + rds
    const int rds = (((lane >> 4) ^ (((lane & 15) >> 1) & 3)) << 4);

    fx4 acc[4][4] = {};

#define STAGE(T)                                                          \
    { const int s_ = (T) % 3; const int k0_ = (T) * 32;                   \
      char* ab_ = Lds + s_ * 8192 + w * 2048;                             \
      char* bb_ = Lds + 24576 + s_ * 8192 + w * 2048;                     \
      gload16(Ag0 + k0_, ab_);                                            \
      gload16(Ag0 + k0_ + 16 * KDIM, ab_ + 1024);                         \
      gload16(Bg0 + k0_, bb_);                                            \
      gload16(Bg0 + k0_ + 16 * KDIM, bb_ + 1024); }

#define TILE(T, VM, DOSTAGE)                                              \
    { if (DOSTAGE) { STAGE((T) + 2); }                                    \
      asm volatile("s_waitcnt vmcnt(" VM ")" ::: "memory");               \
      __builtin_amdgcn_s_barrier(); CFENCE;                               \
      const int s_ = (T) % 3;                                             \
      const char* ap_ = Lds + s_ * 8192;                                  \
      const char* bp_ = Lds + 24576 + s_ * 8192;                          \
      bhalf8 af_[4], bf_[4];                                              \
      _Pragma("unroll")                                                   \
      for (int nj = 0; nj < 4; ++nj)                                      \
          bf_[nj] = *(const bhalf8*)(bp_ + (wn * 64 + nj * 16 + (lane & 15)) * 64 + rds); \
      _Pragma("unroll")                                                   \
      for (int mi = 0; mi < 4; ++mi)                                      \
          af_[mi] = *(const bhalf8*)(ap_ + (wm * 64 + mi * 16 + (lane & 15)) * 64 + rds); \
      __builtin_amdgcn_s_setprio(1);                                      \
      _Pragma("unroll")                                                   \
      for (int mi = 0; mi < 4; ++mi)                                      \
          _Pragma("unroll")                                               \
          for (int nj = 0; nj < 4; ++nj)                                  \
              acc[mi][nj] = __builtin_amdgcn_mfma_f32_16x16x32_bf16(      \
                  af_[mi], bf_[nj], acc[mi][nj], 0, 0, 0);                \
      __builtin_amdgcn_s_setprio(0); CFENCE;                              \
      __builtin_amdgcn_s_barrier(); CFENCE; }

    STAGE(0); STAGE(1);
    for (int t = 0; t < (KDIM / 32) - 2; ++t) {
        TILE(t, "8", 1);
    }
    TILE((KDIM / 32) - 2, "4", 0);
    TILE((KDIM / 32) - 1, "0", 0);

#undef TILE
#undef STAGE

    // ---- epilogue: LDS round-trip for full-line stores ----
    const int gcol = rowB + wn * 64;        // global col base of wave tile
    const int seg  = gcol >> 11;            // 0:q 1:k 2:v 3:skip(fp32)
    const int lcol = gcol & 2047;
    float bv[4];
    #pragma unroll
    for (int nj = 0; nj < 4; ++nj) bv[nj] = bcat[gcol + nj * 16 + (lane & 15)];
    char* scr = Lds + w * 8192;             // wave-private 8KB (32x64 fp32)
    const int growA = rowA + wm * 64;

    #pragma unroll
    for (int h = 0; h < 2; ++h) {
        #pragma unroll
        for (int m2 = 0; m2 < 2; ++m2) {
            const int mi = h * 2 + m2;
            #pragma unroll
            for (int nj = 0; nj < 4; ++nj) {
                const int cl = nj * 16 + (lane & 15);
                #pragma unroll
                for (int i = 0; i < 4; ++i) {
                    const int rl = m2 * 16 + ((lane >> 4) << 2) + i;
                    *(float*)(scr + rl * 256 + cl * 4) = acc[mi][nj][i] + bv[nj];
                }
            }
        }
        CFENCE;
        if (seg < 3) {
            __hip_bfloat16* dst = (seg == 0) ? oq : (seg == 1) ? ok : ov;
            #pragma unroll
            for (int p = 0; p < 4; ++p) {
                const int rl = p * 8 + (lane >> 3);
                const int u  = lane & 7;
                const float4 f0 = *(const float4*)(scr + rl * 256 + u * 32);
                const float4 f1 = *(const float4*)(scr + rl * 256 + u * 32 + 16);
                __hip_bfloat16 tb[8];
                tb[0] = __float2bfloat16(f0.x); tb[1] = __float2bfloat16(f0.y);
                tb[2] = __float2bfloat16(f0.z); tb[3] = __float2bfloat16(f0.w);
                tb[4] = __float2bfloat16(f1.x); tb[5] = __float2bfloat16(f1.y);
                tb[6] = __float2bfloat16(f1.z); tb[7] = __float2bfloat16(f1.w);
                *(bhalf8*)&dst[(size_t)(growA + h * 32 + rl) * 2048 + lcol + u * 8] =
                    *(bhalf8*)tb;
            }
        } else {
            #pragma unroll
            for (int p = 0; p < 8; ++p) {
                const int rl = p * 4 + (lane >> 4);
                const int u  = lane & 15;
                const float4 f = *(const float4*)(scr + rl * 256 + u * 16);
                *(float4*)&oh[(size_t)(growA + h * 32 + rl) * 2048 + lcol + u * 4] = f;
            }
        }
        asm volatile("s_waitcnt lgkmcnt(0)" ::: "memory");
        CFENCE;
    }
}

// ------------------------------------------------------------------
// 128x128 bf16 MFMA GEMM (4 waves), optional split-K via blockIdx.z.
// C[M,N] = A[M,K] @ Bt[N,K]^T (+bias)(+=C). z>0 writes C + z*M*N.
// flags: 1=+bias  2=+=C(read)  4=relu  8=skip C writeback
// ------------------------------------------------------------------
__global__ __launch_bounds__(256) void gemm_bf16(
    const __hip_bfloat16* __restrict__ A,
    const __hip_bfloat16* __restrict__ Bt,
    const float* __restrict__ bias,
    float* __restrict__ C,
    __hip_bfloat16* __restrict__ Cb,
    int M, int N, int K, int flags)
{
    __shared__ alignas(16) __hip_bfloat16 Asm[128 * 64];
    __shared__ alignas(16) __hip_bfloat16 Bsm[128 * 64];
    const int tid  = threadIdx.x;
    const int w    = tid >> 6;
    const int lane = tid & 63;
    const int wr = w >> 1, wc = w & 1;
    const int rowA = blockIdx.y * 128;
    const int rowB = blockIdx.x * 128;
    const int klen = K / gridDim.z;
    const int kbeg = blockIdx.z * klen;

    const int srow = w * 32 + (lane >> 3);
    const int ug8  = ((lane & 7) ^ (lane >> 3)) << 3;
    const __hip_bfloat16* Ag = A  + (size_t)(rowA + srow) * K + ug8;
    const __hip_bfloat16* Bg = Bt + (size_t)(rowB + srow) * K + ug8;
    char* AsBase = (char*)Asm + w * 4096;
    char* BsBase = (char*)Bsm + w * 4096;

    fx4 acc[4][4] = {};

    const int fra = wr * 64 + (lane & 15);
    const int frb = wc * 64 + (lane & 15);
    const int kb  = (lane >> 4) << 4;
    const int swz = (lane & 7) << 4;

    for (int k0 = kbeg; k0 < kbeg + klen; k0 += 64) {
        __syncthreads();
        #pragma unroll
        for (int j = 0; j < 4; ++j) {
            gload16(Ag + (size_t)j * 8 * K + k0, AsBase + j * 1024);
            gload16(Bg + (size_t)j * 8 * K + k0, BsBase + j * 1024);
        }
        __syncthreads();
        #pragma unroll
        for (int kk = 0; kk < 2; ++kk) {
            const int cb = kk * 64 + kb;
            bhalf8 af[4], bfr[4];
            #pragma unroll
            for (int mi = 0; mi < 4; ++mi)
                af[mi] = *(const bhalf8*)((const char*)Asm + (fra + mi * 16) * 128 + (cb ^ swz));
            #pragma unroll
            for (int nj = 0; nj < 4; ++nj)
                bfr[nj] = *(const bhalf8*)((const char*)Bsm + (frb + nj * 16) * 128 + (cb ^ swz));
            #pragma unroll
            for (int mi = 0; mi < 4; ++mi)
                #pragma unroll
                for (int nj = 0; nj < 4; ++nj)
                    acc[mi][nj] = __builtin_amdgcn_mfma_f32_16x16x32_bf16(
                        af[mi], bfr[nj], acc[mi][nj], 0, 0, 0);
        }
    }

    float* Cz = C ? C + (size_t)blockIdx.z * ((size_t)M * N) : nullptr;
    #pragma unroll
    for (int nj = 0; nj < 4; ++nj) {
        const int ccol = rowB + wc * 64 + nj * 16 + (lane & 15);
        const float bv = (flags & 1) ? bias[ccol] : 0.f;
        #pragma unroll
        for (int mi = 0; mi < 4; ++mi) {
            const int crow0 = rowA + wr * 64 + mi * 16 + ((lane >> 4) << 2);
            #pragma unroll
            for (int i = 0; i < 4; ++i) {
                size_t idx = (size_t)(crow0 + i) * N + ccol;
                float v = acc[mi][nj][i] + bv;
                if (flags & 2) v += Cz[idx];
                if (flags & 4) v = fmaxf(v, 0.f);
                if (Cz && !(flags & 8)) Cz[idx] = v;
                if (Cb) Cb[idx] = __float2bfloat16(v);
            }
        }
    }
}

// dst[i] = sum_z parts[z*stride + i] (+ bias[i & colmask])
__global__ void reduce4(const float* __restrict__ parts, size_t stride,
                        const float* __restrict__ bias, int colmask,
                        float* __restrict__ dst, int n)
{
    int i = blockIdx.x * 256 + threadIdx.x;
    if (i >= n) return;
    float v = parts[i] + parts[stride + i] + parts[2 * stride + i] + parts[3 * stride + i];
    if (bias) v += bias[i & colmask];
    dst[i] = v;
}

// ------------------------------------------------------------------
// fp32 tiled GEMM (kept for tiny E2 = ea @ e2w)
// ------------------------------------------------------------------
__global__ __launch_bounds__(256) void gemm_tile(
    const float* __restrict__ A, const float* __restrict__ B,
    const float* __restrict__ bias, float* __restrict__ C,
    int M, int N, int K, int flags)
{
    __shared__ float As[16][68];
    __shared__ float Bs[16][64];
    const int tid = threadIdx.x;
    const int bx = blockIdx.x, by = blockIdx.y;
    const int tx = tid & 15, ty = tid >> 4;
    const int arow = tid >> 2, acol = (tid & 3) << 2;
    const int brow = tid >> 4, bcol = (tid & 15) << 2;
    const float* Ag = A + (size_t)(by * 64 + arow) * K + acol;
    const float* Bg = B + (size_t)brow * N + bx * 64 + bcol;
    float acc[4][4] = {};
    for (int k0 = 0; k0 < K; k0 += 16) {
        const float4 av = *(const float4*)(Ag + k0);
        const float4 bv = *(const float4*)(Bg + (size_t)k0 * N);
        __syncthreads();
        As[acol + 0][arow] = av.x;
        As[acol + 1][arow] = av.y;
        As[acol + 2][arow] = av.z;
        As[acol + 3][arow] = av.w;
        *(float4*)&Bs[brow][bcol] = bv;
        __syncthreads();
        #pragma unroll
        for (int kk = 0; kk < 16; ++kk) {
            const float4 a4 = *(const float4*)&As[kk][ty << 2];
            const float4 b4 = *(const float4*)&Bs[kk][tx << 2];
            const float a[4] = {a4.x, a4.y, a4.z, a4.w};
            const float b[4] = {b4.x, b4.y, b4.z, b4.w};
            #pragma unroll
            for (int i = 0; i < 4; ++i)
                #pragma unroll
                for (int j = 0; j < 4; ++j)
                    acc[i][j] += a[i] * b[j];
        }
    }
    const int crow = by * 64 + (ty << 2);
    const int ccol = bx * 64 + (tx << 2);
    float4 b4 = make_float4(0.f, 0.f, 0.f, 0.f);
    if (flags & 1) b4 = *(const float4*)(bias + ccol);
    #pragma unroll
    for (int i = 0; i < 4; ++i) {
        float* cp = C + (size_t)(crow + i) * N + ccol;
        float4 v;
        v.x = acc[i][0] + b4.x; v.y = acc[i][1] + b4.y;
        v.z = acc[i][2] + b4.z; v.w = acc[i][3] + b4.w;
        if (flags & 2) {
            const float4 o = *(const float4*)cp;
            v.x += o.x; v.y += o.y; v.z += o.z; v.w += o.w;
        }
        *(float4*)cp = v;
    }
}

// ------------------------------------------------------------------
// CSR build
// ------------------------------------------------------------------
__global__ void count_deg(const int* __restrict__ ei, int* __restrict__ deg)
{
    int e = blockIdx.x * 256 + threadIdx.x;
    if (e < NE) atomicAdd(&deg[ei[NE + e]], 1);
}

__global__ __launch_bounds__(1024) void scan_kernel(const int* __restrict__ deg,
                                                    int* __restrict__ rowptr)
{
    __shared__ int s[1024];
    const int t = threadIdx.x;
    const int base = t * 7;
    int loc[7];
    int sum = 0;
    #pragma unroll
    for (int i = 0; i < 7; ++i) {
        int idx = base + i;
        int v = (idx < NN) ? deg[idx] : 0;
        loc[i] = v; sum += v;
    }
    s[t] = sum;
    __syncthreads();
    for (int off = 1; off < 1024; off <<= 1) {
        int v = (t >= off) ? s[t - off] : 0;
        __syncthreads();
        s[t] += v;
        __syncthreads();
    }
    int running = s[t] - sum;
    #pragma unroll
    for (int i = 0; i < 7; ++i) {
        int idx = base + i;
        if (idx <= NN) rowptr[idx] = running;
        if (idx < NN) running += loc[i];
    }
}

__global__ void fill_csr(const int* __restrict__ ei, const int* __restrict__ rowptr,
                         int* __restrict__ fillctr, int* __restrict__ elist)
{
    int e = blockIdx.x * 256 + threadIdx.x;
    if (e >= NE) return;
    int d = ei[NE + e];
    int pos = atomicAdd(&fillctr[d], 1);
    elist[rowptr[d] + pos] = e;
}

__global__ void sort_csr(const int* __restrict__ rowptr, int* __restrict__ elist)
{
    int n = blockIdx.x * 256 + threadIdx.x;
    if (n >= NN) return;
    int s0 = rowptr[n], s1 = rowptr[n + 1];
    for (int i = s0 + 1; i < s1; ++i) {
        int v = elist[i];
        int j = i - 1;
        while (j >= s0 && elist[j] > v) { elist[j + 1] = elist[j]; --j; }
        elist[j + 1] = v;
    }
}

// ------------------------------------------------------------------
// conversions / weight prep
// ------------------------------------------------------------------
__global__ void cvt_pad_bf16(const float* __restrict__ src, __hip_bfloat16* __restrict__ dst,
                             int relu)
{
    size_t i = (size_t)(blockIdx.x * 256 + threadIdx.x) * 4;
    int row = (int)(i >> 11);
    float4 v = make_float4(0.f, 0.f, 0.f, 0.f);
    if (row < NN) v = *(const float4*)&src[i];
    if (relu) {
        v.x = fmaxf(v.x, 0.f); v.y = fmaxf(v.y, 0.f);
        v.z = fmaxf(v.z, 0.f); v.w = fmaxf(v.w, 0.f);
    }
    dst[i + 0] = __float2bfloat16(v.x);
    dst[i + 1] = __float2bfloat16(v.y);
    dst[i + 2] = __float2bfloat16(v.z);
    dst[i + 3] = __float2bfloat16(v.w);
}

// 4 transposes in one dispatch: Bt[z][n][k] = bf16(Wz[k][n])
__global__ __launch_bounds__(256) void transpose_cvt4(
    const float* __restrict__ W0, const float* __restrict__ W1,
    const float* __restrict__ W2, const float* __restrict__ W3,
    __hip_bfloat16* __restrict__ dst)
{
    const float* W = (blockIdx.z == 0) ? W0 : (blockIdx.z == 1) ? W1
                   : (blockIdx.z == 2) ? W2 : W3;
    __hip_bfloat16* Bt = dst + (size_t)blockIdx.z * KDIM * KDIM;
    __shared__ float t[32][33];
    int kb = blockIdx.y * 32, nb = blockIdx.x * 32;
    int tx = threadIdx.x & 31, ty = threadIdx.x >> 5;
    #pragma unroll
    for (int i = 0; i < 32; i += 8)
        t[ty + i][tx] = W[(size_t)(kb + ty + i) * KDIM + nb + tx];
    __syncthreads();
    #pragma unroll
    for (int i = 0; i < 32; i += 8)
        Bt[(size_t)(nb + ty + i) * KDIM + kb + tx] = __float2bfloat16(t[tx][ty + i]);
}

__global__ void build_bcat(const float* __restrict__ q1b, const float* __restrict__ k1b,
                           const float* __restrict__ v1b, const float* __restrict__ s1b,
                           float* __restrict__ bcat)
{
    int i = blockIdx.x * 256 + threadIdx.x;
    if (i >= 4 * KDIM) return;
    int seg = i >> 11, j = i & 2047;
    const float* b = (seg == 0) ? q1b : (seg == 1) ? k1b : (seg == 2) ? v1b : s1b;
    bcat[i] = b[j];
}

__global__ void build_w1pp(const float* __restrict__ e1w, __hip_bfloat16* __restrict__ w1pp)
{
    int idx = blockIdx.x * 256 + threadIdx.x;
    int p = idx >> 11, j = idx & 2047;
    float v = ((j >> 10) == (p >> 6)) ? e1w[(size_t)(p & 63) * KDIM + j] : 0.f;
    w1pp[idx] = __float2bfloat16(v);
}

__global__ void build_w1ppT(const float* __restrict__ e1w, __hip_bfloat16* __restrict__ w1ppT)
{
    int idx = blockIdx.x * 256 + threadIdx.x;
    int n = idx >> 7, k = idx & 127;
    float v = ((n >> 10) == (k >> 6)) ? e1w[(size_t)(k & 63) * KDIM + n] : 0.f;
    w1ppT[idx] = __float2bfloat16(v);
}

__global__ void build_w2t(const float* __restrict__ qw, const float* __restrict__ kw,
                          const float* __restrict__ vw, const float* __restrict__ sw,
                          const float* __restrict__ qb, const float* __restrict__ kb,
                          const float* __restrict__ vb, const float* __restrict__ sb,
                          __hip_bfloat16* __restrict__ w2t, float* __restrict__ b2)
{
    int idx = blockIdx.x * 256 + threadIdx.x;
    int c = idx >> 11, d = idx & 2047;
    int g = c >> 6, j = c & 63;
    const float* w = (g == 0) ? qw : (g == 1) ? kw : (g == 2) ? vw : sw;
    w2t[idx] = __float2bfloat16(w[(size_t)d * 64 + j]);
    if (d == 0) {
        const float* b = (g == 0) ? qb : (g == 1) ? kb : (g == 2) ? vb : sb;
        b2[c] = b[j];
    }
}

// ------------------------------------------------------------------
// edge kernels (CSR slot order)
// ------------------------------------------------------------------
__global__ __launch_bounds__(256) void alpha1_kernel(
    const __hip_bfloat16* __restrict__ q1b, const __hip_bfloat16* __restrict__ k1b,
    const float* __restrict__ P1, const float* __restrict__ ea,
    const int* __restrict__ ei, const int* __restrict__ elist,
    float* __restrict__ alpha)
{
    int i = blockIdx.x * 4 + (threadIdx.x >> 6);
    int lane = threadIdx.x & 63;
    int e = elist[i];
    int src = ei[e], dst = ei[NE + e];
    float eaj = ea[(size_t)e * 64 + lane];
    #pragma unroll
    for (int h = 0; h < 2; ++h) {
        const __hip_bfloat16* qh = q1b + (size_t)dst * HC1 + h * 1024 + lane * 16;
        const __hip_bfloat16* kh = k1b + (size_t)src * HC1 + h * 1024 + lane * 16;
        bhalf8 qa = *(const bhalf8*)qh, qc = *(const bhalf8*)(qh + 8);
        bhalf8 ka = *(const bhalf8*)kh, kc = *(const bhalf8*)(kh + 8);
        float s = 0.f;
        #pragma unroll
        for (int j = 0; j < 8; ++j) s += bf2f(qa[j]) * bf2f(ka[j]);
        #pragma unroll
        for (int j = 0; j < 8; ++j) s += bf2f(qc[j]) * bf2f(kc[j]);
        s += eaj * P1[(size_t)dst * 128 + h * 64 + lane];
        #pragma unroll
        for (int off = 32; off; off >>= 1) s += __shfl_xor(s, off);
        if (lane == 0) alpha[(size_t)i * 2 + h] = s * 0.03125f;
    }
}

__global__ void softmax_kernel(const int* __restrict__ rowptr,
                               float* __restrict__ alpha, int H)
{
    int n = blockIdx.x * 256 + threadIdx.x;
    if (n >= NN) return;
    int s0 = rowptr[n], s1 = rowptr[n + 1];
    for (int h = 0; h < H; ++h) {
        float m = -1e30f;
        for (int i = s0; i < s1; ++i)
            m = fmaxf(m, alpha[(size_t)i * H + h]);
        float ssum = 0.f;
        for (int i = s0; i < s1; ++i) {
            float ex = __expf(alpha[(size_t)i * H + h] - m);
            alpha[(size_t)i * H + h] = ex;
            ssum += ex;
        }
        float inv = 1.f / (ssum + 1e-16f);
        for (int i = s0; i < s1; ++i)
            alpha[(size_t)i * H + h] *= inv;
    }
}

__global__ __launch_bounds__(128) void r1_kernel(
    const int* __restrict__ rowptr, const int* __restrict__ elist,
    const float* __restrict__ attn, const float* __restrict__ ea,
    __hip_bfloat16* __restrict__ R1)
{
    int n = blockIdx.x;
    int p = threadIdx.x;
    int h = p >> 6, j = p & 63;
    int s0 = rowptr[n], s1 = rowptr[n + 1];
    float r = 0.f;
    for (int i = s0; i < s1; ++i) {
        int e = elist[i];
        r += attn[(size_t)i * 2 + h] * ea[(size_t)e * 64 + j];
    }
    R1[(size_t)n * 128 + p] = __float2bfloat16(r);
}

__global__ __launch_bounds__(256) void agg1_kernel(
    const int* __restrict__ rowptr, const int* __restrict__ elist,
    const int* __restrict__ ei, const float* __restrict__ attn,
    const __hip_bfloat16* __restrict__ v1b, float* __restrict__ h1)
{
    int n = blockIdx.x;
    int c0 = threadIdx.x * 8;
    int h = c0 >> 10;
    int s0 = rowptr[n], s1 = rowptr[n + 1];
    float acc[8];
    const float4 p0 = *(const float4*)&h1[(size_t)n * HC1 + c0];
    const float4 p1 = *(const float4*)&h1[(size_t)n * HC1 + c0 + 4];
    acc[0] = p0.x; acc[1] = p0.y; acc[2] = p0.z; acc[3] = p0.w;
    acc[4] = p1.x; acc[5] = p1.y; acc[6] = p1.z; acc[7] = p1.w;
    for (int i = s0; i < s1; ++i) {
        float at = attn[(size_t)i * 2 + h];
        bhalf8 v = *(const bhalf8*)&v1b[(size_t)ei[elist[i]] * HC1 + c0];
        #pragma unroll
        for (int j = 0; j < 8; ++j) acc[j] += at * bf2f(v[j]);
    }
    float4 o0 = make_float4(acc[0], acc[1], acc[2], acc[3]);
    float4 o1 = make_float4(acc[4], acc[5], acc[6], acc[7]);
    *(float4*)&h1[(size_t)n * HC1 + c0] = o0;
    *(float4*)&h1[(size_t)n * HC1 + c0 + 4] = o1;
}

__global__ __launch_bounds__(256) void alpha2_kernel(
    const float* __restrict__ qkvs2, const float* __restrict__ E2,
    const int* __restrict__ ei, const int* __restrict__ elist,
    float* __restrict__ alpha2)
{
    int i = blockIdx.x * 4 + (threadIdx.x >> 6);
    int lane = threadIdx.x & 63;
    int e = elist[i];
    int src = ei[e], dst = ei[NE + e];
    float q = qkvs2[(size_t)dst * 256 + lane];
    float k = qkvs2[(size_t)src * 256 + 64 + lane];
    float s = q * (k + E2[(size_t)e * 64 + lane]);
    #pragma unroll
    for (int off = 32; off; off >>= 1) s += __shfl_xor(s, off);
    if (lane == 0) alpha2[i] = s * 0.125f;
}

__global__ __launch_bounds__(64) void agg2_kernel(
    const int* __restrict__ rowptr, const int* __restrict__ elist,
    const int* __restrict__ ei, const float* __restrict__ attn2,
    const float* __restrict__ qkvs2, const float* __restrict__ E2,
    float* __restrict__ out)
{
    int n = blockIdx.x;
    int c = threadIdx.x;
    int s0 = rowptr[n], s1 = rowptr[n + 1];
    float acc = qkvs2[(size_t)n * 256 + 192 + c];
    for (int i = s0; i < s1; ++i) {
        int e = elist[i];
        acc += attn2[i] * (qkvs2[(size_t)ei[e] * 256 + 128 + c] + E2[(size_t)e * 64 + c]);
    }
    out[(size_t)n * 64 + c] = fmaxf(acc, 0.f);
}

// ------------------------------------------------------------------
extern "C" void kernel_launch(void* const* d_in, const int* in_sizes, int n_in,
                              void* d_out, int out_size, void* d_ws, size_t ws_size,
                              hipStream_t stream)
{
    const float* x   = (const float*)d_in[0];
    const int*   ei  = (const int*)d_in[1];
    const float* ea  = (const float*)d_in[2];
    const float* q1w = (const float*)d_in[3];
    const float* q1b = (const float*)d_in[4];
    const float* k1w = (const float*)d_in[5];
    const float* k1b = (const float*)d_in[6];
    const float* v1w = (const float*)d_in[7];
    const float* v1b = (const float*)d_in[8];
    const float* e1w = (const float*)d_in[9];
    const float* s1w = (const float*)d_in[10];
    const float* s1b = (const float*)d_in[11];
    const float* q2w = (const float*)d_in[12];
    const float* q2b = (const float*)d_in[13];
    const float* k2w = (const float*)d_in[14];
    const float* k2b = (const float*)d_in[15];
    const float* v2w = (const float*)d_in[16];
    const float* v2b = (const float*)d_in[17];
    const float* e2w = (const float*)d_in[18];
    const float* s2w = (const float*)d_in[19];
    const float* s2b = (const float*)d_in[20];
    float* out = (float*)d_out;

    char* base = (char*)d_ws;
    size_t off = 0;
    auto alloc = [&](size_t nbytes) {
        size_t o = off; off += (nbytes + 255) & ~(size_t)255; return o;
    };
    const size_t xb_off   = alloc((size_t)MPAD * KDIM * 2);      // bf16 input (reused as h1b)
    const size_t wcat_off = alloc((size_t)4 * KDIM * KDIM * 2);  // fused weights (reused: Cpart+w2t)
    __hip_bfloat16* xb    = (__hip_bfloat16*)(base + xb_off);
    __hip_bfloat16* wcat  = (__hip_bfloat16*)(base + wcat_off);
    __hip_bfloat16* h1b   = xb;                                   // alias (xb dead after gemm128)
    float*          Cpart = (float*)(base + wcat_off);            // alias (wcat dead after gemm128)
    __hip_bfloat16* w2t   = (__hip_bfloat16*)(base + wcat_off + (size_t)29 * 1024 * 1024);

    __hip_bfloat16* q1bb  = (__hip_bfloat16*)(base + alloc((size_t)MPAD * HC1 * 2));
    __hip_bfloat16* k1bb  = (__hip_bfloat16*)(base + alloc((size_t)MPAD * HC1 * 2));
    __hip_bfloat16* v1bb  = (__hip_bfloat16*)(base + alloc((size_t)MPAD * HC1 * 2));
    float*          h1    = (float*)(base + alloc((size_t)MPAD * HC1 * 4));
    float*          bcat  = (float*)(base + alloc((size_t)4 * KDIM * 4));
    float*          P1    = (float*)(base + alloc((size_t)MPAD * 128 * 4));
    __hip_bfloat16* R1b   = (__hip_bfloat16*)(base + alloc((size_t)MPAD * 128 * 2));
    __hip_bfloat16* w1pp  = (__hip_bfloat16*)(base + alloc((size_t)128 * KDIM * 2));
    __hip_bfloat16* w1ppT = (__hip_bfloat16*)(base + alloc((size_t)KDIM * 128 * 2));
    float*          b2    = (float*)(base + alloc(256 * 4));
    float*          qkvs2 = (float*)(base + alloc((size_t)MPAD * 256 * 4));
    float*          E2    = (float*)(base + alloc((size_t)NE * 64 * 4));
    float*          at1   = (float*)(base + alloc((size_t)NE * 2 * 4));
    float*          at2   = (float*)(base + alloc((size_t)NE * 4));
    int* deg    = (int*)(base + alloc((size_t)NN * 4));
    int* fill   = (int*)(base + alloc((size_t)NN * 4));
    int* rowptr = (int*)(base + alloc((size_t)(NN + 1) * 4));
    int* elist  = (int*)(base + alloc((size_t)NE * 4));

    // --- CSR build ---
    hipMemsetAsync(deg, 0, sizeof(int) * 2 * NN, stream);
    count_deg<<<(NE + 255) / 256, 256, 0, stream>>>(ei, deg);
    scan_kernel<<<1, 1024, 0, stream>>>(deg, rowptr);
    fill_csr<<<(NE + 255) / 256, 256, 0, stream>>>(ei, rowptr, fill, elist);
    sort_csr<<<(NN + 255) / 256, 256, 0, stream>>>(rowptr, elist);

    // --- input conversion + fused weight prep ---
    const int cvblk = (MPAD * KDIM / 4) / 256;
    cvt_pad_bf16<<<cvblk, 256, 0, stream>>>(x, xb, 0);
    transpose_cvt4<<<dim3(KDIM / 32, KDIM / 32, 4), 256, 0, stream>>>(q1w, k1w, v1w, s1w, wcat);
    build_bcat<<<(4 * KDIM) / 256, 256, 0, stream>>>(q1b, k1b, v1b, s1b, bcat);

    // --- fused layer-1 projections: one 3456-block 128^2 dispatch ---
    gemm128_fused<<<3456, 256, 0, stream>>>(xb, wcat, bcat, q1bb, k1bb, v1bb, h1);

    // --- P1 = q1 @ W1p (split-K 4) ---
    build_w1pp<<<(128 * KDIM) / 256, 256, 0, stream>>>(e1w, w1pp);
    build_w1ppT<<<(KDIM * 128) / 256, 256, 0, stream>>>(e1w, w1ppT);
    gemm_bf16<<<dim3(1, MPAD / 128, 4), 256, 0, stream>>>(q1bb, w1pp, nullptr, Cpart, nullptr,
                                                          MPAD, 128, KDIM, 0);
    reduce4<<<(MPAD * 128) / 256, 256, 0, stream>>>(Cpart, (size_t)MPAD * 128, nullptr, 0,
                                                    P1, MPAD * 128);

    // --- attention layer 1 (slot-ordered) ---
    alpha1_kernel<<<NE / 4, 256, 0, stream>>>(q1bb, k1bb, P1, ea, ei, elist, at1);
    softmax_kernel<<<(NN + 255) / 256, 256, 0, stream>>>(rowptr, at1, 2);
    r1_kernel<<<NN, 128, 0, stream>>>(rowptr, elist, at1, ea, R1b);
    agg1_kernel<<<NN, 256, 0, stream>>>(rowptr, elist, ei, at1, v1bb, h1);
    // R1 @ W1pp, += h1, relu, write bf16 h1b directly (no fp32 writeback)
    gemm_bf16<<<dim3(HC1 / 128, MPAD / 128), 256, 0, stream>>>(R1b, w1ppT, nullptr, h1, h1b,
                                                               MPAD, HC1, 128, 2 | 4 | 8);

    // --- layer 2 projections (split-K 4) ---
    build_w2t<<<(256 * KDIM) / 256, 256, 0, stream>>>(q2w, k2w, v2w, s2w, q2b, k2b, v2b, s2b,
                                                      w2t, b2);
    gemm_bf16<<<dim3(2, MPAD / 128, 4), 256, 0, stream>>>(h1b, w2t, nullptr, Cpart, nullptr,
                                                          MPAD, 256, KDIM, 0);
    reduce4<<<(MPAD * 256) / 256, 256, 0, stream>>>(Cpart, (size_t)MPAD * 256, b2, 255,
                                                    qkvs2, MPAD * 256);
    gemm_tile<<<dim3(1, NE / 64), 256, 0, stream>>>(ea, e2w, nullptr, E2, NE, 64, 64, 0);

    // --- attention layer 2 (slot-ordered) ---
    alpha2_kernel<<<NE / 4, 256, 0, stream>>>(qkvs2, E2, ei, elist, at2);
    softmax_kernel<<<(NN + 255) / 256, 256, 0, stream>>>(rowptr, at2, 1);
    agg2_kernel<<<NN, 64, 0, stream>>>(rowptr, elist, ei, at2, qkvs2, E2, out);

    (void)in_sizes; (void)n_in; (void)out_size; (void)ws_size;
}

// Round 6
// 559.833 us; speedup vs baseline: 6.4560x; 1.0436x over previous
//
#include <hip/hip_runtime.h>
#include <hip/hip_bf16.h>
#include <cstdint>
#include <cstddef>

#define NN    6720     // nodes
#define MPAD  6912     // 54 * 128
#define NE    33600    // edges
#define KDIM  2048
#define HC1   2048

typedef __attribute__((ext_vector_type(8))) short bhalf8;
typedef __attribute__((ext_vector_type(4))) float fx4;

__device__ __forceinline__ float bf2f(short s) {
    union { unsigned int u; float f; } c;
    c.u = ((unsigned int)(unsigned short)s) << 16;
    return c.f;
}

__device__ __forceinline__ void gload16(const __hip_bfloat16* g, void* lds)
{
    __builtin_amdgcn_global_load_lds(
        (const __attribute__((address_space(1))) unsigned int*)g,
        (__attribute__((address_space(3))) unsigned int*)lds,
        16, 0, 0);
}

#define CFENCE asm volatile("" ::: "memory")

// ------------------------------------------------------------------
// 128x128-tile 4-wave fused projection GEMM. BK=32, 3-deep LDS ring,
// counted vmcnt, 48KB LDS -> 3 blocks/CU (12 waves/CU TLP).
// A [MPAD x 2048] bf16, Bt [8192 x 2048] bf16 (rows = out cols q|k|v|s).
// Block->tile map: XCD j (bid&7) owns bx stripe [8j,8j+8) for the WHOLE
// kernel (B working set 8x512KB = 4MB = L2); consecutive 8 blocks share
// one A-panel. B streams from HBM ~once instead of once per M-panel.
// ------------------------------------------------------------------
__global__ __launch_bounds__(256, 3) void gemm128_fused(
    const __hip_bfloat16* __restrict__ A,
    const __hip_bfloat16* __restrict__ Bt,
    const float* __restrict__ bcat,
    __hip_bfloat16* __restrict__ oq,
    __hip_bfloat16* __restrict__ ok,
    __hip_bfloat16* __restrict__ ov,
    float* __restrict__ oh)
{
    __shared__ alignas(16) char Lds[49152];   // A ring 3x8KB | B ring 3x8KB

    // XCD-locality map: 3456 = 8 XCD * 432. XCD = bid&7 owns 8 bx panels.
    const int bid = blockIdx.x;
    const int i   = bid >> 3;
    const int bx  = (bid & 7) * 8 + (i & 7);   // N: 64 tiles of 128
    const int by  = i >> 3;                    // M: 54 tiles of 128

    const int tid  = threadIdx.x;
    const int w    = tid >> 6;        // 0..3
    const int lane = tid & 63;
    const int wm = w >> 1, wn = w & 1;    // 2x2 waves, wave tile 64x64
    const int rowA = by * 128;
    const int rowB = bx * 128;

    // staging: wave w covers rows w*32..+31 of each 128x32 plane,
    // 2 gloads per operand (16 rows = 1KB each). Pre-swizzled source:
    // LDS(row, phys u) = global unit u ^ ((row>>1)&3).
    const int sug = ((lane & 3) ^ ((lane >> 3) & 3)) << 3;
    const __hip_bfloat16* Ag0 = A  + (size_t)(rowA + w * 32 + (lane >> 2)) * KDIM + sug;
    const __hip_bfloat16* Bg0 = Bt + (size_t)(rowB + w * 32 + (lane >> 2)) * KDIM + sug;

    // fragment read: row = base16 + (lane&15); byte = row*64 + rds
    const int rds = (((lane >> 4) ^ (((lane & 15) >> 1) & 3)) << 4);

    fx4 acc[4][4] = {};

#define STAGE(T)                                                          \
    { const int s_ = (T) % 3; const int k0_ = (T) * 32;                   \
      char* ab_ = Lds + s_ * 8192 + w * 2048;                             \
      char* bb_ = Lds + 24576 + s_ * 8192 + w * 2048;                     \
      gload16(Ag0 + k0_, ab_);                                            \
      gload16(Ag0 + k0_ + 16 * KDIM, ab_ + 1024);                         \
      gload16(Bg0 + k0_, bb_);                                            \
      gload16(Bg0 + k0_ + 16 * KDIM, bb_ + 1024); }

#define TILE(T, VM, DOSTAGE)                                              \
    { if (DOSTAGE) { STAGE((T) + 2); }                                    \
      asm volatile("s_waitcnt vmcnt(" VM ")" ::: "memory");               \
      __builtin_amdgcn_s_barrier(); CFENCE;                               \
      const int s_ = (T) % 3;                                             \
      const char* ap_ = Lds + s_ * 8192;                                  \
      const char* bp_ = Lds + 24576 + s_ * 8192;                          \
      bhalf8 af_[4], bf_[4];                                              \
      _Pragma("unroll")                                                   \
      for (int nj = 0; nj < 4; ++nj)                                      \
          bf_[nj] = *(const bhalf8*)(bp_ + (wn * 64 + nj * 16 + (lane & 15)) * 64 + rds); \
      _Pragma("unroll")                                                   \
      for (int mi = 0; mi < 4; ++mi)                                      \
          af_[mi] = *(const bhalf8*)(ap_ + (wm * 64 + mi * 16 + (lane & 15)) * 64 + rds); \
      __builtin_amdgcn_s_setprio(1);                                      \
      _Pragma("unroll")                                                   \
      for (int mi = 0; mi < 4; ++mi)                                      \
          _Pragma("unroll")                                               \
          for (int nj = 0; nj < 4; ++nj)                                  \
              acc[mi][nj] = __builtin_amdgcn_mfma_f32_16x16x32_bf16(      \
                  af_[mi], bf_[nj], acc[mi][nj], 0, 0, 0);                \
      __builtin_amdgcn_s_setprio(0); CFENCE;                              \
      __builtin_amdgcn_s_barrier(); CFENCE; }

    STAGE(0); STAGE(1);
    for (int t = 0; t < (KDIM / 32) - 2; ++t) {
        TILE(t, "8", 1);
    }
    TILE((KDIM / 32) - 2, "4", 0);
    TILE((KDIM / 32) - 1, "0", 0);

#undef TILE
#undef STAGE

    // ---- epilogue: LDS round-trip for full-line stores ----
    const int gcol = rowB + wn * 64;        // global col base of wave tile
    const int seg  = gcol >> 11;            // 0:q 1:k 2:v 3:skip(fp32)
    const int lcol = gcol & 2047;
    float bv[4];
    #pragma unroll
    for (int nj = 0; nj < 4; ++nj) bv[nj] = bcat[gcol + nj * 16 + (lane & 15)];
    char* scr = Lds + w * 8192;             // wave-private 8KB (32x64 fp32)
    const int growA = rowA + wm * 64;

    #pragma unroll
    for (int h = 0; h < 2; ++h) {
        #pragma unroll
        for (int m2 = 0; m2 < 2; ++m2) {
            const int mi = h * 2 + m2;
            #pragma unroll
            for (int nj = 0; nj < 4; ++nj) {
                const int cl = nj * 16 + (lane & 15);
                #pragma unroll
                for (int i2 = 0; i2 < 4; ++i2) {
                    const int rl = m2 * 16 + ((lane >> 4) << 2) + i2;
                    *(float*)(scr + rl * 256 + cl * 4) = acc[mi][nj][i2] + bv[nj];
                }
            }
        }
        CFENCE;
        if (seg < 3) {
            __hip_bfloat16* dst = (seg == 0) ? oq : (seg == 1) ? ok : ov;
            #pragma unroll
            for (int p = 0; p < 4; ++p) {
                const int rl = p * 8 + (lane >> 3);
                const int u  = lane & 7;
                const float4 f0 = *(const float4*)(scr + rl * 256 + u * 32);
                const float4 f1 = *(const float4*)(scr + rl * 256 + u * 32 + 16);
                __hip_bfloat16 tb[8];
                tb[0] = __float2bfloat16(f0.x); tb[1] = __float2bfloat16(f0.y);
                tb[2] = __float2bfloat16(f0.z); tb[3] = __float2bfloat16(f0.w);
                tb[4] = __float2bfloat16(f1.x); tb[5] = __float2bfloat16(f1.y);
                tb[6] = __float2bfloat16(f1.z); tb[7] = __float2bfloat16(f1.w);
                *(bhalf8*)&dst[(size_t)(growA + h * 32 + rl) * 2048 + lcol + u * 8] =
                    *(bhalf8*)tb;
            }
        } else {
            #pragma unroll
            for (int p = 0; p < 8; ++p) {
                const int rl = p * 4 + (lane >> 4);
                const int u  = lane & 15;
                const float4 f = *(const float4*)(scr + rl * 256 + u * 16);
                *(float4*)&oh[(size_t)(growA + h * 32 + rl) * 2048 + lcol + u * 4] = f;
            }
        }
        asm volatile("s_waitcnt lgkmcnt(0)" ::: "memory");
        CFENCE;
    }
}

// ------------------------------------------------------------------
// 128x128 bf16 MFMA GEMM (4 waves), optional split-K via blockIdx.z.
// C[M,N] = A[M,K] @ Bt[N,K]^T (+bias)(+=C). z>0 writes C + z*M*N.
// flags: 1=+bias  2=+=C(read)  4=relu  8=skip C writeback
// ------------------------------------------------------------------
__global__ __launch_bounds__(256) void gemm_bf16(
    const __hip_bfloat16* __restrict__ A,
    const __hip_bfloat16* __restrict__ Bt,
    const float* __restrict__ bias,
    float* __restrict__ C,
    __hip_bfloat16* __restrict__ Cb,
    int M, int N, int K, int flags)
{
    __shared__ alignas(16) __hip_bfloat16 Asm[128 * 64];
    __shared__ alignas(16) __hip_bfloat16 Bsm[128 * 64];
    const int tid  = threadIdx.x;
    const int w    = tid >> 6;
    const int lane = tid & 63;
    const int wr = w >> 1, wc = w & 1;
    const int rowA = blockIdx.y * 128;
    const int rowB = blockIdx.x * 128;
    const int klen = K / gridDim.z;
    const int kbeg = blockIdx.z * klen;

    const int srow = w * 32 + (lane >> 3);
    const int ug8  = ((lane & 7) ^ (lane >> 3)) << 3;
    const __hip_bfloat16* Ag = A  + (size_t)(rowA + srow) * K + ug8;
    const __hip_bfloat16* Bg = Bt + (size_t)(rowB + srow) * K + ug8;
    char* AsBase = (char*)Asm + w * 4096;
    char* BsBase = (char*)Bsm + w * 4096;

    fx4 acc[4][4] = {};

    const int fra = wr * 64 + (lane & 15);
    const int frb = wc * 64 + (lane & 15);
    const int kb  = (lane >> 4) << 4;
    const int swz = (lane & 7) << 4;

    for (int k0 = kbeg; k0 < kbeg + klen; k0 += 64) {
        __syncthreads();
        #pragma unroll
        for (int j = 0; j < 4; ++j) {
            gload16(Ag + (size_t)j * 8 * K + k0, AsBase + j * 1024);
            gload16(Bg + (size_t)j * 8 * K + k0, BsBase + j * 1024);
        }
        __syncthreads();
        #pragma unroll
        for (int kk = 0; kk < 2; ++kk) {
            const int cb = kk * 64 + kb;
            bhalf8 af[4], bfr[4];
            #pragma unroll
            for (int mi = 0; mi < 4; ++mi)
                af[mi] = *(const bhalf8*)((const char*)Asm + (fra + mi * 16) * 128 + (cb ^ swz));
            #pragma unroll
            for (int nj = 0; nj < 4; ++nj)
                bfr[nj] = *(const bhalf8*)((const char*)Bsm + (frb + nj * 16) * 128 + (cb ^ swz));
            #pragma unroll
            for (int mi = 0; mi < 4; ++mi)
                #pragma unroll
                for (int nj = 0; nj < 4; ++nj)
                    acc[mi][nj] = __builtin_amdgcn_mfma_f32_16x16x32_bf16(
                        af[mi], bfr[nj], acc[mi][nj], 0, 0, 0);
        }
    }

    float* Cz = C ? C + (size_t)blockIdx.z * ((size_t)M * N) : nullptr;
    #pragma unroll
    for (int nj = 0; nj < 4; ++nj) {
        const int ccol = rowB + wc * 64 + nj * 16 + (lane & 15);
        const float bv = (flags & 1) ? bias[ccol] : 0.f;
        #pragma unroll
        for (int mi = 0; mi < 4; ++mi) {
            const int crow0 = rowA + wr * 64 + mi * 16 + ((lane >> 4) << 2);
            #pragma unroll
            for (int i = 0; i < 4; ++i) {
                size_t idx = (size_t)(crow0 + i) * N + ccol;
                float v = acc[mi][nj][i] + bv;
                if (flags & 2) v += Cz[idx];
                if (flags & 4) v = fmaxf(v, 0.f);
                if (Cz && !(flags & 8)) Cz[idx] = v;
                if (Cb) Cb[idx] = __float2bfloat16(v);
            }
        }
    }
}

// dst[i] = sum_z parts[z*stride + i] (+ bias[i & colmask])
__global__ void reduce4(const float* __restrict__ parts, size_t stride,
                        const float* __restrict__ bias, int colmask,
                        float* __restrict__ dst, int n)
{
    int i = blockIdx.x * 256 + threadIdx.x;
    if (i >= n) return;
    float v = parts[i] + parts[stride + i] + parts[2 * stride + i] + parts[3 * stride + i];
    if (bias) v += bias[i & colmask];
    dst[i] = v;
}

// ------------------------------------------------------------------
// fp32 tiled GEMM (kept for tiny E2 = ea @ e2w)
// ------------------------------------------------------------------
__global__ __launch_bounds__(256) void gemm_tile(
    const float* __restrict__ A, const float* __restrict__ B,
    const float* __restrict__ bias, float* __restrict__ C,
    int M, int N, int K, int flags)
{
    __shared__ float As[16][68];
    __shared__ float Bs[16][64];
    const int tid = threadIdx.x;
    const int bx = blockIdx.x, by = blockIdx.y;
    const int tx = tid & 15, ty = tid >> 4;
    const int arow = tid >> 2, acol = (tid & 3) << 2;
    const int brow = tid >> 4, bcol = (tid & 15) << 2;
    const float* Ag = A + (size_t)(by * 64 + arow) * K + acol;
    const float* Bg = B + (size_t)brow * N + bx * 64 + bcol;
    float acc[4][4] = {};
    for (int k0 = 0; k0 < K; k0 += 16) {
        const float4 av = *(const float4*)(Ag + k0);
        const float4 bv = *(const float4*)(Bg + (size_t)k0 * N);
        __syncthreads();
        As[acol + 0][arow] = av.x;
        As[acol + 1][arow] = av.y;
        As[acol + 2][arow] = av.z;
        As[acol + 3][arow] = av.w;
        *(float4*)&Bs[brow][bcol] = bv;
        __syncthreads();
        #pragma unroll
        for (int kk = 0; kk < 16; ++kk) {
            const float4 a4 = *(const float4*)&As[kk][ty << 2];
            const float4 b4 = *(const float4*)&Bs[kk][tx << 2];
            const float a[4] = {a4.x, a4.y, a4.z, a4.w};
            const float b[4] = {b4.x, b4.y, b4.z, b4.w};
            #pragma unroll
            for (int i = 0; i < 4; ++i)
                #pragma unroll
                for (int j = 0; j < 4; ++j)
                    acc[i][j] += a[i] * b[j];
        }
    }
    const int crow = by * 64 + (ty << 2);
    const int ccol = bx * 64 + (tx << 2);
    float4 b4 = make_float4(0.f, 0.f, 0.f, 0.f);
    if (flags & 1) b4 = *(const float4*)(bias + ccol);
    #pragma unroll
    for (int i = 0; i < 4; ++i) {
        float* cp = C + (size_t)(crow + i) * N + ccol;
        float4 v;
        v.x = acc[i][0] + b4.x; v.y = acc[i][1] + b4.y;
        v.z = acc[i][2] + b4.z; v.w = acc[i][3] + b4.w;
        if (flags & 2) {
            const float4 o = *(const float4*)cp;
            v.x += o.x; v.y += o.y; v.z += o.z; v.w += o.w;
        }
        *(float4*)cp = v;
    }
}

// ------------------------------------------------------------------
// CSR build
// ------------------------------------------------------------------
__global__ void count_deg(const int* __restrict__ ei, int* __restrict__ deg)
{
    int e = blockIdx.x * 256 + threadIdx.x;
    if (e < NE) atomicAdd(&deg[ei[NE + e]], 1);
}

__global__ __launch_bounds__(1024) void scan_kernel(const int* __restrict__ deg,
                                                    int* __restrict__ rowptr)
{
    __shared__ int s[1024];
    const int t = threadIdx.x;
    const int base = t * 7;
    int loc[7];
    int sum = 0;
    #pragma unroll
    for (int i = 0; i < 7; ++i) {
        int idx = base + i;
        int v = (idx < NN) ? deg[idx] : 0;
        loc[i] = v; sum += v;
    }
    s[t] = sum;
    __syncthreads();
    for (int off = 1; off < 1024; off <<= 1) {
        int v = (t >= off) ? s[t - off] : 0;
        __syncthreads();
        s[t] += v;
        __syncthreads();
    }
    int running = s[t] - sum;
    #pragma unroll
    for (int i = 0; i < 7; ++i) {
        int idx = base + i;
        if (idx <= NN) rowptr[idx] = running;
        if (idx < NN) running += loc[i];
    }
}

__global__ void fill_csr(const int* __restrict__ ei, const int* __restrict__ rowptr,
                         int* __restrict__ fillctr, int* __restrict__ elist)
{
    int e = blockIdx.x * 256 + threadIdx.x;
    if (e >= NE) return;
    int d = ei[NE + e];
    int pos = atomicAdd(&fillctr[d], 1);
    elist[rowptr[d] + pos] = e;
}

__global__ void sort_csr(const int* __restrict__ rowptr, int* __restrict__ elist)
{
    int n = blockIdx.x * 256 + threadIdx.x;
    if (n >= NN) return;
    int s0 = rowptr[n], s1 = rowptr[n + 1];
    for (int i = s0 + 1; i < s1; ++i) {
        int v = elist[i];
        int j = i - 1;
        while (j >= s0 && elist[j] > v) { elist[j + 1] = elist[j]; --j; }
        elist[j + 1] = v;
    }
}

// ------------------------------------------------------------------
// conversions / weight prep
// ------------------------------------------------------------------
__global__ void cvt_pad_bf16(const float* __restrict__ src, __hip_bfloat16* __restrict__ dst,
                             int relu)
{
    size_t i = (size_t)(blockIdx.x * 256 + threadIdx.x) * 4;
    int row = (int)(i >> 11);
    float4 v = make_float4(0.f, 0.f, 0.f, 0.f);
    if (row < NN) v = *(const float4*)&src[i];
    if (relu) {
        v.x = fmaxf(v.x, 0.f); v.y = fmaxf(v.y, 0.f);
        v.z = fmaxf(v.z, 0.f); v.w = fmaxf(v.w, 0.f);
    }
    dst[i + 0] = __float2bfloat16(v.x);
    dst[i + 1] = __float2bfloat16(v.y);
    dst[i + 2] = __float2bfloat16(v.z);
    dst[i + 3] = __float2bfloat16(v.w);
}

// 4 transposes in one dispatch: Bt[z][n][k] = bf16(Wz[k][n])
__global__ __launch_bounds__(256) void transpose_cvt4(
    const float* __restrict__ W0, const float* __restrict__ W1,
    const float* __restrict__ W2, const float* __restrict__ W3,
    __hip_bfloat16* __restrict__ dst)
{
    const float* W = (blockIdx.z == 0) ? W0 : (blockIdx.z == 1) ? W1
                   : (blockIdx.z == 2) ? W2 : W3;
    __hip_bfloat16* Bt = dst + (size_t)blockIdx.z * KDIM * KDIM;
    __shared__ float t[32][33];
    int kb = blockIdx.y * 32, nb = blockIdx.x * 32;
    int tx = threadIdx.x & 31, ty = threadIdx.x >> 5;
    #pragma unroll
    for (int i = 0; i < 32; i += 8)
        t[ty + i][tx] = W[(size_t)(kb + ty + i) * KDIM + nb + tx];
    __syncthreads();
    #pragma unroll
    for (int i = 0; i < 32; i += 8)
        Bt[(size_t)(nb + ty + i) * KDIM + kb + tx] = __float2bfloat16(t[tx][ty + i]);
}

__global__ void build_bcat(const float* __restrict__ q1b, const float* __restrict__ k1b,
                           const float* __restrict__ v1b, const float* __restrict__ s1b,
                           float* __restrict__ bcat)
{
    int i = blockIdx.x * 256 + threadIdx.x;
    if (i >= 4 * KDIM) return;
    int seg = i >> 11, j = i & 2047;
    const float* b = (seg == 0) ? q1b : (seg == 1) ? k1b : (seg == 2) ? v1b : s1b;
    bcat[i] = b[j];
}

__global__ void build_w1pp(const float* __restrict__ e1w, __hip_bfloat16* __restrict__ w1pp)
{
    int idx = blockIdx.x * 256 + threadIdx.x;
    int p = idx >> 11, j = idx & 2047;
    float v = ((j >> 10) == (p >> 6)) ? e1w[(size_t)(p & 63) * KDIM + j] : 0.f;
    w1pp[idx] = __float2bfloat16(v);
}

__global__ void build_w1ppT(const float* __restrict__ e1w, __hip_bfloat16* __restrict__ w1ppT)
{
    int idx = blockIdx.x * 256 + threadIdx.x;
    int n = idx >> 7, k = idx & 127;
    float v = ((n >> 10) == (k >> 6)) ? e1w[(size_t)(k & 63) * KDIM + n] : 0.f;
    w1ppT[idx] = __float2bfloat16(v);
}

__global__ void build_w2t(const float* __restrict__ qw, const float* __restrict__ kw,
                          const float* __restrict__ vw, const float* __restrict__ sw,
                          const float* __restrict__ qb, const float* __restrict__ kb,
                          const float* __restrict__ vb, const float* __restrict__ sb,
                          __hip_bfloat16* __restrict__ w2t, float* __restrict__ b2)
{
    int idx = blockIdx.x * 256 + threadIdx.x;
    int c = idx >> 11, d = idx & 2047;
    int g = c >> 6, j = c & 63;
    const float* w = (g == 0) ? qw : (g == 1) ? kw : (g == 2) ? vw : sw;
    w2t[idx] = __float2bfloat16(w[(size_t)d * 64 + j]);
    if (d == 0) {
        const float* b = (g == 0) ? qb : (g == 1) ? kb : (g == 2) ? vb : sb;
        b2[c] = b[j];
    }
}

// ------------------------------------------------------------------
// edge kernels (CSR slot order)
// ------------------------------------------------------------------
__global__ __launch_bounds__(256) void alpha1_kernel(
    const __hip_bfloat16* __restrict__ q1b, const __hip_bfloat16* __restrict__ k1b,
    const float* __restrict__ P1, const float* __restrict__ ea,
    const int* __restrict__ ei, const int* __restrict__ elist,
    float* __restrict__ alpha)
{
    int i = blockIdx.x * 4 + (threadIdx.x >> 6);
    int lane = threadIdx.x & 63;
    int e = elist[i];
    int src = ei[e], dst = ei[NE + e];
    float eaj = ea[(size_t)e * 64 + lane];
    #pragma unroll
    for (int h = 0; h < 2; ++h) {
        const __hip_bfloat16* qh = q1b + (size_t)dst * HC1 + h * 1024 + lane * 16;
        const __hip_bfloat16* kh = k1b + (size_t)src * HC1 + h * 1024 + lane * 16;
        bhalf8 qa = *(const bhalf8*)qh, qc = *(const bhalf8*)(qh + 8);
        bhalf8 ka = *(const bhalf8*)kh, kc = *(const bhalf8*)(kh + 8);
        float s = 0.f;
        #pragma unroll
        for (int j = 0; j < 8; ++j) s += bf2f(qa[j]) * bf2f(ka[j]);
        #pragma unroll
        for (int j = 0; j < 8; ++j) s += bf2f(qc[j]) * bf2f(kc[j]);
        s += eaj * P1[(size_t)dst * 128 + h * 64 + lane];
        #pragma unroll
        for (int off = 32; off; off >>= 1) s += __shfl_xor(s, off);
        if (lane == 0) alpha[(size_t)i * 2 + h] = s * 0.03125f;
    }
}

__global__ void softmax_kernel(const int* __restrict__ rowptr,
                               float* __restrict__ alpha, int H)
{
    int n = blockIdx.x * 256 + threadIdx.x;
    if (n >= NN) return;
    int s0 = rowptr[n], s1 = rowptr[n + 1];
    for (int h = 0; h < H; ++h) {
        float m = -1e30f;
        for (int i = s0; i < s1; ++i)
            m = fmaxf(m, alpha[(size_t)i * H + h]);
        float ssum = 0.f;
        for (int i = s0; i < s1; ++i) {
            float ex = __expf(alpha[(size_t)i * H + h] - m);
            alpha[(size_t)i * H + h] = ex;
            ssum += ex;
        }
        float inv = 1.f / (ssum + 1e-16f);
        for (int i = s0; i < s1; ++i)
            alpha[(size_t)i * H + h] *= inv;
    }
}

__global__ __launch_bounds__(128) void r1_kernel(
    const int* __restrict__ rowptr, const int* __restrict__ elist,
    const float* __restrict__ attn, const float* __restrict__ ea,
    __hip_bfloat16* __restrict__ R1)
{
    int n = blockIdx.x;
    int p = threadIdx.x;
    int h = p >> 6, j = p & 63;
    int s0 = rowptr[n], s1 = rowptr[n + 1];
    float r = 0.f;
    for (int i = s0; i < s1; ++i) {
        int e = elist[i];
        r += attn[(size_t)i * 2 + h] * ea[(size_t)e * 64 + j];
    }
    R1[(size_t)n * 128 + p] = __float2bfloat16(r);
}

__global__ __launch_bounds__(256) void agg1_kernel(
    const int* __restrict__ rowptr, const int* __restrict__ elist,
    const int* __restrict__ ei, const float* __restrict__ attn,
    const __hip_bfloat16* __restrict__ v1b, float* __restrict__ h1)
{
    int n = blockIdx.x;
    int c0 = threadIdx.x * 8;
    int h = c0 >> 10;
    int s0 = rowptr[n], s1 = rowptr[n + 1];
    float acc[8];
    const float4 p0 = *(const float4*)&h1[(size_t)n * HC1 + c0];
    const float4 p1 = *(const float4*)&h1[(size_t)n * HC1 + c0 + 4];
    acc[0] = p0.x; acc[1] = p0.y; acc[2] = p0.z; acc[3] = p0.w;
    acc[4] = p1.x; acc[5] = p1.y; acc[6] = p1.z; acc[7] = p1.w;
    for (int i = s0; i < s1; ++i) {
        float at = attn[(size_t)i * 2 + h];
        bhalf8 v = *(const bhalf8*)&v1b[(size_t)ei[elist[i]] * HC1 + c0];
        #pragma unroll
        for (int j = 0; j < 8; ++j) acc[j] += at * bf2f(v[j]);
    }
    float4 o0 = make_float4(acc[0], acc[1], acc[2], acc[3]);
    float4 o1 = make_float4(acc[4], acc[5], acc[6], acc[7]);
    *(float4*)&h1[(size_t)n * HC1 + c0] = o0;
    *(float4*)&h1[(size_t)n * HC1 + c0 + 4] = o1;
}

__global__ __launch_bounds__(256) void alpha2_kernel(
    const float* __restrict__ qkvs2, const float* __restrict__ E2,
    const int* __restrict__ ei, const int* __restrict__ elist,
    float* __restrict__ alpha2)
{
    int i = blockIdx.x * 4 + (threadIdx.x >> 6);
    int lane = threadIdx.x & 63;
    int e = elist[i];
    int src = ei[e], dst = ei[NE + e];
    float q = qkvs2[(size_t)dst * 256 + lane];
    float k = qkvs2[(size_t)src * 256 + 64 + lane];
    float s = q * (k + E2[(size_t)e * 64 + lane]);
    #pragma unroll
    for (int off = 32; off; off >>= 1) s += __shfl_xor(s, off);
    if (lane == 0) alpha2[i] = s * 0.125f;
}

__global__ __launch_bounds__(64) void agg2_kernel(
    const int* __restrict__ rowptr, const int* __restrict__ elist,
    const int* __restrict__ ei, const float* __restrict__ attn2,
    const float* __restrict__ qkvs2, const float* __restrict__ E2,
    float* __restrict__ out)
{
    int n = blockIdx.x;
    int c = threadIdx.x;
    int s0 = rowptr[n], s1 = rowptr[n + 1];
    float acc = qkvs2[(size_t)n * 256 + 192 + c];
    for (int i = s0; i < s1; ++i) {
        int e = elist[i];
        acc += attn2[i] * (qkvs2[(size_t)ei[e] * 256 + 128 + c] + E2[(size_t)e * 64 + c]);
    }
    out[(size_t)n * 64 + c] = fmaxf(acc, 0.f);
}

// ------------------------------------------------------------------
extern "C" void kernel_launch(void* const* d_in, const int* in_sizes, int n_in,
                              void* d_out, int out_size, void* d_ws, size_t ws_size,
                              hipStream_t stream)
{
    const float* x   = (const float*)d_in[0];
    const int*   ei  = (const int*)d_in[1];
    const float* ea  = (const float*)d_in[2];
    const float* q1w = (const float*)d_in[3];
    const float* q1b = (const float*)d_in[4];
    const float* k1w = (const float*)d_in[5];
    const float* k1b = (const float*)d_in[6];
    const float* v1w = (const float*)d_in[7];
    const float* v1b = (const float*)d_in[8];
    const float* e1w = (const float*)d_in[9];
    const float* s1w = (const float*)d_in[10];
    const float* s1b = (const float*)d_in[11];
    const float* q2w = (const float*)d_in[12];
    const float* q2b = (const float*)d_in[13];
    const float* k2w = (const float*)d_in[14];
    const float* k2b = (const float*)d_in[15];
    const float* v2w = (const float*)d_in[16];
    const float* v2b = (const float*)d_in[17];
    const float* e2w = (const float*)d_in[18];
    const float* s2w = (const float*)d_in[19];
    const float* s2b = (const float*)d_in[20];
    float* out = (float*)d_out;

    char* base = (char*)d_ws;
    size_t off = 0;
    auto alloc = [&](size_t nbytes) {
        size_t o = off; off += (nbytes + 255) & ~(size_t)255; return o;
    };
    const size_t xb_off   = alloc((size_t)MPAD * KDIM * 2);      // bf16 input (reused as h1b)
    const size_t wcat_off = alloc((size_t)4 * KDIM * KDIM * 2);  // fused weights (reused: Cpart+w2t)
    __hip_bfloat16* xb    = (__hip_bfloat16*)(base + xb_off);
    __hip_bfloat16* wcat  = (__hip_bfloat16*)(base + wcat_off);
    __hip_bfloat16* h1b   = xb;                                   // alias (xb dead after gemm128)
    float*          Cpart = (float*)(base + wcat_off);            // alias (wcat dead after gemm128)
    __hip_bfloat16* w2t   = (__hip_bfloat16*)(base + wcat_off + (size_t)29 * 1024 * 1024);

    __hip_bfloat16* q1bb  = (__hip_bfloat16*)(base + alloc((size_t)MPAD * HC1 * 2));
    __hip_bfloat16* k1bb  = (__hip_bfloat16*)(base + alloc((size_t)MPAD * HC1 * 2));
    __hip_bfloat16* v1bb  = (__hip_bfloat16*)(base + alloc((size_t)MPAD * HC1 * 2));
    float*          h1    = (float*)(base + alloc((size_t)MPAD * HC1 * 4));
    float*          bcat  = (float*)(base + alloc((size_t)4 * KDIM * 4));
    float*          P1    = (float*)(base + alloc((size_t)MPAD * 128 * 4));
    __hip_bfloat16* R1b   = (__hip_bfloat16*)(base + alloc((size_t)MPAD * 128 * 2));
    __hip_bfloat16* w1pp  = (__hip_bfloat16*)(base + alloc((size_t)128 * KDIM * 2));
    __hip_bfloat16* w1ppT = (__hip_bfloat16*)(base + alloc((size_t)KDIM * 128 * 2));
    float*          b2    = (float*)(base + alloc(256 * 4));
    float*          qkvs2 = (float*)(base + alloc((size_t)MPAD * 256 * 4));
    float*          E2    = (float*)(base + alloc((size_t)NE * 64 * 4));
    float*          at1   = (float*)(base + alloc((size_t)NE * 2 * 4));
    float*          at2   = (float*)(base + alloc((size_t)NE * 4));
    int* deg    = (int*)(base + alloc((size_t)NN * 4));
    int* fill   = (int*)(base + alloc((size_t)NN * 4));
    int* rowptr = (int*)(base + alloc((size_t)(NN + 1) * 4));
    int* elist  = (int*)(base + alloc((size_t)NE * 4));

    // --- CSR build ---
    hipMemsetAsync(deg, 0, sizeof(int) * 2 * NN, stream);
    count_deg<<<(NE + 255) / 256, 256, 0, stream>>>(ei, deg);
    scan_kernel<<<1, 1024, 0, stream>>>(deg, rowptr);
    fill_csr<<<(NE + 255) / 256, 256, 0, stream>>>(ei, rowptr, fill, elist);
    sort_csr<<<(NN + 255) / 256, 256, 0, stream>>>(rowptr, elist);

    // --- input conversion + fused weight prep ---
    const int cvblk = (MPAD * KDIM / 4) / 256;
    cvt_pad_bf16<<<cvblk, 256, 0, stream>>>(x, xb, 0);
    transpose_cvt4<<<dim3(KDIM / 32, KDIM / 32, 4), 256, 0, stream>>>(q1w, k1w, v1w, s1w, wcat);
    build_bcat<<<(4 * KDIM) / 256, 256, 0, stream>>>(q1b, k1b, v1b, s1b, bcat);

    // --- fused layer-1 projections: one 3456-block 128^2 dispatch ---
    gemm128_fused<<<3456, 256, 0, stream>>>(xb, wcat, bcat, q1bb, k1bb, v1bb, h1);

    // --- P1 = q1 @ W1p (split-K 4) ---
    build_w1pp<<<(128 * KDIM) / 256, 256, 0, stream>>>(e1w, w1pp);
    build_w1ppT<<<(KDIM * 128) / 256, 256, 0, stream>>>(e1w, w1ppT);
    gemm_bf16<<<dim3(1, MPAD / 128, 4), 256, 0, stream>>>(q1bb, w1pp, nullptr, Cpart, nullptr,
                                                          MPAD, 128, KDIM, 0);
    reduce4<<<(MPAD * 128) / 256, 256, 0, stream>>>(Cpart, (size_t)MPAD * 128, nullptr, 0,
                                                    P1, MPAD * 128);

    // --- attention layer 1 (slot-ordered) ---
    alpha1_kernel<<<NE / 4, 256, 0, stream>>>(q1bb, k1bb, P1, ea, ei, elist, at1);
    softmax_kernel<<<(NN + 255) / 256, 256, 0, stream>>>(rowptr, at1, 2);
    r1_kernel<<<NN, 128, 0, stream>>>(rowptr, elist, at1, ea, R1b);
    agg1_kernel<<<NN, 256, 0, stream>>>(rowptr, elist, ei, at1, v1bb, h1);
    // R1 @ W1pp, += h1, relu, write bf16 h1b directly (no fp32 writeback)
    gemm_bf16<<<dim3(HC1 / 128, MPAD / 128), 256, 0, stream>>>(R1b, w1ppT, nullptr, h1, h1b,
                                                               MPAD, HC1, 128, 2 | 4 | 8);

    // --- layer 2 projections (split-K 4) ---
    build_w2t<<<(256 * KDIM) / 256, 256, 0, stream>>>(q2w, k2w, v2w, s2w, q2b, k2b, v2b, s2b,
                                                      w2t, b2);
    gemm_bf16<<<dim3(2, MPAD / 128, 4), 256, 0, stream>>>(h1b, w2t, nullptr, Cpart, nullptr,
                                                          MPAD, 256, KDIM, 0);
    reduce4<<<(MPAD * 256) / 256, 256, 0, stream>>>(Cpart, (size_t)MPAD * 256, b2, 255,
                                                    qkvs2, MPAD * 256);
    gemm_tile<<<dim3(1, NE / 64), 256, 0, stream>>>(ea, e2w, nullptr, E2, NE, 64, 64, 0);

    // --- attention layer 2 (slot-ordered) ---
    alpha2_kernel<<<NE / 4, 256, 0, stream>>>(qkvs2, E2, ei, elist, at2);
    softmax_kernel<<<(NN + 255) / 256, 256, 0, stream>>>(rowptr, at2, 1);
    agg2_kernel<<<NN, 64, 0, stream>>>(rowptr, elist, ei, at2, qkvs2, E2, out);

    (void)in_sizes; (void)n_in; (void)out_size; (void)ws_size;
}

// Round 7
// 526.620 us; speedup vs baseline: 6.8632x; 1.0631x over previous
//
#include <hip/hip_runtime.h>
#include <hip/hip_bf16.h>
#include <cstdint>
#include <cstddef>

#define NN    6720     // nodes
#define MPAD  6912     // 27 * 256
#define NE    33600    // edges
#define KDIM  2048
#define HC1   2048

typedef __attribute__((ext_vector_type(8))) short bhalf8;
typedef __attribute__((ext_vector_type(4))) short bhalf4;
typedef __attribute__((ext_vector_type(4))) float fx4;

__device__ __forceinline__ float bf2f(short s) {
    union { unsigned int u; float f; } c;
    c.u = ((unsigned int)(unsigned short)s) << 16;
    return c.f;
}

__device__ __forceinline__ void gload16(const __hip_bfloat16* g, void* lds)
{
    __builtin_amdgcn_global_load_lds(
        (const __attribute__((address_space(1))) unsigned int*)g,
        (__attribute__((address_space(3))) unsigned int*)lds,
        16, 0, 0);
}

#define CFENCE asm volatile("" ::: "memory")

// ------------------------------------------------------------------
// 256x128-tile 4-wave fused projection GEMM. Wave tile 128x64 (8x4
// frags -> 0.375 ds_read_b128/MFMA, vs 0.5 at 64x64). BK=32, 3-deep
// LDS ring (A 3x16KB + B 3x8KB = 72KB -> 2 blocks/CU), counted
// vmcnt(12/6/0), setprio, XOR-swizzled LDS, XCD-striped block map
// (XCD = bid&7 owns bx panels [8x,8x+8): B working set 4MB = L2).
// Epilogue: 272B-padded LDS scratch (conflict-free stores/reads),
// full-line global stores.
// ------------------------------------------------------------------
__global__ __launch_bounds__(256, 2) void gemm256x128_fused(
    const __hip_bfloat16* __restrict__ A,
    const __hip_bfloat16* __restrict__ Bt,
    const float* __restrict__ bcat,
    __hip_bfloat16* __restrict__ oq,
    __hip_bfloat16* __restrict__ ok,
    __hip_bfloat16* __restrict__ ov,
    float* __restrict__ oh)
{
    __shared__ alignas(16) char Lds[73728];   // A ring 3x16KB @0 | B ring 3x8KB @49152

    // XCD-locality map: 1728 = 8 XCD * 216. XCD = bid&7 owns 8 bx panels.
    const int bid = blockIdx.x;
    const int i0  = bid >> 3;
    const int bx  = (bid & 7) * 8 + (i0 & 7);   // N: 64 panels of 128
    const int by  = i0 >> 3;                    // M: 27 panels of 256

    const int tid  = threadIdx.x;
    const int w    = tid >> 6;        // 0..3
    const int lane = tid & 63;
    const int wm = w >> 1, wn = w & 1;    // 2x2 waves, wave tile 128x64
    const int rowA = by * 256;
    const int rowB = bx * 128;

    // staging: A wave w covers rows w*64..+63 (4 gload16), B rows w*32..+31 (2).
    // Pre-swizzled source: LDS(row, phys u) = global unit u ^ ((row>>1)&3).
    const int sug = ((lane & 3) ^ ((lane >> 3) & 3)) << 3;
    const __hip_bfloat16* Ag0 = A  + (size_t)(rowA + w * 64 + (lane >> 2)) * KDIM + sug;
    const __hip_bfloat16* Bg0 = Bt + (size_t)(rowB + w * 32 + (lane >> 2)) * KDIM + sug;

    // fragment read: row = base16 + (lane&15); byte = row*64 + rds
    const int rds = (((lane >> 4) ^ (((lane & 15) >> 1) & 3)) << 4);

    fx4 acc[8][4] = {};

#define STAGE(T)                                                          \
    { const int s_ = (T) % 3; const int k0_ = (T) * 32;                   \
      char* ab_ = Lds + s_ * 16384 + w * 4096;                            \
      char* bb_ = Lds + 49152 + s_ * 8192 + w * 2048;                     \
      gload16(Ag0 + k0_, ab_);                                            \
      gload16(Ag0 + k0_ + 16 * KDIM, ab_ + 1024);                         \
      gload16(Ag0 + k0_ + 32 * KDIM, ab_ + 2048);                         \
      gload16(Ag0 + k0_ + 48 * KDIM, ab_ + 3072);                         \
      gload16(Bg0 + k0_, bb_);                                            \
      gload16(Bg0 + k0_ + 16 * KDIM, bb_ + 1024); }

#define TILE(T, VM, DOSTAGE)                                              \
    { if (DOSTAGE) { STAGE((T) + 2); }                                    \
      asm volatile("s_waitcnt vmcnt(" VM ")" ::: "memory");               \
      __builtin_amdgcn_s_barrier(); CFENCE;                               \
      const int s_ = (T) % 3;                                             \
      const char* ap_ = Lds + s_ * 16384;                                 \
      const char* bp_ = Lds + 49152 + s_ * 8192;                          \
      bhalf8 af_[8], bf_[4];                                              \
      _Pragma("unroll")                                                   \
      for (int nj = 0; nj < 4; ++nj)                                      \
          bf_[nj] = *(const bhalf8*)(bp_ + (wn * 64 + nj * 16 + (lane & 15)) * 64 + rds); \
      _Pragma("unroll")                                                   \
      for (int mi = 0; mi < 8; ++mi)                                      \
          af_[mi] = *(const bhalf8*)(ap_ + (wm * 128 + mi * 16 + (lane & 15)) * 64 + rds); \
      __builtin_amdgcn_s_setprio(1);                                      \
      _Pragma("unroll")                                                   \
      for (int mi = 0; mi < 8; ++mi)                                      \
          _Pragma("unroll")                                               \
          for (int nj = 0; nj < 4; ++nj)                                  \
              acc[mi][nj] = __builtin_amdgcn_mfma_f32_16x16x32_bf16(      \
                  af_[mi], bf_[nj], acc[mi][nj], 0, 0, 0);                \
      __builtin_amdgcn_s_setprio(0); CFENCE;                              \
      __builtin_amdgcn_s_barrier(); CFENCE; }

    STAGE(0); STAGE(1);
    for (int t = 0; t < (KDIM / 32) - 2; ++t) {
        TILE(t, "12", 1);
    }
    TILE((KDIM / 32) - 2, "6", 0);
    TILE((KDIM / 32) - 1, "0", 0);

#undef TILE
#undef STAGE

    // ---- epilogue: 272B-padded LDS scratch, full-line stores ----
    const int gcol = rowB + wn * 64;        // global col base of wave tile
    const int seg  = gcol >> 11;            // 0:q 1:k 2:v 3:skip(fp32)
    const int lcol = gcol & 2047;
    float bv[4];
    #pragma unroll
    for (int nj = 0; nj < 4; ++nj) bv[nj] = bcat[gcol + nj * 16 + (lane & 15)];
    char* scr = Lds + w * 8704;             // wave-private 32 rows x 272B
    const int growA = rowA + wm * 128;

    #pragma unroll
    for (int c = 0; c < 4; ++c) {           // 4 chunks of 32 rows
        #pragma unroll
        for (int m2 = 0; m2 < 2; ++m2) {
            const int mi = c * 2 + m2;
            #pragma unroll
            for (int nj = 0; nj < 4; ++nj) {
                const int cl = nj * 16 + (lane & 15);
                #pragma unroll
                for (int i2 = 0; i2 < 4; ++i2) {
                    const int rl = m2 * 16 + ((lane >> 4) << 2) + i2;
                    *(float*)(scr + rl * 272 + cl * 4) = acc[mi][nj][i2] + bv[nj];
                }
            }
        }
        asm volatile("s_waitcnt lgkmcnt(0)" ::: "memory");
        CFENCE;
        const int rrow = (lane >> 4);       // 0..3
        const int u    = lane & 15;         // 0..15
        if (seg < 3) {
            __hip_bfloat16* dst = (seg == 0) ? oq : (seg == 1) ? ok : ov;
            #pragma unroll
            for (int p = 0; p < 8; ++p) {
                const int row = p * 4 + rrow;
                const float4 f = *(const float4*)(scr + row * 272 + u * 16);
                bhalf4 tb;
                tb[0] = (short)__bfloat16_as_ushort(__float2bfloat16(f.x));
                tb[1] = (short)__bfloat16_as_ushort(__float2bfloat16(f.y));
                tb[2] = (short)__bfloat16_as_ushort(__float2bfloat16(f.z));
                tb[3] = (short)__bfloat16_as_ushort(__float2bfloat16(f.w));
                *(bhalf4*)&dst[(size_t)(growA + c * 32 + row) * 2048 + lcol + u * 4] = tb;
            }
        } else {
            #pragma unroll
            for (int p = 0; p < 8; ++p) {
                const int row = p * 4 + rrow;
                const float4 f = *(const float4*)(scr + row * 272 + u * 16);
                *(float4*)&oh[(size_t)(growA + c * 32 + row) * 2048 + lcol + u * 4] = f;
            }
        }
        asm volatile("s_waitcnt lgkmcnt(0)" ::: "memory");
        CFENCE;
    }
}

// ------------------------------------------------------------------
// 128x128 bf16 MFMA GEMM (4 waves), optional split-K via blockIdx.z.
// C[M,N] = A[M,K] @ Bt[N,K]^T (+bias)(+=C). z>0 writes C + z*M*N.
// flags: 1=+bias  2=+=C(read)  4=relu  8=skip C writeback
// ------------------------------------------------------------------
__global__ __launch_bounds__(256) void gemm_bf16(
    const __hip_bfloat16* __restrict__ A,
    const __hip_bfloat16* __restrict__ Bt,
    const float* __restrict__ bias,
    float* __restrict__ C,
    __hip_bfloat16* __restrict__ Cb,
    int M, int N, int K, int flags)
{
    __shared__ alignas(16) __hip_bfloat16 Asm[128 * 64];
    __shared__ alignas(16) __hip_bfloat16 Bsm[128 * 64];
    const int tid  = threadIdx.x;
    const int w    = tid >> 6;
    const int lane = tid & 63;
    const int wr = w >> 1, wc = w & 1;
    const int rowA = blockIdx.y * 128;
    const int rowB = blockIdx.x * 128;
    const int klen = K / gridDim.z;
    const int kbeg = blockIdx.z * klen;

    const int srow = w * 32 + (lane >> 3);
    const int ug8  = ((lane & 7) ^ (lane >> 3)) << 3;
    const __hip_bfloat16* Ag = A  + (size_t)(rowA + srow) * K + ug8;
    const __hip_bfloat16* Bg = Bt + (size_t)(rowB + srow) * K + ug8;
    char* AsBase = (char*)Asm + w * 4096;
    char* BsBase = (char*)Bsm + w * 4096;

    fx4 acc[4][4] = {};

    const int fra = wr * 64 + (lane & 15);
    const int frb = wc * 64 + (lane & 15);
    const int kb  = (lane >> 4) << 4;
    const int swz = (lane & 7) << 4;

    for (int k0 = kbeg; k0 < kbeg + klen; k0 += 64) {
        __syncthreads();
        #pragma unroll
        for (int j = 0; j < 4; ++j) {
            gload16(Ag + (size_t)j * 8 * K + k0, AsBase + j * 1024);
            gload16(Bg + (size_t)j * 8 * K + k0, BsBase + j * 1024);
        }
        __syncthreads();
        #pragma unroll
        for (int kk = 0; kk < 2; ++kk) {
            const int cb = kk * 64 + kb;
            bhalf8 af[4], bfr[4];
            #pragma unroll
            for (int mi = 0; mi < 4; ++mi)
                af[mi] = *(const bhalf8*)((const char*)Asm + (fra + mi * 16) * 128 + (cb ^ swz));
            #pragma unroll
            for (int nj = 0; nj < 4; ++nj)
                bfr[nj] = *(const bhalf8*)((const char*)Bsm + (frb + nj * 16) * 128 + (cb ^ swz));
            #pragma unroll
            for (int mi = 0; mi < 4; ++mi)
                #pragma unroll
                for (int nj = 0; nj < 4; ++nj)
                    acc[mi][nj] = __builtin_amdgcn_mfma_f32_16x16x32_bf16(
                        af[mi], bfr[nj], acc[mi][nj], 0, 0, 0);
        }
    }

    float* Cz = C ? C + (size_t)blockIdx.z * ((size_t)M * N) : nullptr;
    #pragma unroll
    for (int nj = 0; nj < 4; ++nj) {
        const int ccol = rowB + wc * 64 + nj * 16 + (lane & 15);
        const float bv = (flags & 1) ? bias[ccol] : 0.f;
        #pragma unroll
        for (int mi = 0; mi < 4; ++mi) {
            const int crow0 = rowA + wr * 64 + mi * 16 + ((lane >> 4) << 2);
            #pragma unroll
            for (int i = 0; i < 4; ++i) {
                size_t idx = (size_t)(crow0 + i) * N + ccol;
                float v = acc[mi][nj][i] + bv;
                if (flags & 2) v += Cz[idx];
                if (flags & 4) v = fmaxf(v, 0.f);
                if (Cz && !(flags & 8)) Cz[idx] = v;
                if (Cb) Cb[idx] = __float2bfloat16(v);
            }
        }
    }
}

// dst[i] = sum_z parts[z*stride + i] (+ bias[i & colmask])
__global__ void reduce4(const float* __restrict__ parts, size_t stride,
                        const float* __restrict__ bias, int colmask,
                        float* __restrict__ dst, int n)
{
    int i = blockIdx.x * 256 + threadIdx.x;
    if (i >= n) return;
    float v = parts[i] + parts[stride + i] + parts[2 * stride + i] + parts[3 * stride + i];
    if (bias) v += bias[i & colmask];
    dst[i] = v;
}

// ------------------------------------------------------------------
// fp32 tiled GEMM (kept for tiny E2 = ea @ e2w)
// ------------------------------------------------------------------
__global__ __launch_bounds__(256) void gemm_tile(
    const float* __restrict__ A, const float* __restrict__ B,
    const float* __restrict__ bias, float* __restrict__ C,
    int M, int N, int K, int flags)
{
    __shared__ float As[16][68];
    __shared__ float Bs[16][64];
    const int tid = threadIdx.x;
    const int bx = blockIdx.x, by = blockIdx.y;
    const int tx = tid & 15, ty = tid >> 4;
    const int arow = tid >> 2, acol = (tid & 3) << 2;
    const int brow = tid >> 4, bcol = (tid & 15) << 2;
    const float* Ag = A + (size_t)(by * 64 + arow) * K + acol;
    const float* Bg = B + (size_t)brow * N + bx * 64 + bcol;
    float acc[4][4] = {};
    for (int k0 = 0; k0 < K; k0 += 16) {
        const float4 av = *(const float4*)(Ag + k0);
        const float4 bv = *(const float4*)(Bg + (size_t)k0 * N);
        __syncthreads();
        As[acol + 0][arow] = av.x;
        As[acol + 1][arow] = av.y;
        As[acol + 2][arow] = av.z;
        As[acol + 3][arow] = av.w;
        *(float4*)&Bs[brow][bcol] = bv;
        __syncthreads();
        #pragma unroll
        for (int kk = 0; kk < 16; ++kk) {
            const float4 a4 = *(const float4*)&As[kk][ty << 2];
            const float4 b4 = *(const float4*)&Bs[kk][tx << 2];
            const float a[4] = {a4.x, a4.y, a4.z, a4.w};
            const float b[4] = {b4.x, b4.y, b4.z, b4.w};
            #pragma unroll
            for (int i = 0; i < 4; ++i)
                #pragma unroll
                for (int j = 0; j < 4; ++j)
                    acc[i][j] += a[i] * b[j];
        }
    }
    const int crow = by * 64 + (ty << 2);
    const int ccol = bx * 64 + (tx << 2);
    float4 b4 = make_float4(0.f, 0.f, 0.f, 0.f);
    if (flags & 1) b4 = *(const float4*)(bias + ccol);
    #pragma unroll
    for (int i = 0; i < 4; ++i) {
        float* cp = C + (size_t)(crow + i) * N + ccol;
        float4 v;
        v.x = acc[i][0] + b4.x; v.y = acc[i][1] + b4.y;
        v.z = acc[i][2] + b4.z; v.w = acc[i][3] + b4.w;
        if (flags & 2) {
            const float4 o = *(const float4*)cp;
            v.x += o.x; v.y += o.y; v.z += o.z; v.w += o.w;
        }
        *(float4*)cp = v;
    }
}

// ------------------------------------------------------------------
// CSR build
// ------------------------------------------------------------------
__global__ void count_deg(const int* __restrict__ ei, int* __restrict__ deg)
{
    int e = blockIdx.x * 256 + threadIdx.x;
    if (e < NE) atomicAdd(&deg[ei[NE + e]], 1);
}

__global__ __launch_bounds__(1024) void scan_kernel(const int* __restrict__ deg,
                                                    int* __restrict__ rowptr)
{
    __shared__ int s[1024];
    const int t = threadIdx.x;
    const int base = t * 7;
    int loc[7];
    int sum = 0;
    #pragma unroll
    for (int i = 0; i < 7; ++i) {
        int idx = base + i;
        int v = (idx < NN) ? deg[idx] : 0;
        loc[i] = v; sum += v;
    }
    s[t] = sum;
    __syncthreads();
    for (int off = 1; off < 1024; off <<= 1) {
        int v = (t >= off) ? s[t - off] : 0;
        __syncthreads();
        s[t] += v;
        __syncthreads();
    }
    int running = s[t] - sum;
    #pragma unroll
    for (int i = 0; i < 7; ++i) {
        int idx = base + i;
        if (idx <= NN) rowptr[idx] = running;
        if (idx < NN) running += loc[i];
    }
}

__global__ void fill_csr(const int* __restrict__ ei, const int* __restrict__ rowptr,
                         int* __restrict__ fillctr, int* __restrict__ elist)
{
    int e = blockIdx.x * 256 + threadIdx.x;
    if (e >= NE) return;
    int d = ei[NE + e];
    int pos = atomicAdd(&fillctr[d], 1);
    elist[rowptr[d] + pos] = e;
}

__global__ void sort_csr(const int* __restrict__ rowptr, int* __restrict__ elist)
{
    int n = blockIdx.x * 256 + threadIdx.x;
    if (n >= NN) return;
    int s0 = rowptr[n], s1 = rowptr[n + 1];
    for (int i = s0 + 1; i < s1; ++i) {
        int v = elist[i];
        int j = i - 1;
        while (j >= s0 && elist[j] > v) { elist[j + 1] = elist[j]; --j; }
        elist[j + 1] = v;
    }
}

// ------------------------------------------------------------------
// conversions / weight prep
// ------------------------------------------------------------------
__global__ void cvt_pad_bf16(const float* __restrict__ src, __hip_bfloat16* __restrict__ dst,
                             int relu)
{
    size_t i = (size_t)(blockIdx.x * 256 + threadIdx.x) * 4;
    int row = (int)(i >> 11);
    float4 v = make_float4(0.f, 0.f, 0.f, 0.f);
    if (row < NN) v = *(const float4*)&src[i];
    if (relu) {
        v.x = fmaxf(v.x, 0.f); v.y = fmaxf(v.y, 0.f);
        v.z = fmaxf(v.z, 0.f); v.w = fmaxf(v.w, 0.f);
    }
    dst[i + 0] = __float2bfloat16(v.x);
    dst[i + 1] = __float2bfloat16(v.y);
    dst[i + 2] = __float2bfloat16(v.z);
    dst[i + 3] = __float2bfloat16(v.w);
}

// 4 transposes in one dispatch: Bt[z][n][k] = bf16(Wz[k][n])
__global__ __launch_bounds__(256) void transpose_cvt4(
    const float* __restrict__ W0, const float* __restrict__ W1,
    const float* __restrict__ W2, const float* __restrict__ W3,
    __hip_bfloat16* __restrict__ dst)
{
    const float* W = (blockIdx.z == 0) ? W0 : (blockIdx.z == 1) ? W1
                   : (blockIdx.z == 2) ? W2 : W3;
    __hip_bfloat16* Bt = dst + (size_t)blockIdx.z * KDIM * KDIM;
    __shared__ float t[32][33];
    int kb = blockIdx.y * 32, nb = blockIdx.x * 32;
    int tx = threadIdx.x & 31, ty = threadIdx.x >> 5;
    #pragma unroll
    for (int i = 0; i < 32; i += 8)
        t[ty + i][tx] = W[(size_t)(kb + ty + i) * KDIM + nb + tx];
    __syncthreads();
    #pragma unroll
    for (int i = 0; i < 32; i += 8)
        Bt[(size_t)(nb + ty + i) * KDIM + kb + tx] = __float2bfloat16(t[tx][ty + i]);
}

__global__ void build_bcat(const float* __restrict__ q1b, const float* __restrict__ k1b,
                           const float* __restrict__ v1b, const float* __restrict__ s1b,
                           float* __restrict__ bcat)
{
    int i = blockIdx.x * 256 + threadIdx.x;
    if (i >= 4 * KDIM) return;
    int seg = i >> 11, j = i & 2047;
    const float* b = (seg == 0) ? q1b : (seg == 1) ? k1b : (seg == 2) ? v1b : s1b;
    bcat[i] = b[j];
}

__global__ void build_w1pp(const float* __restrict__ e1w, __hip_bfloat16* __restrict__ w1pp)
{
    int idx = blockIdx.x * 256 + threadIdx.x;
    int p = idx >> 11, j = idx & 2047;
    float v = ((j >> 10) == (p >> 6)) ? e1w[(size_t)(p & 63) * KDIM + j] : 0.f;
    w1pp[idx] = __float2bfloat16(v);
}

__global__ void build_w1ppT(const float* __restrict__ e1w, __hip_bfloat16* __restrict__ w1ppT)
{
    int idx = blockIdx.x * 256 + threadIdx.x;
    int n = idx >> 7, k = idx & 127;
    float v = ((n >> 10) == (k >> 6)) ? e1w[(size_t)(k & 63) * KDIM + n] : 0.f;
    w1ppT[idx] = __float2bfloat16(v);
}

__global__ void build_w2t(const float* __restrict__ qw, const float* __restrict__ kw,
                          const float* __restrict__ vw, const float* __restrict__ sw,
                          const float* __restrict__ qb, const float* __restrict__ kb,
                          const float* __restrict__ vb, const float* __restrict__ sb,
                          __hip_bfloat16* __restrict__ w2t, float* __restrict__ b2)
{
    int idx = blockIdx.x * 256 + threadIdx.x;
    int c = idx >> 11, d = idx & 2047;
    int g = c >> 6, j = c & 63;
    const float* w = (g == 0) ? qw : (g == 1) ? kw : (g == 2) ? vw : sw;
    w2t[idx] = __float2bfloat16(w[(size_t)d * 64 + j]);
    if (d == 0) {
        const float* b = (g == 0) ? qb : (g == 1) ? kb : (g == 2) ? vb : sb;
        b2[c] = b[j];
    }
}

// ------------------------------------------------------------------
// edge kernels (CSR slot order)
// ------------------------------------------------------------------
__global__ __launch_bounds__(256) void alpha1_kernel(
    const __hip_bfloat16* __restrict__ q1b, const __hip_bfloat16* __restrict__ k1b,
    const float* __restrict__ P1, const float* __restrict__ ea,
    const int* __restrict__ ei, const int* __restrict__ elist,
    float* __restrict__ alpha)
{
    int i = blockIdx.x * 4 + (threadIdx.x >> 6);
    int lane = threadIdx.x & 63;
    int e = elist[i];
    int src = ei[e], dst = ei[NE + e];
    float eaj = ea[(size_t)e * 64 + lane];
    #pragma unroll
    for (int h = 0; h < 2; ++h) {
        const __hip_bfloat16* qh = q1b + (size_t)dst * HC1 + h * 1024 + lane * 16;
        const __hip_bfloat16* kh = k1b + (size_t)src * HC1 + h * 1024 + lane * 16;
        bhalf8 qa = *(const bhalf8*)qh, qc = *(const bhalf8*)(qh + 8);
        bhalf8 ka = *(const bhalf8*)kh, kc = *(const bhalf8*)(kh + 8);
        float s = 0.f;
        #pragma unroll
        for (int j = 0; j < 8; ++j) s += bf2f(qa[j]) * bf2f(ka[j]);
        #pragma unroll
        for (int j = 0; j < 8; ++j) s += bf2f(qc[j]) * bf2f(kc[j]);
        s += eaj * P1[(size_t)dst * 128 + h * 64 + lane];
        #pragma unroll
        for (int off = 32; off; off >>= 1) s += __shfl_xor(s, off);
        if (lane == 0) alpha[(size_t)i * 2 + h] = s * 0.03125f;
    }
}

__global__ void softmax_kernel(const int* __restrict__ rowptr,
                               float* __restrict__ alpha, int H)
{
    int n = blockIdx.x * 256 + threadIdx.x;
    if (n >= NN) return;
    int s0 = rowptr[n], s1 = rowptr[n + 1];
    for (int h = 0; h < H; ++h) {
        float m = -1e30f;
        for (int i = s0; i < s1; ++i)
            m = fmaxf(m, alpha[(size_t)i * H + h]);
        float ssum = 0.f;
        for (int i = s0; i < s1; ++i) {
            float ex = __expf(alpha[(size_t)i * H + h] - m);
            alpha[(size_t)i * H + h] = ex;
            ssum += ex;
        }
        float inv = 1.f / (ssum + 1e-16f);
        for (int i = s0; i < s1; ++i)
            alpha[(size_t)i * H + h] *= inv;
    }
}

__global__ __launch_bounds__(128) void r1_kernel(
    const int* __restrict__ rowptr, const int* __restrict__ elist,
    const float* __restrict__ attn, const float* __restrict__ ea,
    __hip_bfloat16* __restrict__ R1)
{
    int n = blockIdx.x;
    int p = threadIdx.x;
    int h = p >> 6, j = p & 63;
    int s0 = rowptr[n], s1 = rowptr[n + 1];
    float r = 0.f;
    for (int i = s0; i < s1; ++i) {
        int e = elist[i];
        r += attn[(size_t)i * 2 + h] * ea[(size_t)e * 64 + j];
    }
    R1[(size_t)n * 128 + p] = __float2bfloat16(r);
}

__global__ __launch_bounds__(256) void agg1_kernel(
    const int* __restrict__ rowptr, const int* __restrict__ elist,
    const int* __restrict__ ei, const float* __restrict__ attn,
    const __hip_bfloat16* __restrict__ v1b, float* __restrict__ h1)
{
    int n = blockIdx.x;
    int c0 = threadIdx.x * 8;
    int h = c0 >> 10;
    int s0 = rowptr[n], s1 = rowptr[n + 1];
    float acc[8];
    const float4 p0 = *(const float4*)&h1[(size_t)n * HC1 + c0];
    const float4 p1 = *(const float4*)&h1[(size_t)n * HC1 + c0 + 4];
    acc[0] = p0.x; acc[1] = p0.y; acc[2] = p0.z; acc[3] = p0.w;
    acc[4] = p1.x; acc[5] = p1.y; acc[6] = p1.z; acc[7] = p1.w;
    for (int i = s0; i < s1; ++i) {
        float at = attn[(size_t)i * 2 + h];
        bhalf8 v = *(const bhalf8*)&v1b[(size_t)ei[elist[i]] * HC1 + c0];
        #pragma unroll
        for (int j = 0; j < 8; ++j) acc[j] += at * bf2f(v[j]);
    }
    float4 o0 = make_float4(acc[0], acc[1], acc[2], acc[3]);
    float4 o1 = make_float4(acc[4], acc[5], acc[6], acc[7]);
    *(float4*)&h1[(size_t)n * HC1 + c0] = o0;
    *(float4*)&h1[(size_t)n * HC1 + c0 + 4] = o1;
}

__global__ __launch_bounds__(256) void alpha2_kernel(
    const float* __restrict__ qkvs2, const float* __restrict__ E2,
    const int* __restrict__ ei, const int* __restrict__ elist,
    float* __restrict__ alpha2)
{
    int i = blockIdx.x * 4 + (threadIdx.x >> 6);
    int lane = threadIdx.x & 63;
    int e = elist[i];
    int src = ei[e], dst = ei[NE + e];
    float q = qkvs2[(size_t)dst * 256 + lane];
    float k = qkvs2[(size_t)src * 256 + 64 + lane];
    float s = q * (k + E2[(size_t)e * 64 + lane]);
    #pragma unroll
    for (int off = 32; off; off >>= 1) s += __shfl_xor(s, off);
    if (lane == 0) alpha2[i] = s * 0.125f;
}

__global__ __launch_bounds__(64) void agg2_kernel(
    const int* __restrict__ rowptr, const int* __restrict__ elist,
    const int* __restrict__ ei, const float* __restrict__ attn2,
    const float* __restrict__ qkvs2, const float* __restrict__ E2,
    float* __restrict__ out)
{
    int n = blockIdx.x;
    int c = threadIdx.x;
    int s0 = rowptr[n], s1 = rowptr[n + 1];
    float acc = qkvs2[(size_t)n * 256 + 192 + c];
    for (int i = s0; i < s1; ++i) {
        int e = elist[i];
        acc += attn2[i] * (qkvs2[(size_t)ei[e] * 256 + 128 + c] + E2[(size_t)e * 64 + c]);
    }
    out[(size_t)n * 64 + c] = fmaxf(acc, 0.f);
}

// ------------------------------------------------------------------
extern "C" void kernel_launch(void* const* d_in, const int* in_sizes, int n_in,
                              void* d_out, int out_size, void* d_ws, size_t ws_size,
                              hipStream_t stream)
{
    const float* x   = (const float*)d_in[0];
    const int*   ei  = (const int*)d_in[1];
    const float* ea  = (const float*)d_in[2];
    const float* q1w = (const float*)d_in[3];
    const float* q1b = (const float*)d_in[4];
    const float* k1w = (const float*)d_in[5];
    const float* k1b = (const float*)d_in[6];
    const float* v1w = (const float*)d_in[7];
    const float* v1b = (const float*)d_in[8];
    const float* e1w = (const float*)d_in[9];
    const float* s1w = (const float*)d_in[10];
    const float* s1b = (const float*)d_in[11];
    const float* q2w = (const float*)d_in[12];
    const float* q2b = (const float*)d_in[13];
    const float* k2w = (const float*)d_in[14];
    const float* k2b = (const float*)d_in[15];
    const float* v2w = (const float*)d_in[16];
    const float* v2b = (const float*)d_in[17];
    const float* e2w = (const float*)d_in[18];
    const float* s2w = (const float*)d_in[19];
    const float* s2b = (const float*)d_in[20];
    float* out = (float*)d_out;

    char* base = (char*)d_ws;
    size_t off = 0;
    auto alloc = [&](size_t nbytes) {
        size_t o = off; off += (nbytes + 255) & ~(size_t)255; return o;
    };
    const size_t xb_off   = alloc((size_t)MPAD * KDIM * 2);      // bf16 input (reused as h1b)
    const size_t wcat_off = alloc((size_t)4 * KDIM * KDIM * 2);  // fused weights (reused: Cpart+w2t)
    __hip_bfloat16* xb    = (__hip_bfloat16*)(base + xb_off);
    __hip_bfloat16* wcat  = (__hip_bfloat16*)(base + wcat_off);
    __hip_bfloat16* h1b   = xb;                                   // alias (xb dead after fused gemm)
    float*          Cpart = (float*)(base + wcat_off);            // alias (wcat dead after fused gemm)
    __hip_bfloat16* w2t   = (__hip_bfloat16*)(base + wcat_off + (size_t)29 * 1024 * 1024);

    __hip_bfloat16* q1bb  = (__hip_bfloat16*)(base + alloc((size_t)MPAD * HC1 * 2));
    __hip_bfloat16* k1bb  = (__hip_bfloat16*)(base + alloc((size_t)MPAD * HC1 * 2));
    __hip_bfloat16* v1bb  = (__hip_bfloat16*)(base + alloc((size_t)MPAD * HC1 * 2));
    float*          h1    = (float*)(base + alloc((size_t)MPAD * HC1 * 4));
    float*          bcat  = (float*)(base + alloc((size_t)4 * KDIM * 4));
    float*          P1    = (float*)(base + alloc((size_t)MPAD * 128 * 4));
    __hip_bfloat16* R1b   = (__hip_bfloat16*)(base + alloc((size_t)MPAD * 128 * 2));
    __hip_bfloat16* w1pp  = (__hip_bfloat16*)(base + alloc((size_t)128 * KDIM * 2));
    __hip_bfloat16* w1ppT = (__hip_bfloat16*)(base + alloc((size_t)KDIM * 128 * 2));
    float*          b2    = (float*)(base + alloc(256 * 4));
    float*          qkvs2 = (float*)(base + alloc((size_t)MPAD * 256 * 4));
    float*          E2    = (float*)(base + alloc((size_t)NE * 64 * 4));
    float*          at1   = (float*)(base + alloc((size_t)NE * 2 * 4));
    float*          at2   = (float*)(base + alloc((size_t)NE * 4));
    int* deg    = (int*)(base + alloc((size_t)NN * 4));
    int* fill   = (int*)(base + alloc((size_t)NN * 4));
    int* rowptr = (int*)(base + alloc((size_t)(NN + 1) * 4));
    int* elist  = (int*)(base + alloc((size_t)NE * 4));

    // --- CSR build ---
    hipMemsetAsync(deg, 0, sizeof(int) * 2 * NN, stream);
    count_deg<<<(NE + 255) / 256, 256, 0, stream>>>(ei, deg);
    scan_kernel<<<1, 1024, 0, stream>>>(deg, rowptr);
    fill_csr<<<(NE + 255) / 256, 256, 0, stream>>>(ei, rowptr, fill, elist);
    sort_csr<<<(NN + 255) / 256, 256, 0, stream>>>(rowptr, elist);

    // --- input conversion + fused weight prep ---
    const int cvblk = (MPAD * KDIM / 4) / 256;
    cvt_pad_bf16<<<cvblk, 256, 0, stream>>>(x, xb, 0);
    transpose_cvt4<<<dim3(KDIM / 32, KDIM / 32, 4), 256, 0, stream>>>(q1w, k1w, v1w, s1w, wcat);
    build_bcat<<<(4 * KDIM) / 256, 256, 0, stream>>>(q1b, k1b, v1b, s1b, bcat);

    // --- fused layer-1 projections: one 1728-block 256x128 dispatch ---
    gemm256x128_fused<<<1728, 256, 0, stream>>>(xb, wcat, bcat, q1bb, k1bb, v1bb, h1);

    // --- P1 = q1 @ W1p (split-K 4) ---
    build_w1pp<<<(128 * KDIM) / 256, 256, 0, stream>>>(e1w, w1pp);
    build_w1ppT<<<(KDIM * 128) / 256, 256, 0, stream>>>(e1w, w1ppT);
    gemm_bf16<<<dim3(1, MPAD / 128, 4), 256, 0, stream>>>(q1bb, w1pp, nullptr, Cpart, nullptr,
                                                          MPAD, 128, KDIM, 0);
    reduce4<<<(MPAD * 128) / 256, 256, 0, stream>>>(Cpart, (size_t)MPAD * 128, nullptr, 0,
                                                    P1, MPAD * 128);

    // --- attention layer 1 (slot-ordered) ---
    alpha1_kernel<<<NE / 4, 256, 0, stream>>>(q1bb, k1bb, P1, ea, ei, elist, at1);
    softmax_kernel<<<(NN + 255) / 256, 256, 0, stream>>>(rowptr, at1, 2);
    r1_kernel<<<NN, 128, 0, stream>>>(rowptr, elist, at1, ea, R1b);
    agg1_kernel<<<NN, 256, 0, stream>>>(rowptr, elist, ei, at1, v1bb, h1);
    // R1 @ W1pp, += h1, relu, write bf16 h1b directly (no fp32 writeback)
    gemm_bf16<<<dim3(HC1 / 128, MPAD / 128), 256, 0, stream>>>(R1b, w1ppT, nullptr, h1, h1b,
                                                               MPAD, HC1, 128, 2 | 4 | 8);

    // --- layer 2 projections (split-K 4) ---
    build_w2t<<<(256 * KDIM) / 256, 256, 0, stream>>>(q2w, k2w, v2w, s2w, q2b, k2b, v2b, s2b,
                                                      w2t, b2);
    gemm_bf16<<<dim3(2, MPAD / 128, 4), 256, 0, stream>>>(h1b, w2t, nullptr, Cpart, nullptr,
                                                          MPAD, 256, KDIM, 0);
    reduce4<<<(MPAD * 256) / 256, 256, 0, stream>>>(Cpart, (size_t)MPAD * 256, b2, 255,
                                                    qkvs2, MPAD * 256);
    gemm_tile<<<dim3(1, NE / 64), 256, 0, stream>>>(ea, e2w, nullptr, E2, NE, 64, 64, 0);

    // --- attention layer 2 (slot-ordered) ---
    alpha2_kernel<<<NE / 4, 256, 0, stream>>>(qkvs2, E2, ei, elist, at2);
    softmax_kernel<<<(NN + 255) / 256, 256, 0, stream>>>(rowptr, at2, 1);
    agg2_kernel<<<NN, 64, 0, stream>>>(rowptr, elist, ei, at2, qkvs2, E2, out);

    (void)in_sizes; (void)n_in; (void)out_size; (void)ws_size;
}

// Round 8
// 486.487 us; speedup vs baseline: 7.4294x; 1.0825x over previous
//
#include <hip/hip_runtime.h>
#include <hip/hip_bf16.h>
#include <cstdint>
#include <cstddef>

#define NN    6720     // nodes
#define MPAD  6912     // 27 * 256
#define NE    33600    // edges
#define KDIM  2048
#define HC1   2048
#define EAP   2100     // edge_attr tile period

typedef __attribute__((ext_vector_type(8))) short bhalf8;
typedef __attribute__((ext_vector_type(4))) short bhalf4;
typedef __attribute__((ext_vector_type(4))) float fx4;

__device__ __forceinline__ float bf2f(short s) {
    union { unsigned int u; float f; } c;
    c.u = ((unsigned int)(unsigned short)s) << 16;
    return c.f;
}

__device__ __forceinline__ void gload16(const __hip_bfloat16* g, void* lds)
{
    __builtin_amdgcn_global_load_lds(
        (const __attribute__((address_space(1))) unsigned int*)g,
        (__attribute__((address_space(3))) unsigned int*)lds,
        16, 0, 0);
}

#define CFENCE asm volatile("" ::: "memory")

// ------------------------------------------------------------------
// Persistent 256x128-tile 4-wave fused projection GEMM. 512 blocks,
// each loops macro-tiles vt = bid+512k (XCD stripe preserved: 512%8==0).
// BK=32, 3-deep LDS ring, counted vmcnt(12/6/0), setprio, XOR swizzle.
// Per macro-tile: vmcnt(0)+barrier (drain epilogue stores, protect
// cross-wave scratch), then same schedule as r7.
// ------------------------------------------------------------------
__global__ __launch_bounds__(256, 2) void gemm256x128_fused(
    const __hip_bfloat16* __restrict__ A,
    const __hip_bfloat16* __restrict__ Bt,
    const float* __restrict__ bcat,
    __hip_bfloat16* __restrict__ oq,
    __hip_bfloat16* __restrict__ ok,
    __hip_bfloat16* __restrict__ ov,
    float* __restrict__ oh)
{
    __shared__ alignas(16) char Lds[73728];   // A ring 3x16KB @0 | B ring 3x8KB @49152

    const int tid  = threadIdx.x;
    const int w    = tid >> 6;
    const int lane = tid & 63;
    const int wm = w >> 1, wn = w & 1;    // 2x2 waves, wave tile 128x64
    const int sug = ((lane & 3) ^ ((lane >> 3) & 3)) << 3;
    const int rds = (((lane >> 4) ^ (((lane & 15) >> 1) & 3)) << 4);

#define STAGE(T)                                                          \
    { const int s_ = (T) % 3; const int k0_ = (T) * 32;                   \
      char* ab_ = Lds + s_ * 16384 + w * 4096;                            \
      char* bb_ = Lds + 49152 + s_ * 8192 + w * 2048;                     \
      gload16(Ag0 + k0_, ab_);                                            \
      gload16(Ag0 + k0_ + 16 * KDIM, ab_ + 1024);                         \
      gload16(Ag0 + k0_ + 32 * KDIM, ab_ + 2048);                         \
      gload16(Ag0 + k0_ + 48 * KDIM, ab_ + 3072);                         \
      gload16(Bg0 + k0_, bb_);                                            \
      gload16(Bg0 + k0_ + 16 * KDIM, bb_ + 1024); }

#define TILE(T, VM, DOSTAGE)                                              \
    { if (DOSTAGE) { STAGE((T) + 2); }                                    \
      asm volatile("s_waitcnt vmcnt(" VM ")" ::: "memory");               \
      __builtin_amdgcn_s_barrier(); CFENCE;                               \
      const int s_ = (T) % 3;                                             \
      const char* ap_ = Lds + s_ * 16384;                                 \
      const char* bp_ = Lds + 49152 + s_ * 8192;                          \
      bhalf8 af_[8], bf_[4];                                              \
      _Pragma("unroll")                                                   \
      for (int nj = 0; nj < 4; ++nj)                                      \
          bf_[nj] = *(const bhalf8*)(bp_ + (wn * 64 + nj * 16 + (lane & 15)) * 64 + rds); \
      _Pragma("unroll")                                                   \
      for (int mi = 0; mi < 8; ++mi)                                      \
          af_[mi] = *(const bhalf8*)(ap_ + (wm * 128 + mi * 16 + (lane & 15)) * 64 + rds); \
      __builtin_amdgcn_s_setprio(1);                                      \
      _Pragma("unroll")                                                   \
      for (int mi = 0; mi < 8; ++mi)                                      \
          _Pragma("unroll")                                               \
          for (int nj = 0; nj < 4; ++nj)                                  \
              acc[mi][nj] = __builtin_amdgcn_mfma_f32_16x16x32_bf16(      \
                  af_[mi], bf_[nj], acc[mi][nj], 0, 0, 0);                \
      __builtin_amdgcn_s_setprio(0); CFENCE;                              \
      __builtin_amdgcn_s_barrier(); CFENCE; }

    for (int vt = blockIdx.x; vt < 1728; vt += 512) {
        if (vt != (int)blockIdx.x) {
            asm volatile("s_waitcnt vmcnt(0)" ::: "memory");
            __builtin_amdgcn_s_barrier();
            CFENCE;
        }
        const int i0 = vt >> 3;
        const int bx = (vt & 7) * 8 + (i0 & 7);   // N: 64 panels of 128
        const int by = i0 >> 3;                   // M: 27 panels of 256
        const int rowA = by * 256;
        const int rowB = bx * 128;
        const __hip_bfloat16* Ag0 = A  + (size_t)(rowA + w * 64 + (lane >> 2)) * KDIM + sug;
        const __hip_bfloat16* Bg0 = Bt + (size_t)(rowB + w * 32 + (lane >> 2)) * KDIM + sug;

        fx4 acc[8][4] = {};

        STAGE(0); STAGE(1);
        for (int t = 0; t < (KDIM / 32) - 2; ++t) {
            TILE(t, "12", 1);
        }
        TILE((KDIM / 32) - 2, "6", 0);
        TILE((KDIM / 32) - 1, "0", 0);

        // ---- epilogue: 272B-padded LDS scratch, full-line stores ----
        const int gcol = rowB + wn * 64;
        const int seg  = gcol >> 11;            // 0:q 1:k 2:v 3:skip(fp32)
        const int lcol = gcol & 2047;
        float bv[4];
        #pragma unroll
        for (int nj = 0; nj < 4; ++nj) bv[nj] = bcat[gcol + nj * 16 + (lane & 15)];
        char* scr = Lds + w * 8704;             // wave-private 32 rows x 272B
        const int growA = rowA + wm * 128;

        #pragma unroll
        for (int c = 0; c < 4; ++c) {
            #pragma unroll
            for (int m2 = 0; m2 < 2; ++m2) {
                const int mi = c * 2 + m2;
                #pragma unroll
                for (int nj = 0; nj < 4; ++nj) {
                    const int cl = nj * 16 + (lane & 15);
                    #pragma unroll
                    for (int i2 = 0; i2 < 4; ++i2) {
                        const int rl = m2 * 16 + ((lane >> 4) << 2) + i2;
                        *(float*)(scr + rl * 272 + cl * 4) = acc[mi][nj][i2] + bv[nj];
                    }
                }
            }
            asm volatile("s_waitcnt lgkmcnt(0)" ::: "memory");
            CFENCE;
            const int rrow = (lane >> 4);
            const int u    = lane & 15;
            if (seg < 3) {
                __hip_bfloat16* dst = (seg == 0) ? oq : (seg == 1) ? ok : ov;
                #pragma unroll
                for (int p = 0; p < 8; ++p) {
                    const int row = p * 4 + rrow;
                    const float4 f = *(const float4*)(scr + row * 272 + u * 16);
                    bhalf4 tb;
                    tb[0] = (short)__bfloat16_as_ushort(__float2bfloat16(f.x));
                    tb[1] = (short)__bfloat16_as_ushort(__float2bfloat16(f.y));
                    tb[2] = (short)__bfloat16_as_ushort(__float2bfloat16(f.z));
                    tb[3] = (short)__bfloat16_as_ushort(__float2bfloat16(f.w));
                    *(bhalf4*)&dst[(size_t)(growA + c * 32 + row) * 2048 + lcol + u * 4] = tb;
                }
            } else {
                #pragma unroll
                for (int p = 0; p < 8; ++p) {
                    const int row = p * 4 + rrow;
                    const float4 f = *(const float4*)(scr + row * 272 + u * 16);
                    *(float4*)&oh[(size_t)(growA + c * 32 + row) * 2048 + lcol + u * 4] = f;
                }
            }
            asm volatile("s_waitcnt lgkmcnt(0)" ::: "memory");
            CFENCE;
        }
    }
#undef TILE
#undef STAGE
}

// ------------------------------------------------------------------
// 128x128 bf16 MFMA GEMM (4 waves), optional split-K via blockIdx.z.
// flags: 1=+bias  2=+=C(read)  4=relu  8=skip C writeback
// ------------------------------------------------------------------
__global__ __launch_bounds__(256) void gemm_bf16(
    const __hip_bfloat16* __restrict__ A,
    const __hip_bfloat16* __restrict__ Bt,
    const float* __restrict__ bias,
    float* __restrict__ C,
    __hip_bfloat16* __restrict__ Cb,
    int M, int N, int K, int flags)
{
    __shared__ alignas(16) __hip_bfloat16 Asm[128 * 64];
    __shared__ alignas(16) __hip_bfloat16 Bsm[128 * 64];
    const int tid  = threadIdx.x;
    const int w    = tid >> 6;
    const int lane = tid & 63;
    const int wr = w >> 1, wc = w & 1;
    const int rowA = blockIdx.y * 128;
    const int rowB = blockIdx.x * 128;
    const int klen = K / gridDim.z;
    const int kbeg = blockIdx.z * klen;

    const int srow = w * 32 + (lane >> 3);
    const int ug8  = ((lane & 7) ^ (lane >> 3)) << 3;
    const __hip_bfloat16* Ag = A  + (size_t)(rowA + srow) * K + ug8;
    const __hip_bfloat16* Bg = Bt + (size_t)(rowB + srow) * K + ug8;
    char* AsBase = (char*)Asm + w * 4096;
    char* BsBase = (char*)Bsm + w * 4096;

    fx4 acc[4][4] = {};

    const int fra = wr * 64 + (lane & 15);
    const int frb = wc * 64 + (lane & 15);
    const int kb  = (lane >> 4) << 4;
    const int swz = (lane & 7) << 4;

    for (int k0 = kbeg; k0 < kbeg + klen; k0 += 64) {
        __syncthreads();
        #pragma unroll
        for (int j = 0; j < 4; ++j) {
            gload16(Ag + (size_t)j * 8 * K + k0, AsBase + j * 1024);
            gload16(Bg + (size_t)j * 8 * K + k0, BsBase + j * 1024);
        }
        __syncthreads();
        #pragma unroll
        for (int kk = 0; kk < 2; ++kk) {
            const int cb = kk * 64 + kb;
            bhalf8 af[4], bfr[4];
            #pragma unroll
            for (int mi = 0; mi < 4; ++mi)
                af[mi] = *(const bhalf8*)((const char*)Asm + (fra + mi * 16) * 128 + (cb ^ swz));
            #pragma unroll
            for (int nj = 0; nj < 4; ++nj)
                bfr[nj] = *(const bhalf8*)((const char*)Bsm + (frb + nj * 16) * 128 + (cb ^ swz));
            #pragma unroll
            for (int mi = 0; mi < 4; ++mi)
                #pragma unroll
                for (int nj = 0; nj < 4; ++nj)
                    acc[mi][nj] = __builtin_amdgcn_mfma_f32_16x16x32_bf16(
                        af[mi], bfr[nj], acc[mi][nj], 0, 0, 0);
        }
    }

    float* Cz = C ? C + (size_t)blockIdx.z * ((size_t)M * N) : nullptr;
    #pragma unroll
    for (int nj = 0; nj < 4; ++nj) {
        const int ccol = rowB + wc * 64 + nj * 16 + (lane & 15);
        const float bv = (flags & 1) ? bias[ccol] : 0.f;
        #pragma unroll
        for (int mi = 0; mi < 4; ++mi) {
            const int crow0 = rowA + wr * 64 + mi * 16 + ((lane >> 4) << 2);
            #pragma unroll
            for (int i = 0; i < 4; ++i) {
                size_t idx = (size_t)(crow0 + i) * N + ccol;
                float v = acc[mi][nj][i] + bv;
                if (flags & 2) v += Cz[idx];
                if (flags & 4) v = fmaxf(v, 0.f);
                if (Cz && !(flags & 8)) Cz[idx] = v;
                if (Cb) Cb[idx] = __float2bfloat16(v);
            }
        }
    }
}

// dst[i] = sum_z parts[z*stride + i] (+ bias[i & colmask])
__global__ void reduce4(const float* __restrict__ parts, size_t stride,
                        const float* __restrict__ bias, int colmask,
                        float* __restrict__ dst, int n)
{
    int i = blockIdx.x * 256 + threadIdx.x;
    if (i >= n) return;
    float v = parts[i] + parts[stride + i] + parts[2 * stride + i] + parts[3 * stride + i];
    if (bias) v += bias[i & colmask];
    dst[i] = v;
}

// ------------------------------------------------------------------
// fp32 tiled GEMM (tiny E2s = ea[0:2112] @ e2w)
// ------------------------------------------------------------------
__global__ __launch_bounds__(256) void gemm_tile(
    const float* __restrict__ A, const float* __restrict__ B,
    const float* __restrict__ bias, float* __restrict__ C,
    int M, int N, int K, int flags)
{
    __shared__ float As[16][68];
    __shared__ float Bs[16][64];
    const int tid = threadIdx.x;
    const int bx = blockIdx.x, by = blockIdx.y;
    const int tx = tid & 15, ty = tid >> 4;
    const int arow = tid >> 2, acol = (tid & 3) << 2;
    const int brow = tid >> 4, bcol = (tid & 15) << 2;
    const float* Ag = A + (size_t)(by * 64 + arow) * K + acol;
    const float* Bg = B + (size_t)brow * N + bx * 64 + bcol;
    float acc[4][4] = {};
    for (int k0 = 0; k0 < K; k0 += 16) {
        const float4 av = *(const float4*)(Ag + k0);
        const float4 bv = *(const float4*)(Bg + (size_t)k0 * N);
        __syncthreads();
        As[acol + 0][arow] = av.x;
        As[acol + 1][arow] = av.y;
        As[acol + 2][arow] = av.z;
        As[acol + 3][arow] = av.w;
        *(float4*)&Bs[brow][bcol] = bv;
        __syncthreads();
        #pragma unroll
        for (int kk = 0; kk < 16; ++kk) {
            const float4 a4 = *(const float4*)&As[kk][ty << 2];
            const float4 b4 = *(const float4*)&Bs[kk][tx << 2];
            const float a[4] = {a4.x, a4.y, a4.z, a4.w};
            const float b[4] = {b4.x, b4.y, b4.z, b4.w};
            #pragma unroll
            for (int i = 0; i < 4; ++i)
                #pragma unroll
                for (int j = 0; j < 4; ++j)
                    acc[i][j] += a[i] * b[j];
        }
    }
    const int crow = by * 64 + (ty << 2);
    const int ccol = bx * 64 + (tx << 2);
    float4 b4 = make_float4(0.f, 0.f, 0.f, 0.f);
    if (flags & 1) b4 = *(const float4*)(bias + ccol);
    #pragma unroll
    for (int i = 0; i < 4; ++i) {
        float* cp = C + (size_t)(crow + i) * N + ccol;
        float4 v;
        v.x = acc[i][0] + b4.x; v.y = acc[i][1] + b4.y;
        v.z = acc[i][2] + b4.z; v.w = acc[i][3] + b4.w;
        if (flags & 2) {
            const float4 o = *(const float4*)cp;
            v.x += o.x; v.y += o.y; v.z += o.z; v.w += o.w;
        }
        *(float4*)cp = v;
    }
}

// ------------------------------------------------------------------
// CSR build
// ------------------------------------------------------------------
__global__ void count_deg(const int* __restrict__ ei, int* __restrict__ deg)
{
    int e = blockIdx.x * 256 + threadIdx.x;
    if (e < NE) atomicAdd(&deg[ei[NE + e]], 1);
}

__global__ __launch_bounds__(1024) void scan_kernel(const int* __restrict__ deg,
                                                    int* __restrict__ rowptr)
{
    __shared__ int s[1024];
    const int t = threadIdx.x;
    const int base = t * 7;
    int loc[7];
    int sum = 0;
    #pragma unroll
    for (int i = 0; i < 7; ++i) {
        int idx = base + i;
        int v = (idx < NN) ? deg[idx] : 0;
        loc[i] = v; sum += v;
    }
    s[t] = sum;
    __syncthreads();
    for (int off = 1; off < 1024; off <<= 1) {
        int v = (t >= off) ? s[t - off] : 0;
        __syncthreads();
        s[t] += v;
        __syncthreads();
    }
    int running = s[t] - sum;
    #pragma unroll
    for (int i = 0; i < 7; ++i) {
        int idx = base + i;
        if (idx <= NN) rowptr[idx] = running;
        if (idx < NN) running += loc[i];
    }
}

__global__ void fill_csr(const int* __restrict__ ei, const int* __restrict__ rowptr,
                         int* __restrict__ fillctr, int* __restrict__ elist)
{
    int e = blockIdx.x * 256 + threadIdx.x;
    if (e >= NE) return;
    int d = ei[NE + e];
    int pos = atomicAdd(&fillctr[d], 1);
    elist[rowptr[d] + pos] = e;
}

__global__ void sort_csr(const int* __restrict__ rowptr, int* __restrict__ elist)
{
    int n = blockIdx.x * 256 + threadIdx.x;
    if (n >= NN) return;
    int s0 = rowptr[n], s1 = rowptr[n + 1];
    for (int i = s0 + 1; i < s1; ++i) {
        int v = elist[i];
        int j = i - 1;
        while (j >= s0 && elist[j] > v) { elist[j + 1] = elist[j]; --j; }
        elist[j + 1] = v;
    }
}

// ------------------------------------------------------------------
// conversions / weight prep
// ------------------------------------------------------------------
__global__ void cvt_pad_bf16(const float* __restrict__ src, __hip_bfloat16* __restrict__ dst,
                             int relu)
{
    size_t i = (size_t)(blockIdx.x * 256 + threadIdx.x) * 4;
    int row = (int)(i >> 11);
    float4 v = make_float4(0.f, 0.f, 0.f, 0.f);
    if (row < NN) v = *(const float4*)&src[i];
    if (relu) {
        v.x = fmaxf(v.x, 0.f); v.y = fmaxf(v.y, 0.f);
        v.z = fmaxf(v.z, 0.f); v.w = fmaxf(v.w, 0.f);
    }
    dst[i + 0] = __float2bfloat16(v.x);
    dst[i + 1] = __float2bfloat16(v.y);
    dst[i + 2] = __float2bfloat16(v.z);
    dst[i + 3] = __float2bfloat16(v.w);
}

// 4 transposes in one dispatch: Bt[z][n][k] = bf16(Wz[k][n])
__global__ __launch_bounds__(256) void transpose_cvt4(
    const float* __restrict__ W0, const float* __restrict__ W1,
    const float* __restrict__ W2, const float* __restrict__ W3,
    __hip_bfloat16* __restrict__ dst)
{
    const float* W = (blockIdx.z == 0) ? W0 : (blockIdx.z == 1) ? W1
                   : (blockIdx.z == 2) ? W2 : W3;
    __hip_bfloat16* Bt = dst + (size_t)blockIdx.z * KDIM * KDIM;
    __shared__ float t[32][33];
    int kb = blockIdx.y * 32, nb = blockIdx.x * 32;
    int tx = threadIdx.x & 31, ty = threadIdx.x >> 5;
    #pragma unroll
    for (int i = 0; i < 32; i += 8)
        t[ty + i][tx] = W[(size_t)(kb + ty + i) * KDIM + nb + tx];
    __syncthreads();
    #pragma unroll
    for (int i = 0; i < 32; i += 8)
        Bt[(size_t)(nb + ty + i) * KDIM + kb + tx] = __float2bfloat16(t[tx][ty + i]);
}

__global__ void build_bcat(const float* __restrict__ q1b, const float* __restrict__ k1b,
                           const float* __restrict__ v1b, const float* __restrict__ s1b,
                           float* __restrict__ bcat)
{
    int i = blockIdx.x * 256 + threadIdx.x;
    if (i >= 4 * KDIM) return;
    int seg = i >> 11, j = i & 2047;
    const float* b = (seg == 0) ? q1b : (seg == 1) ? k1b : (seg == 2) ? v1b : s1b;
    bcat[i] = b[j];
}

__global__ void build_w1pp(const float* __restrict__ e1w, __hip_bfloat16* __restrict__ w1pp)
{
    int idx = blockIdx.x * 256 + threadIdx.x;
    int p = idx >> 11, j = idx & 2047;
    float v = ((j >> 10) == (p >> 6)) ? e1w[(size_t)(p & 63) * KDIM + j] : 0.f;
    w1pp[idx] = __float2bfloat16(v);
}

__global__ void build_w1ppT(const float* __restrict__ e1w, __hip_bfloat16* __restrict__ w1ppT)
{
    int idx = blockIdx.x * 256 + threadIdx.x;
    int n = idx >> 7, k = idx & 127;
    float v = ((n >> 10) == (k >> 6)) ? e1w[(size_t)(k & 63) * KDIM + n] : 0.f;
    w1ppT[idx] = __float2bfloat16(v);
}

__global__ void build_w2t(const float* __restrict__ qw, const float* __restrict__ kw,
                          const float* __restrict__ vw, const float* __restrict__ sw,
                          const float* __restrict__ qb, const float* __restrict__ kb,
                          const float* __restrict__ vb, const float* __restrict__ sb,
                          __hip_bfloat16* __restrict__ w2t, float* __restrict__ b2)
{
    int idx = blockIdx.x * 256 + threadIdx.x;
    int c = idx >> 11, d = idx & 2047;
    int g = c >> 6, j = c & 63;
    const float* w = (g == 0) ? qw : (g == 1) ? kw : (g == 2) ? vw : sw;
    w2t[idx] = __float2bfloat16(w[(size_t)d * 64 + j]);
    if (d == 0) {
        const float* b = (g == 0) ? qb : (g == 1) ? kb : (g == 2) ? vb : sb;
        b2[c] = b[j];
    }
}

// ------------------------------------------------------------------
// node1: fused alpha1 + softmax + R1 + V-aggregation. One block/node.
// Phase A: 4 waves compute per-edge dual-head dots -> LDS.
// Phase B: 2 threads do softmax over deg entries per head.
// Phase C: 128 threads R1; Phase D: 256 threads h1 += sum attn*v.
// ------------------------------------------------------------------
__global__ __launch_bounds__(256) void node1_kernel(
    const __hip_bfloat16* __restrict__ q1b, const __hip_bfloat16* __restrict__ k1b,
    const __hip_bfloat16* __restrict__ v1b,
    const float* __restrict__ P1, const float* __restrict__ ea,
    const int* __restrict__ ei, const int* __restrict__ rowptr,
    const int* __restrict__ elist,
    float* __restrict__ h1, __hip_bfloat16* __restrict__ R1)
{
    __shared__ int   s_src[256];
    __shared__ int   s_em[256];
    __shared__ float s_at[256][2];
    const int n = blockIdx.x;
    const int s0 = rowptr[n];
    const int deg = rowptr[n + 1] - s0;
    const int w = threadIdx.x >> 6, lane = threadIdx.x & 63;

    // phase A: dots
    for (int j = w; j < deg; j += 4) {
        const int e = elist[s0 + j];
        const int src = ei[e];
        const int em = e % EAP;
        if (lane == 0) { s_src[j] = src; s_em[j] = em; }
        const float eaj = ea[(size_t)em * 64 + lane];
        #pragma unroll
        for (int h = 0; h < 2; ++h) {
            const __hip_bfloat16* qh = q1b + (size_t)n * HC1 + h * 1024 + lane * 16;
            const __hip_bfloat16* kh = k1b + (size_t)src * HC1 + h * 1024 + lane * 16;
            bhalf8 qa = *(const bhalf8*)qh, qc = *(const bhalf8*)(qh + 8);
            bhalf8 ka = *(const bhalf8*)kh, kc = *(const bhalf8*)(kh + 8);
            float s = 0.f;
            #pragma unroll
            for (int jj = 0; jj < 8; ++jj) s += bf2f(qa[jj]) * bf2f(ka[jj]);
            #pragma unroll
            for (int jj = 0; jj < 8; ++jj) s += bf2f(qc[jj]) * bf2f(kc[jj]);
            s += eaj * P1[(size_t)n * 128 + h * 64 + lane];
            #pragma unroll
            for (int off = 32; off; off >>= 1) s += __shfl_xor(s, off);
            if (lane == 0) s_at[j][h] = s * 0.03125f;
        }
    }
    __syncthreads();

    // phase B: softmax per head
    if (threadIdx.x < 2) {
        const int h = threadIdx.x;
        float m = -1e30f;
        for (int j = 0; j < deg; ++j) m = fmaxf(m, s_at[j][h]);
        float sum = 0.f;
        for (int j = 0; j < deg; ++j) {
            float ex = __expf(s_at[j][h] - m);
            s_at[j][h] = ex; sum += ex;
        }
        float inv = 1.f / (sum + 1e-16f);
        for (int j = 0; j < deg; ++j) s_at[j][h] *= inv;
    }
    __syncthreads();

    // phase C: R1[n][p] = sum attn[j][h] * ea[em_j][p&63]
    if (threadIdx.x < 128) {
        const int h = threadIdx.x >> 6, jj = threadIdx.x & 63;
        float r = 0.f;
        for (int j = 0; j < deg; ++j)
            r += s_at[j][h] * ea[(size_t)s_em[j] * 64 + jj];
        R1[(size_t)n * 128 + threadIdx.x] = __float2bfloat16(r);
    }

    // phase D: h1[n][c] += sum attn * v1[src]
    const int c0 = threadIdx.x * 8;
    const int h = c0 >> 10;
    float acc[8];
    const float4 p0 = *(const float4*)&h1[(size_t)n * HC1 + c0];
    const float4 p1 = *(const float4*)&h1[(size_t)n * HC1 + c0 + 4];
    acc[0] = p0.x; acc[1] = p0.y; acc[2] = p0.z; acc[3] = p0.w;
    acc[4] = p1.x; acc[5] = p1.y; acc[6] = p1.z; acc[7] = p1.w;
    for (int j = 0; j < deg; ++j) {
        const float at = s_at[j][h];
        bhalf8 v = *(const bhalf8*)&v1b[(size_t)s_src[j] * HC1 + c0];
        #pragma unroll
        for (int jj = 0; jj < 8; ++jj) acc[jj] += at * bf2f(v[jj]);
    }
    *(float4*)&h1[(size_t)n * HC1 + c0]     = make_float4(acc[0], acc[1], acc[2], acc[3]);
    *(float4*)&h1[(size_t)n * HC1 + c0 + 4] = make_float4(acc[4], acc[5], acc[6], acc[7]);
}

// ------------------------------------------------------------------
// node2: fused alpha2 + softmax + aggregation + relu. 1 wave/node.
// ------------------------------------------------------------------
__global__ __launch_bounds__(64) void node2_kernel(
    const float* __restrict__ qkvs2, const float* __restrict__ E2s,
    const int* __restrict__ ei, const int* __restrict__ rowptr,
    const int* __restrict__ elist, float* __restrict__ out)
{
    __shared__ float s_at[256];
    __shared__ int   s_src[256];
    __shared__ int   s_em[256];
    const int n = blockIdx.x;
    const int s0 = rowptr[n];
    const int deg = rowptr[n + 1] - s0;
    const int c = threadIdx.x;
    const float q = qkvs2[(size_t)n * 256 + c];

    for (int j = 0; j < deg; ++j) {
        const int e = elist[s0 + j];
        const int src = ei[e];
        const int em = e % EAP;
        float s = q * (qkvs2[(size_t)src * 256 + 64 + c] + E2s[(size_t)em * 64 + c]);
        #pragma unroll
        for (int off = 32; off; off >>= 1) s += __shfl_xor(s, off);
        if (c == 0) { s_at[j] = s * 0.125f; s_src[j] = src; s_em[j] = em; }
    }
    __syncthreads();
    // all-lane softmax params (broadcast LDS reads)
    float m = -1e30f;
    for (int j = 0; j < deg; ++j) m = fmaxf(m, s_at[j]);
    float sum = 0.f;
    for (int j = 0; j < deg; ++j) sum += __expf(s_at[j] - m);
    const float inv = 1.f / (sum + 1e-16f);

    float acc = qkvs2[(size_t)n * 256 + 192 + c];
    for (int j = 0; j < deg; ++j) {
        const float at = __expf(s_at[j] - m) * inv;
        acc += at * (qkvs2[(size_t)s_src[j] * 256 + 128 + c] + E2s[(size_t)s_em[j] * 64 + c]);
    }
    out[(size_t)n * 64 + c] = fmaxf(acc, 0.f);
}

// ------------------------------------------------------------------
extern "C" void kernel_launch(void* const* d_in, const int* in_sizes, int n_in,
                              void* d_out, int out_size, void* d_ws, size_t ws_size,
                              hipStream_t stream)
{
    const float* x   = (const float*)d_in[0];
    const int*   ei  = (const int*)d_in[1];
    const float* ea  = (const float*)d_in[2];
    const float* q1w = (const float*)d_in[3];
    const float* q1b = (const float*)d_in[4];
    const float* k1w = (const float*)d_in[5];
    const float* k1b = (const float*)d_in[6];
    const float* v1w = (const float*)d_in[7];
    const float* v1b = (const float*)d_in[8];
    const float* e1w = (const float*)d_in[9];
    const float* s1w = (const float*)d_in[10];
    const float* s1b = (const float*)d_in[11];
    const float* q2w = (const float*)d_in[12];
    const float* q2b = (const float*)d_in[13];
    const float* k2w = (const float*)d_in[14];
    const float* k2b = (const float*)d_in[15];
    const float* v2w = (const float*)d_in[16];
    const float* v2b = (const float*)d_in[17];
    const float* e2w = (const float*)d_in[18];
    const float* s2w = (const float*)d_in[19];
    const float* s2b = (const float*)d_in[20];
    float* out = (float*)d_out;

    char* base = (char*)d_ws;
    size_t off = 0;
    auto alloc = [&](size_t nbytes) {
        size_t o = off; off += (nbytes + 255) & ~(size_t)255; return o;
    };
    const size_t xb_off   = alloc((size_t)MPAD * KDIM * 2);      // bf16 input (reused as h1b)
    const size_t wcat_off = alloc((size_t)4 * KDIM * KDIM * 2);  // fused weights (reused: Cpart+w2t)
    __hip_bfloat16* xb    = (__hip_bfloat16*)(base + xb_off);
    __hip_bfloat16* wcat  = (__hip_bfloat16*)(base + wcat_off);
    __hip_bfloat16* h1b   = xb;                                   // alias (xb dead after fused gemm)
    float*          Cpart = (float*)(base + wcat_off);            // alias (wcat dead after fused gemm)
    __hip_bfloat16* w2t   = (__hip_bfloat16*)(base + wcat_off + (size_t)29 * 1024 * 1024);

    __hip_bfloat16* q1bb  = (__hip_bfloat16*)(base + alloc((size_t)MPAD * HC1 * 2));
    __hip_bfloat16* k1bb  = (__hip_bfloat16*)(base + alloc((size_t)MPAD * HC1 * 2));
    __hip_bfloat16* v1bb  = (__hip_bfloat16*)(base + alloc((size_t)MPAD * HC1 * 2));
    float*          h1    = (float*)(base + alloc((size_t)MPAD * HC1 * 4));
    float*          bcat  = (float*)(base + alloc((size_t)4 * KDIM * 4));
    float*          P1    = (float*)(base + alloc((size_t)MPAD * 128 * 4));
    __hip_bfloat16* R1b   = (__hip_bfloat16*)(base + alloc((size_t)MPAD * 128 * 2));
    __hip_bfloat16* w1pp  = (__hip_bfloat16*)(base + alloc((size_t)128 * KDIM * 2));
    __hip_bfloat16* w1ppT = (__hip_bfloat16*)(base + alloc((size_t)KDIM * 128 * 2));
    float*          b2    = (float*)(base + alloc(256 * 4));
    float*          qkvs2 = (float*)(base + alloc((size_t)MPAD * 256 * 4));
    float*          E2s   = (float*)(base + alloc((size_t)2112 * 64 * 4));
    int* deg    = (int*)(base + alloc((size_t)NN * 4));
    int* fill   = (int*)(base + alloc((size_t)NN * 4));
    int* rowptr = (int*)(base + alloc((size_t)(NN + 1) * 4));
    int* elist  = (int*)(base + alloc((size_t)NE * 4));

    // --- CSR build ---
    hipMemsetAsync(deg, 0, sizeof(int) * 2 * NN, stream);
    count_deg<<<(NE + 255) / 256, 256, 0, stream>>>(ei, deg);
    scan_kernel<<<1, 1024, 0, stream>>>(deg, rowptr);
    fill_csr<<<(NE + 255) / 256, 256, 0, stream>>>(ei, rowptr, fill, elist);
    sort_csr<<<(NN + 255) / 256, 256, 0, stream>>>(rowptr, elist);

    // --- input conversion + weight prep (independent of GEMMs) ---
    const int cvblk = (MPAD * KDIM / 4) / 256;
    cvt_pad_bf16<<<cvblk, 256, 0, stream>>>(x, xb, 0);
    transpose_cvt4<<<dim3(KDIM / 32, KDIM / 32, 4), 256, 0, stream>>>(q1w, k1w, v1w, s1w, wcat);
    build_bcat<<<(4 * KDIM) / 256, 256, 0, stream>>>(q1b, k1b, v1b, s1b, bcat);
    build_w1pp<<<(128 * KDIM) / 256, 256, 0, stream>>>(e1w, w1pp);
    build_w1ppT<<<(KDIM * 128) / 256, 256, 0, stream>>>(e1w, w1ppT);
    gemm_tile<<<dim3(1, 33), 256, 0, stream>>>(ea, e2w, nullptr, E2s, 2112, 64, 64, 0);

    // --- fused layer-1 projections: persistent 512-block dispatch ---
    gemm256x128_fused<<<512, 256, 0, stream>>>(xb, wcat, bcat, q1bb, k1bb, v1bb, h1);

    // --- P1 = q1 @ W1p (split-K 4) ---
    gemm_bf16<<<dim3(1, MPAD / 128, 4), 256, 0, stream>>>(q1bb, w1pp, nullptr, Cpart, nullptr,
                                                          MPAD, 128, KDIM, 0);
    reduce4<<<(MPAD * 128) / 256, 256, 0, stream>>>(Cpart, (size_t)MPAD * 128, nullptr, 0,
                                                    P1, MPAD * 128);

    // --- fused layer-1 attention (alpha+softmax+R1+agg) ---
    node1_kernel<<<NN, 256, 0, stream>>>(q1bb, k1bb, v1bb, P1, ea, ei, rowptr, elist, h1, R1b);
    // R1 @ W1pp, += h1, relu, write bf16 h1b directly
    gemm_bf16<<<dim3(HC1 / 128, MPAD / 128), 256, 0, stream>>>(R1b, w1ppT, nullptr, h1, h1b,
                                                               MPAD, HC1, 128, 2 | 4 | 8);

    // --- layer 2 projections (split-K 4) ---
    build_w2t<<<(256 * KDIM) / 256, 256, 0, stream>>>(q2w, k2w, v2w, s2w, q2b, k2b, v2b, s2b,
                                                      w2t, b2);
    gemm_bf16<<<dim3(2, MPAD / 128, 4), 256, 0, stream>>>(h1b, w2t, nullptr, Cpart, nullptr,
                                                          MPAD, 256, KDIM, 0);
    reduce4<<<(MPAD * 256) / 256, 256, 0, stream>>>(Cpart, (size_t)MPAD * 256, b2, 255,
                                                    qkvs2, MPAD * 256);

    // --- fused layer-2 attention ---
    node2_kernel<<<NN, 64, 0, stream>>>(qkvs2, E2s, ei, rowptr, elist, out);

    (void)in_sizes; (void)n_in; (void)out_size; (void)ws_size;
}

// Round 9
// 483.440 us; speedup vs baseline: 7.4762x; 1.0063x over previous
//
#include <hip/hip_runtime.h>
#include <hip/hip_bf16.h>
#include <cstdint>
#include <cstddef>

#define NN    6720     // nodes
#define MPAD  6912     // 27 * 256
#define NE    33600    // edges
#define KDIM  2048
#define HC1   2048
#define EAP   2100     // edge_attr tile period

typedef __attribute__((ext_vector_type(8))) short bhalf8;
typedef __attribute__((ext_vector_type(4))) short bhalf4;
typedef __attribute__((ext_vector_type(4))) float fx4;

__device__ __forceinline__ float bf2f(short s) {
    union { unsigned int u; float f; } c;
    c.u = ((unsigned int)(unsigned short)s) << 16;
    return c.f;
}

__device__ __forceinline__ void gload16(const __hip_bfloat16* g, void* lds)
{
    __builtin_amdgcn_global_load_lds(
        (const __attribute__((address_space(1))) unsigned int*)g,
        (__attribute__((address_space(3))) unsigned int*)lds,
        16, 0, 0);
}

#define CFENCE asm volatile("" ::: "memory")

// ------------------------------------------------------------------
// 256x256-tile 8-wave quad-phased fused projection GEMM (m201-style).
// BK=64, 2 dbuf x 2 half per operand (4x16KB A + 4x16KB B = 128KB).
// Per K-tile T (dbuf T&1): 4 phases; phase q stages ONE half-tile of
// T+1 (dbuf (T+1)&1 - free since T-1 retired), vmcnt(2) once per tile
// (counted: only the just-issued stage outstanding), reads af pair
// (+ all bf at phase 0, held in regs), 16-MFMA setprio cluster,
// barrier. Wave tile 128x64 (wm 2 x wn 4). XCD stripe: XCD owns 4 of
// 32 N-panels (B slice 4MB = L2). Epilogue: 272B-padded LDS scratch.
// ------------------------------------------------------------------
__global__ __launch_bounds__(512, 2) void gemm256_8ph(
    const __hip_bfloat16* __restrict__ A,
    const __hip_bfloat16* __restrict__ Bt,
    const float* __restrict__ bcat,
    __hip_bfloat16* __restrict__ oq,
    __hip_bfloat16* __restrict__ ok,
    __hip_bfloat16* __restrict__ ov,
    float* __restrict__ oh)
{
    __shared__ alignas(16) char Lds[131072];  // A: [dbuf][half] 4x16KB @0 | B @65536

    // XCD map: 864 = 8 XCD * 108; XCD = bid&7 owns bx in [4*xcd, 4*xcd+4)
    const int bid = blockIdx.x;
    const int i0  = bid >> 3;
    const int bx  = (bid & 7) * 4 + (i0 & 3);   // 32 N-panels of 256
    const int by  = i0 >> 2;                    // 27 M-panels of 256

    const int tid  = threadIdx.x;
    const int w    = tid >> 6;        // 0..7
    const int lane = tid & 63;
    const int wm = w >> 2, wn = w & 3;          // wave tile 128x64
    const int l15 = lane & 15;
    const int rowA = by * 256;
    const int rowB = bx * 256;

    // staging: half-tile = 128 rows x 64 K (16KB). Per thread 2 gload16.
    // rows: w*16 + j*8 + (lane>>3); pre-swizzled source unit.
    const int sug = ((lane & 7) ^ (lane >> 3)) << 3;
    const __hip_bfloat16* Agb = A  + (size_t)(rowA + w * 16 + (lane >> 3)) * KDIM + sug;
    const __hip_bfloat16* Bgb = Bt + (size_t)(rowB + w * 16 + (lane >> 3)) * KDIM + sug;

    // fragment read swizzled unit bytes for kk=0,1
    const int uk0 = (((lane >> 4)    ) ^ (lane & 7)) << 4;
    const int uk1 = (((lane >> 4) + 4) ^ (lane & 7)) << 4;

    fx4 acc[8][4] = {};

#define STAGE_A(T, H)                                                      \
    { char* dst_ = Lds + ((T) & 1) * 32768 + (H) * 16384 + (w * 16) * 128; \
      const __hip_bfloat16* g_ = Agb + (size_t)((H) * 128) * KDIM + (size_t)(T) * 64; \
      gload16(g_, dst_);                                                   \
      gload16(g_ + 8 * KDIM, dst_ + 1024); }

#define STAGE_B(T, H)                                                      \
    { char* dst_ = Lds + 65536 + ((T) & 1) * 32768 + (H) * 16384 + (w * 16) * 128; \
      const __hip_bfloat16* g_ = Bgb + (size_t)((H) * 128) * KDIM + (size_t)(T) * 64; \
      gload16(g_, dst_);                                                   \
      gload16(g_ + 8 * KDIM, dst_ + 1024); }

#define PH_READ_AF(q)                                                      \
    _Pragma("unroll")                                                      \
    for (int m2 = 0; m2 < 2; ++m2) {                                       \
        const char* rp_ = Ab + (((q) * 2 + m2) * 16 + l15) * 128;          \
        af[m2][0] = *(const bhalf8*)(rp_ + uk0);                           \
        af[m2][1] = *(const bhalf8*)(rp_ + uk1);                           \
    }

#define PH_MFMA(q)                                                         \
    __builtin_amdgcn_s_setprio(1);                                         \
    _Pragma("unroll")                                                      \
    for (int m2 = 0; m2 < 2; ++m2)                                         \
        _Pragma("unroll")                                                  \
        for (int nj = 0; nj < 4; ++nj)                                     \
            _Pragma("unroll")                                              \
            for (int kk = 0; kk < 2; ++kk)                                 \
                acc[(q) * 2 + m2][nj] = __builtin_amdgcn_mfma_f32_16x16x32_bf16( \
                    af[m2][kk], bf[nj][kk], acc[(q) * 2 + m2][nj], 0, 0, 0); \
    __builtin_amdgcn_s_setprio(0);

    // prologue: stage tile 0 fully (8 loads)
    STAGE_A(0, 0); STAGE_B(0, 0); STAGE_A(0, 1); STAGE_B(0, 1);

    for (int T = 0; T < 32; ++T) {
        const char* Ab = Lds + (T & 1) * 32768 + wm * 16384;
        const char* Bb = Lds + 65536 + (T & 1) * 32768 + (wn >> 1) * 16384;
        bhalf8 bf[4][2], af[2][2];

        // ---- phase 0 ----
        if (T < 31) { STAGE_A(T + 1, 0); }
        if (T < 31) { asm volatile("s_waitcnt vmcnt(2)" ::: "memory"); }
        else        { asm volatile("s_waitcnt vmcnt(0)" ::: "memory"); }
        __builtin_amdgcn_s_barrier(); CFENCE;
        #pragma unroll
        for (int nj = 0; nj < 4; ++nj) {
            const char* rp_ = Bb + ((wn & 1) * 64 + nj * 16 + l15) * 128;
            bf[nj][0] = *(const bhalf8*)(rp_ + uk0);
            bf[nj][1] = *(const bhalf8*)(rp_ + uk1);
        }
        PH_READ_AF(0);
        PH_MFMA(0);
        CFENCE; __builtin_amdgcn_s_barrier(); CFENCE;
        // ---- phase 1 ----
        if (T < 31) { STAGE_B(T + 1, 0); }
        PH_READ_AF(1);
        PH_MFMA(1);
        CFENCE; __builtin_amdgcn_s_barrier(); CFENCE;
        // ---- phase 2 ----
        if (T < 31) { STAGE_A(T + 1, 1); }
        PH_READ_AF(2);
        PH_MFMA(2);
        CFENCE; __builtin_amdgcn_s_barrier(); CFENCE;
        // ---- phase 3 ----
        if (T < 31) { STAGE_B(T + 1, 1); }
        PH_READ_AF(3);
        PH_MFMA(3);
        CFENCE; __builtin_amdgcn_s_barrier(); CFENCE;
    }
#undef PH_MFMA
#undef PH_READ_AF
#undef STAGE_B
#undef STAGE_A

    // ---- epilogue: 272B-padded LDS scratch, full-line stores ----
    const int gcol = rowB + wn * 64;
    const int seg  = gcol >> 11;            // 0:q 1:k 2:v 3:skip(fp32)
    const int lcol = gcol & 2047;
    float bv[4];
    #pragma unroll
    for (int nj = 0; nj < 4; ++nj) bv[nj] = bcat[gcol + nj * 16 + l15];
    char* scr = Lds + w * 8704;             // wave-private 32 rows x 272B
    const int growA = rowA + wm * 128;

    #pragma unroll
    for (int c = 0; c < 4; ++c) {
        #pragma unroll
        for (int m2 = 0; m2 < 2; ++m2) {
            const int mi = c * 2 + m2;
            #pragma unroll
            for (int nj = 0; nj < 4; ++nj) {
                const int cl = nj * 16 + l15;
                #pragma unroll
                for (int i2 = 0; i2 < 4; ++i2) {
                    const int rl = m2 * 16 + ((lane >> 4) << 2) + i2;
                    *(float*)(scr + rl * 272 + cl * 4) = acc[mi][nj][i2] + bv[nj];
                }
            }
        }
        asm volatile("s_waitcnt lgkmcnt(0)" ::: "memory");
        CFENCE;
        const int rrow = (lane >> 4);
        const int u    = lane & 15;
        if (seg < 3) {
            __hip_bfloat16* dst = (seg == 0) ? oq : (seg == 1) ? ok : ov;
            #pragma unroll
            for (int p = 0; p < 8; ++p) {
                const int row = p * 4 + rrow;
                const float4 f = *(const float4*)(scr + row * 272 + u * 16);
                bhalf4 tb;
                tb[0] = (short)__bfloat16_as_ushort(__float2bfloat16(f.x));
                tb[1] = (short)__bfloat16_as_ushort(__float2bfloat16(f.y));
                tb[2] = (short)__bfloat16_as_ushort(__float2bfloat16(f.z));
                tb[3] = (short)__bfloat16_as_ushort(__float2bfloat16(f.w));
                *(bhalf4*)&dst[(size_t)(growA + c * 32 + row) * 2048 + lcol + u * 4] = tb;
            }
        } else {
            #pragma unroll
            for (int p = 0; p < 8; ++p) {
                const int row = p * 4 + rrow;
                const float4 f = *(const float4*)(scr + row * 272 + u * 16);
                *(float4*)&oh[(size_t)(growA + c * 32 + row) * 2048 + lcol + u * 4] = f;
            }
        }
        asm volatile("s_waitcnt lgkmcnt(0)" ::: "memory");
        CFENCE;
    }
}

// ------------------------------------------------------------------
// 128x128 bf16 MFMA GEMM (4 waves), optional split-K via blockIdx.z.
// flags: 1=+bias  2=+=C(read)  4=relu  8=skip C writeback
// ------------------------------------------------------------------
__global__ __launch_bounds__(256) void gemm_bf16(
    const __hip_bfloat16* __restrict__ A,
    const __hip_bfloat16* __restrict__ Bt,
    const float* __restrict__ bias,
    float* __restrict__ C,
    __hip_bfloat16* __restrict__ Cb,
    int M, int N, int K, int flags)
{
    __shared__ alignas(16) __hip_bfloat16 Asm[128 * 64];
    __shared__ alignas(16) __hip_bfloat16 Bsm[128 * 64];
    const int tid  = threadIdx.x;
    const int w    = tid >> 6;
    const int lane = tid & 63;
    const int wr = w >> 1, wc = w & 1;
    const int rowA = blockIdx.y * 128;
    const int rowB = blockIdx.x * 128;
    const int klen = K / gridDim.z;
    const int kbeg = blockIdx.z * klen;

    const int srow = w * 32 + (lane >> 3);
    const int ug8  = ((lane & 7) ^ (lane >> 3)) << 3;
    const __hip_bfloat16* Ag = A  + (size_t)(rowA + srow) * K + ug8;
    const __hip_bfloat16* Bg = Bt + (size_t)(rowB + srow) * K + ug8;
    char* AsBase = (char*)Asm + w * 4096;
    char* BsBase = (char*)Bsm + w * 4096;

    fx4 acc[4][4] = {};

    const int fra = wr * 64 + (lane & 15);
    const int frb = wc * 64 + (lane & 15);
    const int kb  = (lane >> 4) << 4;
    const int swz = (lane & 7) << 4;

    for (int k0 = kbeg; k0 < kbeg + klen; k0 += 64) {
        __syncthreads();
        #pragma unroll
        for (int j = 0; j < 4; ++j) {
            gload16(Ag + (size_t)j * 8 * K + k0, AsBase + j * 1024);
            gload16(Bg + (size_t)j * 8 * K + k0, BsBase + j * 1024);
        }
        __syncthreads();
        #pragma unroll
        for (int kk = 0; kk < 2; ++kk) {
            const int cb = kk * 64 + kb;
            bhalf8 af[4], bfr[4];
            #pragma unroll
            for (int mi = 0; mi < 4; ++mi)
                af[mi] = *(const bhalf8*)((const char*)Asm + (fra + mi * 16) * 128 + (cb ^ swz));
            #pragma unroll
            for (int nj = 0; nj < 4; ++nj)
                bfr[nj] = *(const bhalf8*)((const char*)Bsm + (frb + nj * 16) * 128 + (cb ^ swz));
            #pragma unroll
            for (int mi = 0; mi < 4; ++mi)
                #pragma unroll
                for (int nj = 0; nj < 4; ++nj)
                    acc[mi][nj] = __builtin_amdgcn_mfma_f32_16x16x32_bf16(
                        af[mi], bfr[nj], acc[mi][nj], 0, 0, 0);
        }
    }

    float* Cz = C ? C + (size_t)blockIdx.z * ((size_t)M * N) : nullptr;
    #pragma unroll
    for (int nj = 0; nj < 4; ++nj) {
        const int ccol = rowB + wc * 64 + nj * 16 + (lane & 15);
        const float bv = (flags & 1) ? bias[ccol] : 0.f;
        #pragma unroll
        for (int mi = 0; mi < 4; ++mi) {
            const int crow0 = rowA + wr * 64 + mi * 16 + ((lane >> 4) << 2);
            #pragma unroll
            for (int i = 0; i < 4; ++i) {
                size_t idx = (size_t)(crow0 + i) * N + ccol;
                float v = acc[mi][nj][i] + bv;
                if (flags & 2) v += Cz[idx];
                if (flags & 4) v = fmaxf(v, 0.f);
                if (Cz && !(flags & 8)) Cz[idx] = v;
                if (Cb) Cb[idx] = __float2bfloat16(v);
            }
        }
    }
}

// dst[i] = sum_z parts[z*stride + i] (+ bias[i & colmask])
__global__ void reduce4(const float* __restrict__ parts, size_t stride,
                        const float* __restrict__ bias, int colmask,
                        float* __restrict__ dst, int n)
{
    int i = blockIdx.x * 256 + threadIdx.x;
    if (i >= n) return;
    float v = parts[i] + parts[stride + i] + parts[2 * stride + i] + parts[3 * stride + i];
    if (bias) v += bias[i & colmask];
    dst[i] = v;
}

// ------------------------------------------------------------------
// fp32 tiled GEMM (tiny E2s = ea[0:2112] @ e2w)
// ------------------------------------------------------------------
__global__ __launch_bounds__(256) void gemm_tile(
    const float* __restrict__ A, const float* __restrict__ B,
    const float* __restrict__ bias, float* __restrict__ C,
    int M, int N, int K, int flags)
{
    __shared__ float As[16][68];
    __shared__ float Bs[16][64];
    const int tid = threadIdx.x;
    const int bx = blockIdx.x, by = blockIdx.y;
    const int tx = tid & 15, ty = tid >> 4;
    const int arow = tid >> 2, acol = (tid & 3) << 2;
    const int brow = tid >> 4, bcol = (tid & 15) << 2;
    const float* Ag = A + (size_t)(by * 64 + arow) * K + acol;
    const float* Bg = B + (size_t)brow * N + bx * 64 + bcol;
    float acc[4][4] = {};
    for (int k0 = 0; k0 < K; k0 += 16) {
        const float4 av = *(const float4*)(Ag + k0);
        const float4 bv = *(const float4*)(Bg + (size_t)k0 * N);
        __syncthreads();
        As[acol + 0][arow] = av.x;
        As[acol + 1][arow] = av.y;
        As[acol + 2][arow] = av.z;
        As[acol + 3][arow] = av.w;
        *(float4*)&Bs[brow][bcol] = bv;
        __syncthreads();
        #pragma unroll
        for (int kk = 0; kk < 16; ++kk) {
            const float4 a4 = *(const float4*)&As[kk][ty << 2];
            const float4 b4 = *(const float4*)&Bs[kk][tx << 2];
            const float a[4] = {a4.x, a4.y, a4.z, a4.w};
            const float b[4] = {b4.x, b4.y, b4.z, b4.w};
            #pragma unroll
            for (int i = 0; i < 4; ++i)
                #pragma unroll
                for (int j = 0; j < 4; ++j)
                    acc[i][j] += a[i] * b[j];
        }
    }
    const int crow = by * 64 + (ty << 2);
    const int ccol = bx * 64 + (tx << 2);
    float4 b4 = make_float4(0.f, 0.f, 0.f, 0.f);
    if (flags & 1) b4 = *(const float4*)(bias + ccol);
    #pragma unroll
    for (int i = 0; i < 4; ++i) {
        float* cp = C + (size_t)(crow + i) * N + ccol;
        float4 v;
        v.x = acc[i][0] + b4.x; v.y = acc[i][1] + b4.y;
        v.z = acc[i][2] + b4.z; v.w = acc[i][3] + b4.w;
        if (flags & 2) {
            const float4 o = *(const float4*)cp;
            v.x += o.x; v.y += o.y; v.z += o.z; v.w += o.w;
        }
        *(float4*)cp = v;
    }
}

// ------------------------------------------------------------------
// CSR build
// ------------------------------------------------------------------
__global__ void count_deg(const int* __restrict__ ei, int* __restrict__ deg)
{
    int e = blockIdx.x * 256 + threadIdx.x;
    if (e < NE) atomicAdd(&deg[ei[NE + e]], 1);
}

__global__ __launch_bounds__(1024) void scan_kernel(const int* __restrict__ deg,
                                                    int* __restrict__ rowptr)
{
    __shared__ int s[1024];
    const int t = threadIdx.x;
    const int base = t * 7;
    int loc[7];
    int sum = 0;
    #pragma unroll
    for (int i = 0; i < 7; ++i) {
        int idx = base + i;
        int v = (idx < NN) ? deg[idx] : 0;
        loc[i] = v; sum += v;
    }
    s[t] = sum;
    __syncthreads();
    for (int off = 1; off < 1024; off <<= 1) {
        int v = (t >= off) ? s[t - off] : 0;
        __syncthreads();
        s[t] += v;
        __syncthreads();
    }
    int running = s[t] - sum;
    #pragma unroll
    for (int i = 0; i < 7; ++i) {
        int idx = base + i;
        if (idx <= NN) rowptr[idx] = running;
        if (idx < NN) running += loc[i];
    }
}

__global__ void fill_csr(const int* __restrict__ ei, const int* __restrict__ rowptr,
                         int* __restrict__ fillctr, int* __restrict__ elist)
{
    int e = blockIdx.x * 256 + threadIdx.x;
    if (e >= NE) return;
    int d = ei[NE + e];
    int pos = atomicAdd(&fillctr[d], 1);
    elist[rowptr[d] + pos] = e;
}

__global__ void sort_csr(const int* __restrict__ rowptr, int* __restrict__ elist)
{
    int n = blockIdx.x * 256 + threadIdx.x;
    if (n >= NN) return;
    int s0 = rowptr[n], s1 = rowptr[n + 1];
    for (int i = s0 + 1; i < s1; ++i) {
        int v = elist[i];
        int j = i - 1;
        while (j >= s0 && elist[j] > v) { elist[j + 1] = elist[j]; --j; }
        elist[j + 1] = v;
    }
}

// ------------------------------------------------------------------
// conversions / weight prep
// ------------------------------------------------------------------
__global__ void cvt_pad_bf16(const float* __restrict__ src, __hip_bfloat16* __restrict__ dst,
                             int relu)
{
    size_t i = (size_t)(blockIdx.x * 256 + threadIdx.x) * 4;
    int row = (int)(i >> 11);
    float4 v = make_float4(0.f, 0.f, 0.f, 0.f);
    if (row < NN) v = *(const float4*)&src[i];
    if (relu) {
        v.x = fmaxf(v.x, 0.f); v.y = fmaxf(v.y, 0.f);
        v.z = fmaxf(v.z, 0.f); v.w = fmaxf(v.w, 0.f);
    }
    dst[i + 0] = __float2bfloat16(v.x);
    dst[i + 1] = __float2bfloat16(v.y);
    dst[i + 2] = __float2bfloat16(v.z);
    dst[i + 3] = __float2bfloat16(v.w);
}

// 4 transposes in one dispatch: Bt[z][n][k] = bf16(Wz[k][n])
__global__ __launch_bounds__(256) void transpose_cvt4(
    const float* __restrict__ W0, const float* __restrict__ W1,
    const float* __restrict__ W2, const float* __restrict__ W3,
    __hip_bfloat16* __restrict__ dst)
{
    const float* W = (blockIdx.z == 0) ? W0 : (blockIdx.z == 1) ? W1
                   : (blockIdx.z == 2) ? W2 : W3;
    __hip_bfloat16* Bt = dst + (size_t)blockIdx.z * KDIM * KDIM;
    __shared__ float t[32][33];
    int kb = blockIdx.y * 32, nb = blockIdx.x * 32;
    int tx = threadIdx.x & 31, ty = threadIdx.x >> 5;
    #pragma unroll
    for (int i = 0; i < 32; i += 8)
        t[ty + i][tx] = W[(size_t)(kb + ty + i) * KDIM + nb + tx];
    __syncthreads();
    #pragma unroll
    for (int i = 0; i < 32; i += 8)
        Bt[(size_t)(nb + ty + i) * KDIM + kb + tx] = __float2bfloat16(t[tx][ty + i]);
}

__global__ void build_bcat(const float* __restrict__ q1b, const float* __restrict__ k1b,
                           const float* __restrict__ v1b, const float* __restrict__ s1b,
                           float* __restrict__ bcat)
{
    int i = blockIdx.x * 256 + threadIdx.x;
    if (i >= 4 * KDIM) return;
    int seg = i >> 11, j = i & 2047;
    const float* b = (seg == 0) ? q1b : (seg == 1) ? k1b : (seg == 2) ? v1b : s1b;
    bcat[i] = b[j];
}

__global__ void build_w1pp(const float* __restrict__ e1w, __hip_bfloat16* __restrict__ w1pp)
{
    int idx = blockIdx.x * 256 + threadIdx.x;
    int p = idx >> 11, j = idx & 2047;
    float v = ((j >> 10) == (p >> 6)) ? e1w[(size_t)(p & 63) * KDIM + j] : 0.f;
    w1pp[idx] = __float2bfloat16(v);
}

__global__ void build_w1ppT(const float* __restrict__ e1w, __hip_bfloat16* __restrict__ w1ppT)
{
    int idx = blockIdx.x * 256 + threadIdx.x;
    int n = idx >> 7, k = idx & 127;
    float v = ((n >> 10) == (k >> 6)) ? e1w[(size_t)(k & 63) * KDIM + n] : 0.f;
    w1ppT[idx] = __float2bfloat16(v);
}

__global__ void build_w2t(const float* __restrict__ qw, const float* __restrict__ kw,
                          const float* __restrict__ vw, const float* __restrict__ sw,
                          const float* __restrict__ qb, const float* __restrict__ kb,
                          const float* __restrict__ vb, const float* __restrict__ sb,
                          __hip_bfloat16* __restrict__ w2t, float* __restrict__ b2)
{
    int idx = blockIdx.x * 256 + threadIdx.x;
    int c = idx >> 11, d = idx & 2047;
    int g = c >> 6, j = c & 63;
    const float* w = (g == 0) ? qw : (g == 1) ? kw : (g == 2) ? vw : sw;
    w2t[idx] = __float2bfloat16(w[(size_t)d * 64 + j]);
    if (d == 0) {
        const float* b = (g == 0) ? qb : (g == 1) ? kb : (g == 2) ? vb : sb;
        b2[c] = b[j];
    }
}

// ------------------------------------------------------------------
// node1: fused alpha1 + softmax + R1 + V-aggregation. One block/node.
// ------------------------------------------------------------------
__global__ __launch_bounds__(256) void node1_kernel(
    const __hip_bfloat16* __restrict__ q1b, const __hip_bfloat16* __restrict__ k1b,
    const __hip_bfloat16* __restrict__ v1b,
    const float* __restrict__ P1, const float* __restrict__ ea,
    const int* __restrict__ ei, const int* __restrict__ rowptr,
    const int* __restrict__ elist,
    float* __restrict__ h1, __hip_bfloat16* __restrict__ R1)
{
    __shared__ int   s_src[256];
    __shared__ int   s_em[256];
    __shared__ float s_at[256][2];
    const int n = blockIdx.x;
    const int s0 = rowptr[n];
    const int deg = rowptr[n + 1] - s0;
    const int w = threadIdx.x >> 6, lane = threadIdx.x & 63;

    // phase A: dots
    for (int j = w; j < deg; j += 4) {
        const int e = elist[s0 + j];
        const int src = ei[e];
        const int em = e % EAP;
        if (lane == 0) { s_src[j] = src; s_em[j] = em; }
        const float eaj = ea[(size_t)em * 64 + lane];
        #pragma unroll
        for (int h = 0; h < 2; ++h) {
            const __hip_bfloat16* qh = q1b + (size_t)n * HC1 + h * 1024 + lane * 16;
            const __hip_bfloat16* kh = k1b + (size_t)src * HC1 + h * 1024 + lane * 16;
            bhalf8 qa = *(const bhalf8*)qh, qc = *(const bhalf8*)(qh + 8);
            bhalf8 ka = *(const bhalf8*)kh, kc = *(const bhalf8*)(kh + 8);
            float s = 0.f;
            #pragma unroll
            for (int jj = 0; jj < 8; ++jj) s += bf2f(qa[jj]) * bf2f(ka[jj]);
            #pragma unroll
            for (int jj = 0; jj < 8; ++jj) s += bf2f(qc[jj]) * bf2f(kc[jj]);
            s += eaj * P1[(size_t)n * 128 + h * 64 + lane];
            #pragma unroll
            for (int off = 32; off; off >>= 1) s += __shfl_xor(s, off);
            if (lane == 0) s_at[j][h] = s * 0.03125f;
        }
    }
    __syncthreads();

    // phase B: softmax per head
    if (threadIdx.x < 2) {
        const int h = threadIdx.x;
        float m = -1e30f;
        for (int j = 0; j < deg; ++j) m = fmaxf(m, s_at[j][h]);
        float sum = 0.f;
        for (int j = 0; j < deg; ++j) {
            float ex = __expf(s_at[j][h] - m);
            s_at[j][h] = ex; sum += ex;
        }
        float inv = 1.f / (sum + 1e-16f);
        for (int j = 0; j < deg; ++j) s_at[j][h] *= inv;
    }
    __syncthreads();

    // phase C: R1
    if (threadIdx.x < 128) {
        const int h = threadIdx.x >> 6, jj = threadIdx.x & 63;
        float r = 0.f;
        for (int j = 0; j < deg; ++j)
            r += s_at[j][h] * ea[(size_t)s_em[j] * 64 + jj];
        R1[(size_t)n * 128 + threadIdx.x] = __float2bfloat16(r);
    }

    // phase D: h1[n][c] += sum attn * v1[src]
    const int c0 = threadIdx.x * 8;
    const int h = c0 >> 10;
    float acc[8];
    const float4 p0 = *(const float4*)&h1[(size_t)n * HC1 + c0];
    const float4 p1 = *(const float4*)&h1[(size_t)n * HC1 + c0 + 4];
    acc[0] = p0.x; acc[1] = p0.y; acc[2] = p0.z; acc[3] = p0.w;
    acc[4] = p1.x; acc[5] = p1.y; acc[6] = p1.z; acc[7] = p1.w;
    for (int j = 0; j < deg; ++j) {
        const float at = s_at[j][h];
        bhalf8 v = *(const bhalf8*)&v1b[(size_t)s_src[j] * HC1 + c0];
        #pragma unroll
        for (int jj = 0; jj < 8; ++jj) acc[jj] += at * bf2f(v[jj]);
    }
    *(float4*)&h1[(size_t)n * HC1 + c0]     = make_float4(acc[0], acc[1], acc[2], acc[3]);
    *(float4*)&h1[(size_t)n * HC1 + c0 + 4] = make_float4(acc[4], acc[5], acc[6], acc[7]);
}

// ------------------------------------------------------------------
// node2: fused alpha2 + softmax + aggregation + relu. 1 wave/node.
// ------------------------------------------------------------------
__global__ __launch_bounds__(64) void node2_kernel(
    const float* __restrict__ qkvs2, const float* __restrict__ E2s,
    const int* __restrict__ ei, const int* __restrict__ rowptr,
    const int* __restrict__ elist, float* __restrict__ out)
{
    __shared__ float s_at[256];
    __shared__ int   s_src[256];
    __shared__ int   s_em[256];
    const int n = blockIdx.x;
    const int s0 = rowptr[n];
    const int deg = rowptr[n + 1] - s0;
    const int c = threadIdx.x;
    const float q = qkvs2[(size_t)n * 256 + c];

    for (int j = 0; j < deg; ++j) {
        const int e = elist[s0 + j];
        const int src = ei[e];
        const int em = e % EAP;
        float s = q * (qkvs2[(size_t)src * 256 + 64 + c] + E2s[(size_t)em * 64 + c]);
        #pragma unroll
        for (int off = 32; off; off >>= 1) s += __shfl_xor(s, off);
        if (c == 0) { s_at[j] = s * 0.125f; s_src[j] = src; s_em[j] = em; }
    }
    __syncthreads();
    float m = -1e30f;
    for (int j = 0; j < deg; ++j) m = fmaxf(m, s_at[j]);
    float sum = 0.f;
    for (int j = 0; j < deg; ++j) sum += __expf(s_at[j] - m);
    const float inv = 1.f / (sum + 1e-16f);

    float acc = qkvs2[(size_t)n * 256 + 192 + c];
    for (int j = 0; j < deg; ++j) {
        const float at = __expf(s_at[j] - m) * inv;
        acc += at * (qkvs2[(size_t)s_src[j] * 256 + 128 + c] + E2s[(size_t)s_em[j] * 64 + c]);
    }
    out[(size_t)n * 64 + c] = fmaxf(acc, 0.f);
}

// ------------------------------------------------------------------
extern "C" void kernel_launch(void* const* d_in, const int* in_sizes, int n_in,
                              void* d_out, int out_size, void* d_ws, size_t ws_size,
                              hipStream_t stream)
{
    const float* x   = (const float*)d_in[0];
    const int*   ei  = (const int*)d_in[1];
    const float* ea  = (const float*)d_in[2];
    const float* q1w = (const float*)d_in[3];
    const float* q1b = (const float*)d_in[4];
    const float* k1w = (const float*)d_in[5];
    const float* k1b = (const float*)d_in[6];
    const float* v1w = (const float*)d_in[7];
    const float* v1b = (const float*)d_in[8];
    const float* e1w = (const float*)d_in[9];
    const float* s1w = (const float*)d_in[10];
    const float* s1b = (const float*)d_in[11];
    const float* q2w = (const float*)d_in[12];
    const float* q2b = (const float*)d_in[13];
    const float* k2w = (const float*)d_in[14];
    const float* k2b = (const float*)d_in[15];
    const float* v2w = (const float*)d_in[16];
    const float* v2b = (const float*)d_in[17];
    const float* e2w = (const float*)d_in[18];
    const float* s2w = (const float*)d_in[19];
    const float* s2b = (const float*)d_in[20];
    float* out = (float*)d_out;

    char* base = (char*)d_ws;
    size_t off = 0;
    auto alloc = [&](size_t nbytes) {
        size_t o = off; off += (nbytes + 255) & ~(size_t)255; return o;
    };
    const size_t xb_off   = alloc((size_t)MPAD * KDIM * 2);      // bf16 input (reused as h1b)
    const size_t wcat_off = alloc((size_t)4 * KDIM * KDIM * 2);  // fused weights (reused: Cpart+w2t)
    __hip_bfloat16* xb    = (__hip_bfloat16*)(base + xb_off);
    __hip_bfloat16* wcat  = (__hip_bfloat16*)(base + wcat_off);
    __hip_bfloat16* h1b   = xb;                                   // alias (xb dead after fused gemm)
    float*          Cpart = (float*)(base + wcat_off);            // alias (wcat dead after fused gemm)
    __hip_bfloat16* w2t   = (__hip_bfloat16*)(base + wcat_off + (size_t)29 * 1024 * 1024);

    __hip_bfloat16* q1bb  = (__hip_bfloat16*)(base + alloc((size_t)MPAD * HC1 * 2));
    __hip_bfloat16* k1bb  = (__hip_bfloat16*)(base + alloc((size_t)MPAD * HC1 * 2));
    __hip_bfloat16* v1bb  = (__hip_bfloat16*)(base + alloc((size_t)MPAD * HC1 * 2));
    float*          h1    = (float*)(base + alloc((size_t)MPAD * HC1 * 4));
    float*          bcat  = (float*)(base + alloc((size_t)4 * KDIM * 4));
    float*          P1    = (float*)(base + alloc((size_t)MPAD * 128 * 4));
    __hip_bfloat16* R1b   = (__hip_bfloat16*)(base + alloc((size_t)MPAD * 128 * 2));
    __hip_bfloat16* w1pp  = (__hip_bfloat16*)(base + alloc((size_t)128 * KDIM * 2));
    __hip_bfloat16* w1ppT = (__hip_bfloat16*)(base + alloc((size_t)KDIM * 128 * 2));
    float*          b2    = (float*)(base + alloc(256 * 4));
    float*          qkvs2 = (float*)(base + alloc((size_t)MPAD * 256 * 4));
    float*          E2s   = (float*)(base + alloc((size_t)2112 * 64 * 4));
    int* deg    = (int*)(base + alloc((size_t)NN * 4));
    int* fill   = (int*)(base + alloc((size_t)NN * 4));
    int* rowptr = (int*)(base + alloc((size_t)(NN + 1) * 4));
    int* elist  = (int*)(base + alloc((size_t)NE * 4));

    // --- CSR build ---
    hipMemsetAsync(deg, 0, sizeof(int) * 2 * NN, stream);
    count_deg<<<(NE + 255) / 256, 256, 0, stream>>>(ei, deg);
    scan_kernel<<<1, 1024, 0, stream>>>(deg, rowptr);
    fill_csr<<<(NE + 255) / 256, 256, 0, stream>>>(ei, rowptr, fill, elist);
    sort_csr<<<(NN + 255) / 256, 256, 0, stream>>>(rowptr, elist);

    // --- input conversion + weight prep ---
    const int cvblk = (MPAD * KDIM / 4) / 256;
    cvt_pad_bf16<<<cvblk, 256, 0, stream>>>(x, xb, 0);
    transpose_cvt4<<<dim3(KDIM / 32, KDIM / 32, 4), 256, 0, stream>>>(q1w, k1w, v1w, s1w, wcat);
    build_bcat<<<(4 * KDIM) / 256, 256, 0, stream>>>(q1b, k1b, v1b, s1b, bcat);
    build_w1pp<<<(128 * KDIM) / 256, 256, 0, stream>>>(e1w, w1pp);
    build_w1ppT<<<(KDIM * 128) / 256, 256, 0, stream>>>(e1w, w1ppT);
    gemm_tile<<<dim3(1, 33), 256, 0, stream>>>(ea, e2w, nullptr, E2s, 2112, 64, 64, 0);

    // --- fused layer-1 projections: 864-block 256^2 8-phase dispatch ---
    gemm256_8ph<<<864, 512, 0, stream>>>(xb, wcat, bcat, q1bb, k1bb, v1bb, h1);

    // --- P1 = q1 @ W1p (split-K 4) ---
    gemm_bf16<<<dim3(1, MPAD / 128, 4), 256, 0, stream>>>(q1bb, w1pp, nullptr, Cpart, nullptr,
                                                          MPAD, 128, KDIM, 0);
    reduce4<<<(MPAD * 128) / 256, 256, 0, stream>>>(Cpart, (size_t)MPAD * 128, nullptr, 0,
                                                    P1, MPAD * 128);

    // --- fused layer-1 attention ---
    node1_kernel<<<NN, 256, 0, stream>>>(q1bb, k1bb, v1bb, P1, ea, ei, rowptr, elist, h1, R1b);
    gemm_bf16<<<dim3(HC1 / 128, MPAD / 128), 256, 0, stream>>>(R1b, w1ppT, nullptr, h1, h1b,
                                                               MPAD, HC1, 128, 2 | 4 | 8);

    // --- layer 2 projections (split-K 4) ---
    build_w2t<<<(256 * KDIM) / 256, 256, 0, stream>>>(q2w, k2w, v2w, s2w, q2b, k2b, v2b, s2b,
                                                      w2t, b2);
    gemm_bf16<<<dim3(2, MPAD / 128, 4), 256, 0, stream>>>(h1b, w2t, nullptr, Cpart, nullptr,
                                                          MPAD, 256, KDIM, 0);
    reduce4<<<(MPAD * 256) / 256, 256, 0, stream>>>(Cpart, (size_t)MPAD * 256, b2, 255,
                                                    qkvs2, MPAD * 256);

    // --- fused layer-2 attention ---
    node2_kernel<<<NN, 64, 0, stream>>>(qkvs2, E2s, ei, rowptr, elist, out);

    (void)in_sizes; (void)n_in; (void)out_size; (void)ws_size;
}

// Round 11
// 477.521 us; speedup vs baseline: 7.5689x; 1.0124x over previous
//
#include <hip/hip_runtime.h>
#include <hip/hip_bf16.h>
#include <cstdint>
#include <cstddef>

#define NN    6720     // nodes
#define MPAD  6912     // 27 * 256
#define NE    33600    // edges
#define KDIM  2048
#define HC1   2048
#define EAP   2100     // edge_attr tile period

typedef __attribute__((ext_vector_type(8))) short bhalf8;
typedef __attribute__((ext_vector_type(4))) short bhalf4;
typedef __attribute__((ext_vector_type(4))) float fx4;

__device__ __forceinline__ float bf2f(short s) {
    union { unsigned int u; float f; } c;
    c.u = ((unsigned int)(unsigned short)s) << 16;
    return c.f;
}

__device__ __forceinline__ void gload16(const __hip_bfloat16* g, void* lds)
{
    __builtin_amdgcn_global_load_lds(
        (const __attribute__((address_space(1))) unsigned int*)g,
        (__attribute__((address_space(3))) unsigned int*)lds,
        16, 0, 0);
}

#define CFENCE asm volatile("" ::: "memory")

// ------------------------------------------------------------------
// 256x256-tile 8-wave fused projection GEMM, front-loaded-read form.
// BK=64 split as two K-half planes [256 rows][32 K] (64B rows), 2 dbuf
// -> 4x16KB per operand = 128KB LDS. Per K-tile T (4 phases):
//  ph0: read ALL frags (24 ds_read_b128 -> 48 VGPR); stage tile T+1's
//       last quarter (other dbuf - safe); barrier; lgkmcnt(0);
//       16 MFMA (mi0-3,kk0); barrier.  After this barrier ALL waves'
//       reads are complete -> current dbuf is free for restaging.
//  ph1-3: stage one quarter of tile T+2 into the CURRENT dbuf
//       (hazard-free per above); pure 16-MFMA region; barrier.
//  tile end: vmcnt(6) (T<=29) / vmcnt(0) (T==30): tile T+1 fully
//       staged; T+2's 3 quarters (6 loads) still in flight.
// XCD stripe: XCD owns 4 of 32 N-panels (B slice 4MB = L2).
// Epilogue: 272B-padded LDS scratch, full-line stores (r7-verified).
// ------------------------------------------------------------------
__global__ __launch_bounds__(512, 2) void gemm256_fl(
    const __hip_bfloat16* __restrict__ A,
    const __hip_bfloat16* __restrict__ Bt,
    const float* __restrict__ bcat,
    __hip_bfloat16* __restrict__ oq,
    __hip_bfloat16* __restrict__ ok,
    __hip_bfloat16* __restrict__ ov,
    float* __restrict__ oh)
{
    __shared__ alignas(16) char Lds[131072];  // A: [dbuf][khalf] 4x16KB @0 | B @65536

    const int bid = blockIdx.x;
    const int i0  = bid >> 3;
    const int bx  = (bid & 7) * 4 + (i0 & 3);   // 32 N-panels of 256
    const int by  = i0 >> 2;                    // 27 M-panels of 256

    const int tid  = threadIdx.x;
    const int w    = tid >> 6;        // 0..7
    const int lane = tid & 63;
    const int wm = w >> 2, wn = w & 3;          // wave tile 128x64
    const int l15 = lane & 15;
    const int rowA = by * 256;
    const int rowB = bx * 256;

    const int sug = ((lane & 3) ^ ((lane >> 3) & 3)) << 3;
    const __hip_bfloat16* Agb = A  + (size_t)(rowA + w * 32 + (lane >> 2)) * KDIM + sug;
    const __hip_bfloat16* Bgb = Bt + (size_t)(rowB + w * 32 + (lane >> 2)) * KDIM + sug;

    const int rds = ((lane >> 4) ^ ((l15 >> 1) & 3)) << 4;

    fx4 acc[8][4] = {};

#define STAGE(TS, H)                                                       \
    { char* dst_ = Lds + (((H) >> 1) ? 65536 : 0) + ((TS) & 1) * 32768     \
                   + ((H) & 1) * 16384 + w * 2048;                         \
      const __hip_bfloat16* g_ = ((((H) >> 1)) ? Bgb : Agb)                \
                   + (size_t)(TS) * 64 + ((H) & 1) * 32;                   \
      gload16(g_, dst_);                                                   \
      gload16(g_ + 16 * KDIM, dst_ + 1024); }

#define QMFMA(MI0, KK)                                                     \
    __builtin_amdgcn_s_setprio(1);                                         \
    _Pragma("unroll")                                                      \
    for (int mi = 0; mi < 4; ++mi)                                         \
        _Pragma("unroll")                                                  \
        for (int nj = 0; nj < 4; ++nj)                                     \
            acc[(MI0) + mi][nj] = __builtin_amdgcn_mfma_f32_16x16x32_bf16( \
                af[(MI0) + mi][KK], bf[nj][KK], acc[(MI0) + mi][nj], 0, 0, 0); \
    __builtin_amdgcn_s_setprio(0);

    STAGE(0, 0); STAGE(0, 1); STAGE(0, 2); STAGE(0, 3);
    STAGE(1, 0); STAGE(1, 1); STAGE(1, 2);
    asm volatile("s_waitcnt vmcnt(6)" ::: "memory");
    __builtin_amdgcn_s_barrier(); CFENCE;

    for (int T = 0; T < 32; ++T) {
        const char* A0 = Lds + (T & 1) * 32768;
        const char* B0 = Lds + 65536 + (T & 1) * 32768;
        bhalf8 af[8][2], bf[4][2];

        // ---- phase 0: front-loaded reads + q0 ----
        #pragma unroll
        for (int nj = 0; nj < 4; ++nj)
            bf[nj][0] = *(const bhalf8*)(B0 + (wn * 64 + nj * 16 + l15) * 64 + rds);
        #pragma unroll
        for (int mi = 0; mi < 8; ++mi)
            af[mi][0] = *(const bhalf8*)(A0 + (wm * 128 + mi * 16 + l15) * 64 + rds);
        #pragma unroll
        for (int nj = 0; nj < 4; ++nj)
            bf[nj][1] = *(const bhalf8*)(B0 + 16384 + (wn * 64 + nj * 16 + l15) * 64 + rds);
        #pragma unroll
        for (int mi = 0; mi < 8; ++mi)
            af[mi][1] = *(const bhalf8*)(A0 + 16384 + (wm * 128 + mi * 16 + l15) * 64 + rds);
        if (T <= 30) { STAGE(T + 1, 3) }
        CFENCE;
        __builtin_amdgcn_s_barrier();
        asm volatile("s_waitcnt lgkmcnt(0)" ::: "memory");
        CFENCE;
        QMFMA(0, 0)
        CFENCE; __builtin_amdgcn_s_barrier(); CFENCE;
        // ---- phase 1: pure MFMA + restage current dbuf (freed) ----
        if (T <= 29) { STAGE(T + 2, 0) }
        QMFMA(4, 0)
        CFENCE; __builtin_amdgcn_s_barrier(); CFENCE;
        // ---- phase 2 ----
        if (T <= 29) { STAGE(T + 2, 1) }
        QMFMA(0, 1)
        CFENCE; __builtin_amdgcn_s_barrier(); CFENCE;
        // ---- phase 3 ----
        if (T <= 29) { STAGE(T + 2, 2) }
        QMFMA(4, 1)
        if (T <= 29)      { asm volatile("s_waitcnt vmcnt(6)" ::: "memory"); }
        else if (T == 30) { asm volatile("s_waitcnt vmcnt(0)" ::: "memory"); }
        CFENCE; __builtin_amdgcn_s_barrier(); CFENCE;
    }
#undef QMFMA
#undef STAGE

    // ---- epilogue: 272B-padded LDS scratch, full-line stores ----
    const int gcol = rowB + wn * 64;
    const int seg  = gcol >> 11;            // 0:q 1:k 2:v 3:skip(fp32)
    const int lcol = gcol & 2047;
    float bv[4];
    #pragma unroll
    for (int nj = 0; nj < 4; ++nj) bv[nj] = bcat[gcol + nj * 16 + l15];
    char* scr = Lds + w * 8704;             // wave-private 32 rows x 272B
    const int growA = rowA + wm * 128;

    #pragma unroll
    for (int c = 0; c < 4; ++c) {
        #pragma unroll
        for (int m2 = 0; m2 < 2; ++m2) {
            const int mi = c * 2 + m2;
            #pragma unroll
            for (int nj = 0; nj < 4; ++nj) {
                const int cl = nj * 16 + l15;
                #pragma unroll
                for (int i2 = 0; i2 < 4; ++i2) {
                    const int rl = m2 * 16 + ((lane >> 4) << 2) + i2;
                    *(float*)(scr + rl * 272 + cl * 4) = acc[mi][nj][i2] + bv[nj];
                }
            }
        }
        asm volatile("s_waitcnt lgkmcnt(0)" ::: "memory");
        CFENCE;
        const int rrow = (lane >> 4);
        const int u    = lane & 15;
        if (seg < 3) {
            __hip_bfloat16* dst = (seg == 0) ? oq : (seg == 1) ? ok : ov;
            #pragma unroll
            for (int p = 0; p < 8; ++p) {
                const int row = p * 4 + rrow;
                const float4 f = *(const float4*)(scr + row * 272 + u * 16);
                bhalf4 tb;
                tb[0] = (short)__bfloat16_as_ushort(__float2bfloat16(f.x));
                tb[1] = (short)__bfloat16_as_ushort(__float2bfloat16(f.y));
                tb[2] = (short)__bfloat16_as_ushort(__float2bfloat16(f.z));
                tb[3] = (short)__bfloat16_as_ushort(__float2bfloat16(f.w));
                *(bhalf4*)&dst[(size_t)(growA + c * 32 + row) * 2048 + lcol + u * 4] = tb;
            }
        } else {
            #pragma unroll
            for (int p = 0; p < 8; ++p) {
                const int row = p * 4 + rrow;
                const float4 f = *(const float4*)(scr + row * 272 + u * 16);
                *(float4*)&oh[(size_t)(growA + c * 32 + row) * 2048 + lcol + u * 4] = f;
            }
        }
        asm volatile("s_waitcnt lgkmcnt(0)" ::: "memory");
        CFENCE;
    }
}

// ------------------------------------------------------------------
// 128x128 bf16 MFMA GEMM (4 waves), optional split-K via blockIdx.z.
// flags: 1=+bias  2=+=C(read)  4=relu  8=skip C writeback
// ------------------------------------------------------------------
__global__ __launch_bounds__(256) void gemm_bf16(
    const __hip_bfloat16* __restrict__ A,
    const __hip_bfloat16* __restrict__ Bt,
    const float* __restrict__ bias,
    float* __restrict__ C,
    __hip_bfloat16* __restrict__ Cb,
    int M, int N, int K, int flags)
{
    __shared__ alignas(16) __hip_bfloat16 Asm[128 * 64];
    __shared__ alignas(16) __hip_bfloat16 Bsm[128 * 64];
    const int tid  = threadIdx.x;
    const int w    = tid >> 6;
    const int lane = tid & 63;
    const int wr = w >> 1, wc = w & 1;
    const int rowA = blockIdx.y * 128;
    const int rowB = blockIdx.x * 128;
    const int klen = K / gridDim.z;
    const int kbeg = blockIdx.z * klen;

    const int srow = w * 32 + (lane >> 3);
    const int ug8  = ((lane & 7) ^ (lane >> 3)) << 3;
    const __hip_bfloat16* Ag = A  + (size_t)(rowA + srow) * K + ug8;
    const __hip_bfloat16* Bg = Bt + (size_t)(rowB + srow) * K + ug8;
    char* AsBase = (char*)Asm + w * 4096;
    char* BsBase = (char*)Bsm + w * 4096;

    fx4 acc[4][4] = {};

    const int fra = wr * 64 + (lane & 15);
    const int frb = wc * 64 + (lane & 15);
    const int kb  = (lane >> 4) << 4;
    const int swz = (lane & 7) << 4;

    for (int k0 = kbeg; k0 < kbeg + klen; k0 += 64) {
        __syncthreads();
        #pragma unroll
        for (int j = 0; j < 4; ++j) {
            gload16(Ag + (size_t)j * 8 * K + k0, AsBase + j * 1024);
            gload16(Bg + (size_t)j * 8 * K + k0, BsBase + j * 1024);
        }
        __syncthreads();
        #pragma unroll
        for (int kk = 0; kk < 2; ++kk) {
            const int cb = kk * 64 + kb;
            bhalf8 af[4], bfr[4];
            #pragma unroll
            for (int mi = 0; mi < 4; ++mi)
                af[mi] = *(const bhalf8*)((const char*)Asm + (fra + mi * 16) * 128 + (cb ^ swz));
            #pragma unroll
            for (int nj = 0; nj < 4; ++nj)
                bfr[nj] = *(const bhalf8*)((const char*)Bsm + (frb + nj * 16) * 128 + (cb ^ swz));
            #pragma unroll
            for (int mi = 0; mi < 4; ++mi)
                #pragma unroll
                for (int nj = 0; nj < 4; ++nj)
                    acc[mi][nj] = __builtin_amdgcn_mfma_f32_16x16x32_bf16(
                        af[mi], bfr[nj], acc[mi][nj], 0, 0, 0);
        }
    }

    float* Cz = C ? C + (size_t)blockIdx.z * ((size_t)M * N) : nullptr;
    #pragma unroll
    for (int nj = 0; nj < 4; ++nj) {
        const int ccol = rowB + wc * 64 + nj * 16 + (lane & 15);
        const float bv = (flags & 1) ? bias[ccol] : 0.f;
        #pragma unroll
        for (int mi = 0; mi < 4; ++mi) {
            const int crow0 = rowA + wr * 64 + mi * 16 + ((lane >> 4) << 2);
            #pragma unroll
            for (int i = 0; i < 4; ++i) {
                size_t idx = (size_t)(crow0 + i) * N + ccol;
                float v = acc[mi][nj][i] + bv;
                if (flags & 2) v += Cz[idx];
                if (flags & 4) v = fmaxf(v, 0.f);
                if (Cz && !(flags & 8)) Cz[idx] = v;
                if (Cb) Cb[idx] = __float2bfloat16(v);
            }
        }
    }
}

// dst[i] = sum_z parts[z*stride + i] (+ bias[i & colmask])
__global__ void reduce4(const float* __restrict__ parts, size_t stride,
                        const float* __restrict__ bias, int colmask,
                        float* __restrict__ dst, int n)
{
    int i = blockIdx.x * 256 + threadIdx.x;
    if (i >= n) return;
    float v = parts[i] + parts[stride + i] + parts[2 * stride + i] + parts[3 * stride + i];
    if (bias) v += bias[i & colmask];
    dst[i] = v;
}

// ------------------------------------------------------------------
// fp32 tiled GEMM (tiny E2s = ea[0:2112] @ e2w)
// ------------------------------------------------------------------
__global__ __launch_bounds__(256) void gemm_tile(
    const float* __restrict__ A, const float* __restrict__ B,
    const float* __restrict__ bias, float* __restrict__ C,
    int M, int N, int K, int flags)
{
    __shared__ float As[16][68];
    __shared__ float Bs[16][64];
    const int tid = threadIdx.x;
    const int bx = blockIdx.x, by = blockIdx.y;
    const int tx = tid & 15, ty = tid >> 4;
    const int arow = tid >> 2, acol = (tid & 3) << 2;
    const int brow = tid >> 4, bcol = (tid & 15) << 2;
    const float* Ag = A + (size_t)(by * 64 + arow) * K + acol;
    const float* Bg = B + (size_t)brow * N + bx * 64 + bcol;
    float acc[4][4] = {};
    for (int k0 = 0; k0 < K; k0 += 16) {
        const float4 av = *(const float4*)(Ag + k0);
        const float4 bv = *(const float4*)(Bg + (size_t)k0 * N);
        __syncthreads();
        As[acol + 0][arow] = av.x;
        As[acol + 1][arow] = av.y;
        As[acol + 2][arow] = av.z;
        As[acol + 3][arow] = av.w;
        *(float4*)&Bs[brow][bcol] = bv;
        __syncthreads();
        #pragma unroll
        for (int kk = 0; kk < 16; ++kk) {
            const float4 a4 = *(const float4*)&As[kk][ty << 2];
            const float4 b4 = *(const float4*)&Bs[kk][tx << 2];
            const float a[4] = {a4.x, a4.y, a4.z, a4.w};
            const float b[4] = {b4.x, b4.y, b4.z, b4.w};
            #pragma unroll
            for (int i = 0; i < 4; ++i)
                #pragma unroll
                for (int j = 0; j < 4; ++j)
                    acc[i][j] += a[i] * b[j];
        }
    }
    const int crow = by * 64 + (ty << 2);
    const int ccol = bx * 64 + (tx << 2);
    float4 b4 = make_float4(0.f, 0.f, 0.f, 0.f);
    if (flags & 1) b4 = *(const float4*)(bias + ccol);
    #pragma unroll
    for (int i = 0; i < 4; ++i) {
        float* cp = C + (size_t)(crow + i) * N + ccol;
        float4 v;
        v.x = acc[i][0] + b4.x; v.y = acc[i][1] + b4.y;
        v.z = acc[i][2] + b4.z; v.w = acc[i][3] + b4.w;
        if (flags & 2) {
            const float4 o = *(const float4*)cp;
            v.x += o.x; v.y += o.y; v.z += o.z; v.w += o.w;
        }
        *(float4*)cp = v;
    }
}

// ------------------------------------------------------------------
// CSR build
// ------------------------------------------------------------------
__global__ void count_deg(const int* __restrict__ ei, int* __restrict__ deg)
{
    int e = blockIdx.x * 256 + threadIdx.x;
    if (e < NE) atomicAdd(&deg[ei[NE + e]], 1);
}

__global__ __launch_bounds__(1024) void scan_kernel(const int* __restrict__ deg,
                                                    int* __restrict__ rowptr)
{
    __shared__ int s[1024];
    const int t = threadIdx.x;
    const int base = t * 7;
    int loc[7];
    int sum = 0;
    #pragma unroll
    for (int i = 0; i < 7; ++i) {
        int idx = base + i;
        int v = (idx < NN) ? deg[idx] : 0;
        loc[i] = v; sum += v;
    }
    s[t] = sum;
    __syncthreads();
    for (int off = 1; off < 1024; off <<= 1) {
        int v = (t >= off) ? s[t - off] : 0;
        __syncthreads();
        s[t] += v;
        __syncthreads();
    }
    int running = s[t] - sum;
    #pragma unroll
    for (int i = 0; i < 7; ++i) {
        int idx = base + i;
        if (idx <= NN) rowptr[idx] = running;
        if (idx < NN) running += loc[i];
    }
}

__global__ void fill_csr(const int* __restrict__ ei, const int* __restrict__ rowptr,
                         int* __restrict__ fillctr, int* __restrict__ elist)
{
    int e = blockIdx.x * 256 + threadIdx.x;
    if (e >= NE) return;
    int d = ei[NE + e];
    int pos = atomicAdd(&fillctr[d], 1);
    elist[rowptr[d] + pos] = e;
}

__global__ void sort_csr(const int* __restrict__ rowptr, int* __restrict__ elist)
{
    int n = blockIdx.x * 256 + threadIdx.x;
    if (n >= NN) return;
    int s0 = rowptr[n], s1 = rowptr[n + 1];
    for (int i = s0 + 1; i < s1; ++i) {
        int v = elist[i];
        int j = i - 1;
        while (j >= s0 && elist[j] > v) { elist[j + 1] = elist[j]; --j; }
        elist[j + 1] = v;
    }
}

// ------------------------------------------------------------------
// conversions / weight prep
// ------------------------------------------------------------------
__global__ void cvt_pad_bf16(const float* __restrict__ src, __hip_bfloat16* __restrict__ dst,
                             int relu)
{
    size_t i = (size_t)(blockIdx.x * 256 + threadIdx.x) * 4;
    int row = (int)(i >> 11);
    float4 v = make_float4(0.f, 0.f, 0.f, 0.f);
    if (row < NN) v = *(const float4*)&src[i];
    if (relu) {
        v.x = fmaxf(v.x, 0.f); v.y = fmaxf(v.y, 0.f);
        v.z = fmaxf(v.z, 0.f); v.w = fmaxf(v.w, 0.f);
    }
    dst[i + 0] = __float2bfloat16(v.x);
    dst[i + 1] = __float2bfloat16(v.y);
    dst[i + 2] = __float2bfloat16(v.z);
    dst[i + 3] = __float2bfloat16(v.w);
}

// 4 transposes in one dispatch: Bt[z][n][k] = bf16(Wz[k][n])
__global__ __launch_bounds__(256) void transpose_cvt4(
    const float* __restrict__ W0, const float* __restrict__ W1,
    const float* __restrict__ W2, const float* __restrict__ W3,
    __hip_bfloat16* __restrict__ dst)
{
    const float* W = (blockIdx.z == 0) ? W0 : (blockIdx.z == 1) ? W1
                   : (blockIdx.z == 2) ? W2 : W3;
    __hip_bfloat16* Bt = dst + (size_t)blockIdx.z * KDIM * KDIM;
    __shared__ float t[32][33];
    int kb = blockIdx.y * 32, nb = blockIdx.x * 32;
    int tx = threadIdx.x & 31, ty = threadIdx.x >> 5;
    #pragma unroll
    for (int i = 0; i < 32; i += 8)
        t[ty + i][tx] = W[(size_t)(kb + ty + i) * KDIM + nb + tx];
    __syncthreads();
    #pragma unroll
    for (int i = 0; i < 32; i += 8)
        Bt[(size_t)(nb + ty + i) * KDIM + kb + tx] = __float2bfloat16(t[tx][ty + i]);
}

// merged small weight-prep: bcat | w1pp | w1ppT | w2t+b2
__global__ void build_misc(
    const float* __restrict__ q1b, const float* __restrict__ k1b,
    const float* __restrict__ v1b, const float* __restrict__ s1b,
    const float* __restrict__ e1w,
    const float* __restrict__ q2w, const float* __restrict__ k2w,
    const float* __restrict__ v2w, const float* __restrict__ s2w,
    const float* __restrict__ q2bb, const float* __restrict__ k2bb,
    const float* __restrict__ v2bb, const float* __restrict__ s2bb,
    float* __restrict__ bcat, __hip_bfloat16* __restrict__ w1pp,
    __hip_bfloat16* __restrict__ w1ppT, __hip_bfloat16* __restrict__ w2t,
    float* __restrict__ b2)
{
    int idx = blockIdx.x * 256 + threadIdx.x;
    if (idx < 8192) {
        int seg = idx >> 11, j = idx & 2047;
        const float* b = (seg == 0) ? q1b : (seg == 1) ? k1b : (seg == 2) ? v1b : s1b;
        bcat[idx] = b[j];
        return;
    }
    idx -= 8192;
    if (idx < 262144) {   // w1pp [128][2048]
        int p = idx >> 11, j = idx & 2047;
        float v = ((j >> 10) == (p >> 6)) ? e1w[(size_t)(p & 63) * KDIM + j] : 0.f;
        w1pp[idx] = __float2bfloat16(v);
        return;
    }
    idx -= 262144;
    if (idx < 262144) {   // w1ppT [2048][128]
        int n = idx >> 7, k = idx & 127;
        float v = ((n >> 10) == (k >> 6)) ? e1w[(size_t)(k & 63) * KDIM + n] : 0.f;
        w1ppT[idx] = __float2bfloat16(v);
        return;
    }
    idx -= 262144;        // w2t [256][2048] + b2
    int c = idx >> 11, d = idx & 2047;
    int g = c >> 6, j = c & 63;
    const float* w = (g == 0) ? q2w : (g == 1) ? k2w : (g == 2) ? v2w : s2w;
    w2t[idx] = __float2bfloat16(w[(size_t)d * 64 + j]);
    if (d == 0) {
        const float* b = (g == 0) ? q2bb : (g == 1) ? k2bb : (g == 2) ? v2bb : s2bb;
        b2[c] = b[j];
    }
}

// ------------------------------------------------------------------
// node1: fused alpha1 + softmax + R1 + V-aggregation. One block/node.
// ------------------------------------------------------------------
__global__ __launch_bounds__(256) void node1_kernel(
    const __hip_bfloat16* __restrict__ q1b, const __hip_bfloat16* __restrict__ k1b,
    const __hip_bfloat16* __restrict__ v1b,
    const float* __restrict__ P1, const float* __restrict__ ea,
    const int* __restrict__ ei, const int* __restrict__ rowptr,
    const int* __restrict__ elist,
    float* __restrict__ h1, __hip_bfloat16* __restrict__ R1)
{
    __shared__ int   s_src[256];
    __shared__ int   s_em[256];
    __shared__ float s_at[256][2];
    const int n = blockIdx.x;
    const int s0 = rowptr[n];
    const int deg = rowptr[n + 1] - s0;
    const int w = threadIdx.x >> 6, lane = threadIdx.x & 63;

    for (int j = w; j < deg; j += 4) {
        const int e = elist[s0 + j];
        const int src = ei[e];
        const int em = e % EAP;
        if (lane == 0) { s_src[j] = src; s_em[j] = em; }
        const float eaj = ea[(size_t)em * 64 + lane];
        #pragma unroll
        for (int h = 0; h < 2; ++h) {
            const __hip_bfloat16* qh = q1b + (size_t)n * HC1 + h * 1024 + lane * 16;
            const __hip_bfloat16* kh = k1b + (size_t)src * HC1 + h * 1024 + lane * 16;
            bhalf8 qa = *(const bhalf8*)qh, qc = *(const bhalf8*)(qh + 8);
            bhalf8 ka = *(const bhalf8*)kh, kc = *(const bhalf8*)(kh + 8);
            float s = 0.f;
            #pragma unroll
            for (int jj = 0; jj < 8; ++jj) s += bf2f(qa[jj]) * bf2f(ka[jj]);
            #pragma unroll
            for (int jj = 0; jj < 8; ++jj) s += bf2f(qc[jj]) * bf2f(kc[jj]);
            s += eaj * P1[(size_t)n * 128 + h * 64 + lane];
            #pragma unroll
            for (int off = 32; off; off >>= 1) s += __shfl_xor(s, off);
            if (lane == 0) s_at[j][h] = s * 0.03125f;
        }
    }
    __syncthreads();

    if (threadIdx.x < 2) {
        const int h = threadIdx.x;
        float m = -1e30f;
        for (int j = 0; j < deg; ++j) m = fmaxf(m, s_at[j][h]);
        float sum = 0.f;
        for (int j = 0; j < deg; ++j) {
            float ex = __expf(s_at[j][h] - m);
            s_at[j][h] = ex; sum += ex;
        }
        float inv = 1.f / (sum + 1e-16f);
        for (int j = 0; j < deg; ++j) s_at[j][h] *= inv;
    }
    __syncthreads();

    if (threadIdx.x < 128) {
        const int h = threadIdx.x >> 6, jj = threadIdx.x & 63;
        float r = 0.f;
        for (int j = 0; j < deg; ++j)
            r += s_at[j][h] * ea[(size_t)s_em[j] * 64 + jj];
        R1[(size_t)n * 128 + threadIdx.x] = __float2bfloat16(r);
    }

    const int c0 = threadIdx.x * 8;
    const int h = c0 >> 10;
    float acc[8];
    const float4 p0 = *(const float4*)&h1[(size_t)n * HC1 + c0];
    const float4 p1 = *(const float4*)&h1[(size_t)n * HC1 + c0 + 4];
    acc[0] = p0.x; acc[1] = p0.y; acc[2] = p0.z; acc[3] = p0.w;
    acc[4] = p1.x; acc[5] = p1.y; acc[6] = p1.z; acc[7] = p1.w;
    for (int j = 0; j < deg; ++j) {
        const float at = s_at[j][h];
        bhalf8 v = *(const bhalf8*)&v1b[(size_t)s_src[j] * HC1 + c0];
        #pragma unroll
        for (int jj = 0; jj < 8; ++jj) acc[jj] += at * bf2f(v[jj]);
    }
    *(float4*)&h1[(size_t)n * HC1 + c0]     = make_float4(acc[0], acc[1], acc[2], acc[3]);
    *(float4*)&h1[(size_t)n * HC1 + c0 + 4] = make_float4(acc[4], acc[5], acc[6], acc[7]);
}

// ------------------------------------------------------------------
// node2: fused alpha2 + softmax + aggregation + relu. 1 wave/node.
// ------------------------------------------------------------------
__global__ __launch_bounds__(64) void node2_kernel(
    const float* __restrict__ qkvs2, const float* __restrict__ E2s,
    const int* __restrict__ ei, const int* __restrict__ rowptr,
    const int* __restrict__ elist, float* __restrict__ out)
{
    __shared__ float s_at[256];
    __shared__ int   s_src[256];
    __shared__ int   s_em[256];
    const int n = blockIdx.x;
    const int s0 = rowptr[n];
    const int deg = rowptr[n + 1] - s0;
    const int c = threadIdx.x;
    const float q = qkvs2[(size_t)n * 256 + c];

    for (int j = 0; j < deg; ++j) {
        const int e = elist[s0 + j];
        const int src = ei[e];
        const int em = e % EAP;
        float s = q * (qkvs2[(size_t)src * 256 + 64 + c] + E2s[(size_t)em * 64 + c]);
        #pragma unroll
        for (int off = 32; off; off >>= 1) s += __shfl_xor(s, off);
        if (c == 0) { s_at[j] = s * 0.125f; s_src[j] = src; s_em[j] = em; }
    }
    __syncthreads();
    float m = -1e30f;
    for (int j = 0; j < deg; ++j) m = fmaxf(m, s_at[j]);
    float sum = 0.f;
    for (int j = 0; j < deg; ++j) sum += __expf(s_at[j] - m);
    const float inv = 1.f / (sum + 1e-16f);

    float acc = qkvs2[(size_t)n * 256 + 192 + c];
    for (int j = 0; j < deg; ++j) {
        const float at = __expf(s_at[j] - m) * inv;
        acc += at * (qkvs2[(size_t)s_src[j] * 256 + 128 + c] + E2s[(size_t)s_em[j] * 64 + c]);
    }
    out[(size_t)n * 64 + c] = fmaxf(acc, 0.f);
}

// ------------------------------------------------------------------
extern "C" void kernel_launch(void* const* d_in, const int* in_sizes, int n_in,
                              void* d_out, int out_size, void* d_ws, size_t ws_size,
                              hipStream_t stream)
{
    const float* x   = (const float*)d_in[0];
    const int*   ei  = (const int*)d_in[1];
    const float* ea  = (const float*)d_in[2];
    const float* q1w = (const float*)d_in[3];
    const float* q1b = (const float*)d_in[4];
    const float* k1w = (const float*)d_in[5];
    const float* k1b = (const float*)d_in[6];
    const float* v1w = (const float*)d_in[7];
    const float* v1b = (const float*)d_in[8];
    const float* e1w = (const float*)d_in[9];
    const float* s1w = (const float*)d_in[10];
    const float* s1b = (const float*)d_in[11];
    const float* q2w = (const float*)d_in[12];
    const float* q2b = (const float*)d_in[13];
    const float* k2w = (const float*)d_in[14];
    const float* k2b = (const float*)d_in[15];
    const float* v2w = (const float*)d_in[16];
    const float* v2b = (const float*)d_in[17];
    const float* e2w = (const float*)d_in[18];
    const float* s2w = (const float*)d_in[19];
    const float* s2b = (const float*)d_in[20];
    float* out = (float*)d_out;

    char* base = (char*)d_ws;
    size_t off = 0;
    auto alloc = [&](size_t nbytes) {
        size_t o = off; off += (nbytes + 255) & ~(size_t)255; return o;
    };
    const size_t xb_off   = alloc((size_t)MPAD * KDIM * 2);      // bf16 input (reused as h1b)
    const size_t wcat_off = alloc((size_t)4 * KDIM * KDIM * 2);  // fused weights (reused: Cpart)
    __hip_bfloat16* xb    = (__hip_bfloat16*)(base + xb_off);
    __hip_bfloat16* wcat  = (__hip_bfloat16*)(base + wcat_off);
    __hip_bfloat16* h1b   = xb;                                   // alias (xb dead after fused gemm)
    float*          Cpart = (float*)(base + wcat_off);            // alias (wcat dead after fused gemm)

    __hip_bfloat16* q1bb  = (__hip_bfloat16*)(base + alloc((size_t)MPAD * HC1 * 2));
    __hip_bfloat16* k1bb  = (__hip_bfloat16*)(base + alloc((size_t)MPAD * HC1 * 2));
    __hip_bfloat16* v1bb  = (__hip_bfloat16*)(base + alloc((size_t)MPAD * HC1 * 2));
    float*          h1    = (float*)(base + alloc((size_t)MPAD * HC1 * 4));
    float*          bcat  = (float*)(base + alloc((size_t)4 * KDIM * 4));
    float*          P1    = (float*)(base + alloc((size_t)MPAD * 128 * 4));
    __hip_bfloat16* R1b   = (__hip_bfloat16*)(base + alloc((size_t)MPAD * 128 * 2));
    __hip_bfloat16* w1pp  = (__hip_bfloat16*)(base + alloc((size_t)128 * KDIM * 2));
    __hip_bfloat16* w1ppT = (__hip_bfloat16*)(base + alloc((size_t)KDIM * 128 * 2));
    __hip_bfloat16* w2t   = (__hip_bfloat16*)(base + alloc((size_t)256 * KDIM * 2));  // DEDICATED (r10 bug: aliased wcat)
    float*          b2    = (float*)(base + alloc(256 * 4));
    float*          qkvs2 = (float*)(base + alloc((size_t)MPAD * 256 * 4));
    float*          E2s   = (float*)(base + alloc((size_t)2112 * 64 * 4));
    int* deg    = (int*)(base + alloc((size_t)NN * 4));
    int* fill   = (int*)(base + alloc((size_t)NN * 4));
    int* rowptr = (int*)(base + alloc((size_t)(NN + 1) * 4));
    int* elist  = (int*)(base + alloc((size_t)NE * 4));

    // --- CSR build ---
    hipMemsetAsync(deg, 0, sizeof(int) * 2 * NN, stream);
    count_deg<<<(NE + 255) / 256, 256, 0, stream>>>(ei, deg);
    scan_kernel<<<1, 1024, 0, stream>>>(deg, rowptr);
    fill_csr<<<(NE + 255) / 256, 256, 0, stream>>>(ei, rowptr, fill, elist);
    sort_csr<<<(NN + 255) / 256, 256, 0, stream>>>(rowptr, elist);

    // --- input conversion + weight prep ---
    const int cvblk = (MPAD * KDIM / 4) / 256;
    cvt_pad_bf16<<<cvblk, 256, 0, stream>>>(x, xb, 0);
    transpose_cvt4<<<dim3(KDIM / 32, KDIM / 32, 4), 256, 0, stream>>>(q1w, k1w, v1w, s1w, wcat);
    build_misc<<<4128, 256, 0, stream>>>(q1b, k1b, v1b, s1b, e1w,
                                         q2w, k2w, v2w, s2w, q2b, k2b, v2b, s2b,
                                         bcat, w1pp, w1ppT, w2t, b2);
    gemm_tile<<<dim3(1, 33), 256, 0, stream>>>(ea, e2w, nullptr, E2s, 2112, 64, 64, 0);

    // --- fused layer-1 projections: 864-block front-loaded-read dispatch ---
    gemm256_fl<<<864, 512, 0, stream>>>(xb, wcat, bcat, q1bb, k1bb, v1bb, h1);

    // --- P1 = q1 @ W1p (split-K 4) ---
    gemm_bf16<<<dim3(1, MPAD / 128, 4), 256, 0, stream>>>(q1bb, w1pp, nullptr, Cpart, nullptr,
                                                          MPAD, 128, KDIM, 0);
    reduce4<<<(MPAD * 128) / 256, 256, 0, stream>>>(Cpart, (size_t)MPAD * 128, nullptr, 0,
                                                    P1, MPAD * 128);

    // --- fused layer-1 attention ---
    node1_kernel<<<NN, 256, 0, stream>>>(q1bb, k1bb, v1bb, P1, ea, ei, rowptr, elist, h1, R1b);
    gemm_bf16<<<dim3(HC1 / 128, MPAD / 128), 256, 0, stream>>>(R1b, w1ppT, nullptr, h1, h1b,
                                                               MPAD, HC1, 128, 2 | 4 | 8);

    // --- layer 2 projections (split-K 4) ---
    gemm_bf16<<<dim3(2, MPAD / 128, 4), 256, 0, stream>>>(h1b, w2t, nullptr, Cpart, nullptr,
                                                          MPAD, 256, KDIM, 0);
    reduce4<<<(MPAD * 256) / 256, 256, 0, stream>>>(Cpart, (size_t)MPAD * 256, b2, 255,
                                                    qkvs2, MPAD * 256);

    // --- fused layer-2 attention ---
    node2_kernel<<<NN, 64, 0, stream>>>(qkvs2, E2s, ei, rowptr, elist, out);

    (void)in_sizes; (void)n_in; (void)out_size; (void)ws_size;
}

// Round 12
// 456.631 us; speedup vs baseline: 7.9152x; 1.0457x over previous
//
#include <hip/hip_runtime.h>
#include <hip/hip_bf16.h>
#include <cstdint>
#include <cstddef>

#define NN    6720     // nodes
#define MPAD  6912     // 27 * 256 = 54 * 128
#define NE    33600    // edges
#define KDIM  2048
#define HC1   2048
#define EAP   2100     // edge_attr tile period

typedef __attribute__((ext_vector_type(8))) short bhalf8;
typedef __attribute__((ext_vector_type(4))) short bhalf4;
typedef __attribute__((ext_vector_type(4))) float fx4;

__device__ __forceinline__ float bf2f(short s) {
    union { unsigned int u; float f; } c;
    c.u = ((unsigned int)(unsigned short)s) << 16;
    return c.f;
}

__device__ __forceinline__ void gload16(const __hip_bfloat16* g, void* lds)
{
    __builtin_amdgcn_global_load_lds(
        (const __attribute__((address_space(1))) unsigned int*)g,
        (__attribute__((address_space(3))) unsigned int*)lds,
        16, 0, 0);
}

#define CFENCE asm volatile("" ::: "memory")

// ------------------------------------------------------------------
// 256x128-tile 4-wave fused projection GEMM (r7 kernel - best measured:
// 243µs / 43.4% MfmaUtil). Wave tile 128x64. BK=32, 3-deep LDS ring
// (72KB -> 2 blocks/CU), counted vmcnt(12/6/0), setprio, XOR swizzle,
// XCD-striped block map (XCD=bid&7 owns bx [8x,8x+8): B slice 4MB=L2).
// Epilogue: 272B-padded LDS scratch; UNIFORM bf16 full-line stores
// (skip segment now bf16 too - h1 is bf16 end-to-end).
// ------------------------------------------------------------------
__global__ __launch_bounds__(256, 2) void gemm256x128_fused(
    const __hip_bfloat16* __restrict__ A,
    const __hip_bfloat16* __restrict__ Bt,
    const float* __restrict__ bcat,
    __hip_bfloat16* __restrict__ oq,
    __hip_bfloat16* __restrict__ ok,
    __hip_bfloat16* __restrict__ ov,
    __hip_bfloat16* __restrict__ oh)
{
    __shared__ alignas(16) char Lds[73728];   // A ring 3x16KB @0 | B ring 3x8KB @49152

    // XCD-locality map: 1728 = 8 XCD * 216. XCD = bid&7 owns 8 bx panels.
    const int bid = blockIdx.x;
    const int i0  = bid >> 3;
    const int bx  = (bid & 7) * 8 + (i0 & 7);   // N: 64 panels of 128
    const int by  = i0 >> 3;                    // M: 27 panels of 256

    const int tid  = threadIdx.x;
    const int w    = tid >> 6;        // 0..3
    const int lane = tid & 63;
    const int wm = w >> 1, wn = w & 1;    // 2x2 waves, wave tile 128x64
    const int rowA = by * 256;
    const int rowB = bx * 128;

    const int sug = ((lane & 3) ^ ((lane >> 3) & 3)) << 3;
    const __hip_bfloat16* Ag0 = A  + (size_t)(rowA + w * 64 + (lane >> 2)) * KDIM + sug;
    const __hip_bfloat16* Bg0 = Bt + (size_t)(rowB + w * 32 + (lane >> 2)) * KDIM + sug;

    const int rds = (((lane >> 4) ^ (((lane & 15) >> 1) & 3)) << 4);

    fx4 acc[8][4] = {};

#define STAGE(T)                                                          \
    { const int s_ = (T) % 3; const int k0_ = (T) * 32;                   \
      char* ab_ = Lds + s_ * 16384 + w * 4096;                            \
      char* bb_ = Lds + 49152 + s_ * 8192 + w * 2048;                     \
      gload16(Ag0 + k0_, ab_);                                            \
      gload16(Ag0 + k0_ + 16 * KDIM, ab_ + 1024);                         \
      gload16(Ag0 + k0_ + 32 * KDIM, ab_ + 2048);                         \
      gload16(Ag0 + k0_ + 48 * KDIM, ab_ + 3072);                         \
      gload16(Bg0 + k0_, bb_);                                            \
      gload16(Bg0 + k0_ + 16 * KDIM, bb_ + 1024); }

#define TILE(T, VM, DOSTAGE)                                              \
    { if (DOSTAGE) { STAGE((T) + 2); }                                    \
      asm volatile("s_waitcnt vmcnt(" VM ")" ::: "memory");               \
      __builtin_amdgcn_s_barrier(); CFENCE;                               \
      const int s_ = (T) % 3;                                             \
      const char* ap_ = Lds + s_ * 16384;                                 \
      const char* bp_ = Lds + 49152 + s_ * 8192;                          \
      bhalf8 af_[8], bf_[4];                                              \
      _Pragma("unroll")                                                   \
      for (int nj = 0; nj < 4; ++nj)                                      \
          bf_[nj] = *(const bhalf8*)(bp_ + (wn * 64 + nj * 16 + (lane & 15)) * 64 + rds); \
      _Pragma("unroll")                                                   \
      for (int mi = 0; mi < 8; ++mi)                                      \
          af_[mi] = *(const bhalf8*)(ap_ + (wm * 128 + mi * 16 + (lane & 15)) * 64 + rds); \
      __builtin_amdgcn_s_setprio(1);                                      \
      _Pragma("unroll")                                                   \
      for (int mi = 0; mi < 8; ++mi)                                      \
          _Pragma("unroll")                                               \
          for (int nj = 0; nj < 4; ++nj)                                  \
              acc[mi][nj] = __builtin_amdgcn_mfma_f32_16x16x32_bf16(      \
                  af_[mi], bf_[nj], acc[mi][nj], 0, 0, 0);                \
      __builtin_amdgcn_s_setprio(0); CFENCE;                              \
      __builtin_amdgcn_s_barrier(); CFENCE; }

    STAGE(0); STAGE(1);
    for (int t = 0; t < (KDIM / 32) - 2; ++t) {
        TILE(t, "12", 1);
    }
    TILE((KDIM / 32) - 2, "6", 0);
    TILE((KDIM / 32) - 1, "0", 0);

#undef TILE
#undef STAGE

    // ---- epilogue: 272B-padded LDS scratch, uniform bf16 stores ----
    const int gcol = rowB + wn * 64;
    const int seg  = gcol >> 11;            // 0:q 1:k 2:v 3:skip
    const int lcol = gcol & 2047;
    float bv[4];
    #pragma unroll
    for (int nj = 0; nj < 4; ++nj) bv[nj] = bcat[gcol + nj * 16 + (lane & 15)];
    char* scr = Lds + w * 8704;             // wave-private 32 rows x 272B
    const int growA = rowA + wm * 128;
    __hip_bfloat16* dst = (seg == 0) ? oq : (seg == 1) ? ok : (seg == 2) ? ov : oh;

    #pragma unroll
    for (int c = 0; c < 4; ++c) {           // 4 chunks of 32 rows
        #pragma unroll
        for (int m2 = 0; m2 < 2; ++m2) {
            const int mi = c * 2 + m2;
            #pragma unroll
            for (int nj = 0; nj < 4; ++nj) {
                const int cl = nj * 16 + (lane & 15);
                #pragma unroll
                for (int i2 = 0; i2 < 4; ++i2) {
                    const int rl = m2 * 16 + ((lane >> 4) << 2) + i2;
                    *(float*)(scr + rl * 272 + cl * 4) = acc[mi][nj][i2] + bv[nj];
                }
            }
        }
        asm volatile("s_waitcnt lgkmcnt(0)" ::: "memory");
        CFENCE;
        const int rrow = (lane >> 4);
        const int u    = lane & 15;
        #pragma unroll
        for (int p = 0; p < 8; ++p) {
            const int row = p * 4 + rrow;
            const float4 f = *(const float4*)(scr + row * 272 + u * 16);
            bhalf4 tb;
            tb[0] = (short)__bfloat16_as_ushort(__float2bfloat16(f.x));
            tb[1] = (short)__bfloat16_as_ushort(__float2bfloat16(f.y));
            tb[2] = (short)__bfloat16_as_ushort(__float2bfloat16(f.z));
            tb[3] = (short)__bfloat16_as_ushort(__float2bfloat16(f.w));
            *(bhalf4*)&dst[(size_t)(growA + c * 32 + row) * 2048 + lcol + u * 4] = tb;
        }
        asm volatile("s_waitcnt lgkmcnt(0)" ::: "memory");
        CFENCE;
    }
}

// ------------------------------------------------------------------
// 128x128 bf16 MFMA GEMM (4 waves), optional split-K via blockIdx.z.
// flags: 1=+bias  2=+=C fp32 read  4=relu  8=skip C writeback
//        16=+=Cb bf16 read (in-place bf16 accumulate path)
// ------------------------------------------------------------------
__global__ __launch_bounds__(256) void gemm_bf16(
    const __hip_bfloat16* __restrict__ A,
    const __hip_bfloat16* __restrict__ Bt,
    const float* __restrict__ bias,
    float* __restrict__ C,
    __hip_bfloat16* __restrict__ Cb,
    int M, int N, int K, int flags)
{
    __shared__ alignas(16) __hip_bfloat16 Asm[128 * 64];
    __shared__ alignas(16) __hip_bfloat16 Bsm[128 * 64];
    const int tid  = threadIdx.x;
    const int w    = tid >> 6;
    const int lane = tid & 63;
    const int wr = w >> 1, wc = w & 1;
    const int rowA = blockIdx.y * 128;
    const int rowB = blockIdx.x * 128;
    const int klen = K / gridDim.z;
    const int kbeg = blockIdx.z * klen;

    const int srow = w * 32 + (lane >> 3);
    const int ug8  = ((lane & 7) ^ (lane >> 3)) << 3;
    const __hip_bfloat16* Ag = A  + (size_t)(rowA + srow) * K + ug8;
    const __hip_bfloat16* Bg = Bt + (size_t)(rowB + srow) * K + ug8;
    char* AsBase = (char*)Asm + w * 4096;
    char* BsBase = (char*)Bsm + w * 4096;

    fx4 acc[4][4] = {};

    const int fra = wr * 64 + (lane & 15);
    const int frb = wc * 64 + (lane & 15);
    const int kb  = (lane >> 4) << 4;
    const int swz = (lane & 7) << 4;

    for (int k0 = kbeg; k0 < kbeg + klen; k0 += 64) {
        __syncthreads();
        #pragma unroll
        for (int j = 0; j < 4; ++j) {
            gload16(Ag + (size_t)j * 8 * K + k0, AsBase + j * 1024);
            gload16(Bg + (size_t)j * 8 * K + k0, BsBase + j * 1024);
        }
        __syncthreads();
        #pragma unroll
        for (int kk = 0; kk < 2; ++kk) {
            const int cb = kk * 64 + kb;
            bhalf8 af[4], bfr[4];
            #pragma unroll
            for (int mi = 0; mi < 4; ++mi)
                af[mi] = *(const bhalf8*)((const char*)Asm + (fra + mi * 16) * 128 + (cb ^ swz));
            #pragma unroll
            for (int nj = 0; nj < 4; ++nj)
                bfr[nj] = *(const bhalf8*)((const char*)Bsm + (frb + nj * 16) * 128 + (cb ^ swz));
            #pragma unroll
            for (int mi = 0; mi < 4; ++mi)
                #pragma unroll
                for (int nj = 0; nj < 4; ++nj)
                    acc[mi][nj] = __builtin_amdgcn_mfma_f32_16x16x32_bf16(
                        af[mi], bfr[nj], acc[mi][nj], 0, 0, 0);
        }
    }

    float* Cz = C ? C + (size_t)blockIdx.z * ((size_t)M * N) : nullptr;
    #pragma unroll
    for (int nj = 0; nj < 4; ++nj) {
        const int ccol = rowB + wc * 64 + nj * 16 + (lane & 15);
        const float bv = (flags & 1) ? bias[ccol] : 0.f;
        #pragma unroll
        for (int mi = 0; mi < 4; ++mi) {
            const int crow0 = rowA + wr * 64 + mi * 16 + ((lane >> 4) << 2);
            #pragma unroll
            for (int i = 0; i < 4; ++i) {
                size_t idx = (size_t)(crow0 + i) * N + ccol;
                float v = acc[mi][nj][i] + bv;
                if (flags & 2)  v += Cz[idx];
                if (flags & 16) v += __bfloat162float(Cb[idx]);
                if (flags & 4)  v = fmaxf(v, 0.f);
                if (Cz && !(flags & 8)) Cz[idx] = v;
                if (Cb) Cb[idx] = __float2bfloat16(v);
            }
        }
    }
}

// dst[i] = sum_z parts[z*stride + i] (+ bias[i & colmask])
__global__ void reduce4(const float* __restrict__ parts, size_t stride,
                        const float* __restrict__ bias, int colmask,
                        float* __restrict__ dst, int n)
{
    int i = blockIdx.x * 256 + threadIdx.x;
    if (i >= n) return;
    float v = parts[i] + parts[stride + i] + parts[2 * stride + i] + parts[3 * stride + i];
    if (bias) v += bias[i & colmask];
    dst[i] = v;
}

// ------------------------------------------------------------------
// fp32 tiled GEMM (tiny E2s = ea[0:2112] @ e2w)
// ------------------------------------------------------------------
__global__ __launch_bounds__(256) void gemm_tile(
    const float* __restrict__ A, const float* __restrict__ B,
    const float* __restrict__ bias, float* __restrict__ C,
    int M, int N, int K, int flags)
{
    __shared__ float As[16][68];
    __shared__ float Bs[16][64];
    const int tid = threadIdx.x;
    const int bx = blockIdx.x, by = blockIdx.y;
    const int tx = tid & 15, ty = tid >> 4;
    const int arow = tid >> 2, acol = (tid & 3) << 2;
    const int brow = tid >> 4, bcol = (tid & 15) << 2;
    const float* Ag = A + (size_t)(by * 64 + arow) * K + acol;
    const float* Bg = B + (size_t)brow * N + bx * 64 + bcol;
    float acc[4][4] = {};
    for (int k0 = 0; k0 < K; k0 += 16) {
        const float4 av = *(const float4*)(Ag + k0);
        const float4 bv = *(const float4*)(Bg + (size_t)k0 * N);
        __syncthreads();
        As[acol + 0][arow] = av.x;
        As[acol + 1][arow] = av.y;
        As[acol + 2][arow] = av.z;
        As[acol + 3][arow] = av.w;
        *(float4*)&Bs[brow][bcol] = bv;
        __syncthreads();
        #pragma unroll
        for (int kk = 0; kk < 16; ++kk) {
            const float4 a4 = *(const float4*)&As[kk][ty << 2];
            const float4 b4 = *(const float4*)&Bs[kk][tx << 2];
            const float a[4] = {a4.x, a4.y, a4.z, a4.w};
            const float b[4] = {b4.x, b4.y, b4.z, b4.w};
            #pragma unroll
            for (int i = 0; i < 4; ++i)
                #pragma unroll
                for (int j = 0; j < 4; ++j)
                    acc[i][j] += a[i] * b[j];
        }
    }
    const int crow = by * 64 + (ty << 2);
    const int ccol = bx * 64 + (tx << 2);
    float4 b4 = make_float4(0.f, 0.f, 0.f, 0.f);
    if (flags & 1) b4 = *(const float4*)(bias + ccol);
    #pragma unroll
    for (int i = 0; i < 4; ++i) {
        float* cp = C + (size_t)(crow + i) * N + ccol;
        float4 v;
        v.x = acc[i][0] + b4.x; v.y = acc[i][1] + b4.y;
        v.z = acc[i][2] + b4.z; v.w = acc[i][3] + b4.w;
        if (flags & 2) {
            const float4 o = *(const float4*)cp;
            v.x += o.x; v.y += o.y; v.z += o.z; v.w += o.w;
        }
        *(float4*)cp = v;
    }
}

// ------------------------------------------------------------------
// CSR build
// ------------------------------------------------------------------
__global__ void count_deg(const int* __restrict__ ei, int* __restrict__ deg)
{
    int e = blockIdx.x * 256 + threadIdx.x;
    if (e < NE) atomicAdd(&deg[ei[NE + e]], 1);
}

__global__ __launch_bounds__(1024) void scan_kernel(const int* __restrict__ deg,
                                                    int* __restrict__ rowptr)
{
    __shared__ int s[1024];
    const int t = threadIdx.x;
    const int base = t * 7;
    int loc[7];
    int sum = 0;
    #pragma unroll
    for (int i = 0; i < 7; ++i) {
        int idx = base + i;
        int v = (idx < NN) ? deg[idx] : 0;
        loc[i] = v; sum += v;
    }
    s[t] = sum;
    __syncthreads();
    for (int off = 1; off < 1024; off <<= 1) {
        int v = (t >= off) ? s[t - off] : 0;
        __syncthreads();
        s[t] += v;
        __syncthreads();
    }
    int running = s[t] - sum;
    #pragma unroll
    for (int i = 0; i < 7; ++i) {
        int idx = base + i;
        if (idx <= NN) rowptr[idx] = running;
        if (idx < NN) running += loc[i];
    }
}

__global__ void fill_csr(const int* __restrict__ ei, const int* __restrict__ rowptr,
                         int* __restrict__ fillctr, int* __restrict__ elist)
{
    int e = blockIdx.x * 256 + threadIdx.x;
    if (e >= NE) return;
    int d = ei[NE + e];
    int pos = atomicAdd(&fillctr[d], 1);
    elist[rowptr[d] + pos] = e;
}

__global__ void sort_csr(const int* __restrict__ rowptr, int* __restrict__ elist)
{
    int n = blockIdx.x * 256 + threadIdx.x;
    if (n >= NN) return;
    int s0 = rowptr[n], s1 = rowptr[n + 1];
    for (int i = s0 + 1; i < s1; ++i) {
        int v = elist[i];
        int j = i - 1;
        while (j >= s0 && elist[j] > v) { elist[j + 1] = elist[j]; --j; }
        elist[j + 1] = v;
    }
}

// ------------------------------------------------------------------
// conversions / weight prep
// ------------------------------------------------------------------
__global__ void cvt_pad_bf16(const float* __restrict__ src, __hip_bfloat16* __restrict__ dst,
                             int relu)
{
    size_t i = (size_t)(blockIdx.x * 256 + threadIdx.x) * 4;
    int row = (int)(i >> 11);
    float4 v = make_float4(0.f, 0.f, 0.f, 0.f);
    if (row < NN) v = *(const float4*)&src[i];
    if (relu) {
        v.x = fmaxf(v.x, 0.f); v.y = fmaxf(v.y, 0.f);
        v.z = fmaxf(v.z, 0.f); v.w = fmaxf(v.w, 0.f);
    }
    dst[i + 0] = __float2bfloat16(v.x);
    dst[i + 1] = __float2bfloat16(v.y);
    dst[i + 2] = __float2bfloat16(v.z);
    dst[i + 3] = __float2bfloat16(v.w);
}

// 4 transposes in one dispatch: Bt[z][n][k] = bf16(Wz[k][n])
__global__ __launch_bounds__(256) void transpose_cvt4(
    const float* __restrict__ W0, const float* __restrict__ W1,
    const float* __restrict__ W2, const float* __restrict__ W3,
    __hip_bfloat16* __restrict__ dst)
{
    const float* W = (blockIdx.z == 0) ? W0 : (blockIdx.z == 1) ? W1
                   : (blockIdx.z == 2) ? W2 : W3;
    __hip_bfloat16* Bt = dst + (size_t)blockIdx.z * KDIM * KDIM;
    __shared__ float t[32][33];
    int kb = blockIdx.y * 32, nb = blockIdx.x * 32;
    int tx = threadIdx.x & 31, ty = threadIdx.x >> 5;
    #pragma unroll
    for (int i = 0; i < 32; i += 8)
        t[ty + i][tx] = W[(size_t)(kb + ty + i) * KDIM + nb + tx];
    __syncthreads();
    #pragma unroll
    for (int i = 0; i < 32; i += 8)
        Bt[(size_t)(nb + ty + i) * KDIM + kb + tx] = __float2bfloat16(t[tx][ty + i]);
}

// merged small weight-prep: bcat | w1pp | w1ppT | w2t+b2
__global__ void build_misc(
    const float* __restrict__ q1b, const float* __restrict__ k1b,
    const float* __restrict__ v1b, const float* __restrict__ s1b,
    const float* __restrict__ e1w,
    const float* __restrict__ q2w, const float* __restrict__ k2w,
    const float* __restrict__ v2w, const float* __restrict__ s2w,
    const float* __restrict__ q2bb, const float* __restrict__ k2bb,
    const float* __restrict__ v2bb, const float* __restrict__ s2bb,
    float* __restrict__ bcat, __hip_bfloat16* __restrict__ w1pp,
    __hip_bfloat16* __restrict__ w1ppT, __hip_bfloat16* __restrict__ w2t,
    float* __restrict__ b2)
{
    int idx = blockIdx.x * 256 + threadIdx.x;
    if (idx < 8192) {
        int seg = idx >> 11, j = idx & 2047;
        const float* b = (seg == 0) ? q1b : (seg == 1) ? k1b : (seg == 2) ? v1b : s1b;
        bcat[idx] = b[j];
        return;
    }
    idx -= 8192;
    if (idx < 262144) {   // w1pp [128][2048]
        int p = idx >> 11, j = idx & 2047;
        float v = ((j >> 10) == (p >> 6)) ? e1w[(size_t)(p & 63) * KDIM + j] : 0.f;
        w1pp[idx] = __float2bfloat16(v);
        return;
    }
    idx -= 262144;
    if (idx < 262144) {   // w1ppT [2048][128]
        int n = idx >> 7, k = idx & 127;
        float v = ((n >> 10) == (k >> 6)) ? e1w[(size_t)(k & 63) * KDIM + n] : 0.f;
        w1ppT[idx] = __float2bfloat16(v);
        return;
    }
    idx -= 262144;        // w2t [256][2048] + b2
    int c = idx >> 11, d = idx & 2047;
    int g = c >> 6, j = c & 63;
    const float* w = (g == 0) ? q2w : (g == 1) ? k2w : (g == 2) ? v2w : s2w;
    w2t[idx] = __float2bfloat16(w[(size_t)d * 64 + j]);
    if (d == 0) {
        const float* b = (g == 0) ? q2bb : (g == 1) ? k2bb : (g == 2) ? v2bb : s2bb;
        b2[c] = b[j];
    }
}

// ------------------------------------------------------------------
// node1: fused alpha1 + softmax + R1 + V-aggregation. One block/node.
// h1 is bf16 (read-modify-write; fp32 accumulate in registers).
// ------------------------------------------------------------------
__global__ __launch_bounds__(256) void node1_kernel(
    const __hip_bfloat16* __restrict__ q1b, const __hip_bfloat16* __restrict__ k1b,
    const __hip_bfloat16* __restrict__ v1b,
    const float* __restrict__ P1, const float* __restrict__ ea,
    const int* __restrict__ ei, const int* __restrict__ rowptr,
    const int* __restrict__ elist,
    __hip_bfloat16* __restrict__ h1, __hip_bfloat16* __restrict__ R1)
{
    __shared__ int   s_src[256];
    __shared__ int   s_em[256];
    __shared__ float s_at[256][2];
    const int n = blockIdx.x;
    const int s0 = rowptr[n];
    const int deg = rowptr[n + 1] - s0;
    const int w = threadIdx.x >> 6, lane = threadIdx.x & 63;

    for (int j = w; j < deg; j += 4) {
        const int e = elist[s0 + j];
        const int src = ei[e];
        const int em = e % EAP;
        if (lane == 0) { s_src[j] = src; s_em[j] = em; }
        const float eaj = ea[(size_t)em * 64 + lane];
        #pragma unroll
        for (int h = 0; h < 2; ++h) {
            const __hip_bfloat16* qh = q1b + (size_t)n * HC1 + h * 1024 + lane * 16;
            const __hip_bfloat16* kh = k1b + (size_t)src * HC1 + h * 1024 + lane * 16;
            bhalf8 qa = *(const bhalf8*)qh, qc = *(const bhalf8*)(qh + 8);
            bhalf8 ka = *(const bhalf8*)kh, kc = *(const bhalf8*)(kh + 8);
            float s = 0.f;
            #pragma unroll
            for (int jj = 0; jj < 8; ++jj) s += bf2f(qa[jj]) * bf2f(ka[jj]);
            #pragma unroll
            for (int jj = 0; jj < 8; ++jj) s += bf2f(qc[jj]) * bf2f(kc[jj]);
            s += eaj * P1[(size_t)n * 128 + h * 64 + lane];
            #pragma unroll
            for (int off = 32; off; off >>= 1) s += __shfl_xor(s, off);
            if (lane == 0) s_at[j][h] = s * 0.03125f;
        }
    }
    __syncthreads();

    if (threadIdx.x < 2) {
        const int h = threadIdx.x;
        float m = -1e30f;
        for (int j = 0; j < deg; ++j) m = fmaxf(m, s_at[j][h]);
        float sum = 0.f;
        for (int j = 0; j < deg; ++j) {
            float ex = __expf(s_at[j][h] - m);
            s_at[j][h] = ex; sum += ex;
        }
        float inv = 1.f / (sum + 1e-16f);
        for (int j = 0; j < deg; ++j) s_at[j][h] *= inv;
    }
    __syncthreads();

    if (threadIdx.x < 128) {
        const int h = threadIdx.x >> 6, jj = threadIdx.x & 63;
        float r = 0.f;
        for (int j = 0; j < deg; ++j)
            r += s_at[j][h] * ea[(size_t)s_em[j] * 64 + jj];
        R1[(size_t)n * 128 + threadIdx.x] = __float2bfloat16(r);
    }

    const int c0 = threadIdx.x * 8;
    const int h = c0 >> 10;
    float acc[8];
    const bhalf8 cur = *(const bhalf8*)&h1[(size_t)n * HC1 + c0];
    #pragma unroll
    for (int jj = 0; jj < 8; ++jj) acc[jj] = bf2f(cur[jj]);
    for (int j = 0; j < deg; ++j) {
        const float at = s_at[j][h];
        bhalf8 v = *(const bhalf8*)&v1b[(size_t)s_src[j] * HC1 + c0];
        #pragma unroll
        for (int jj = 0; jj < 8; ++jj) acc[jj] += at * bf2f(v[jj]);
    }
    bhalf8 o;
    #pragma unroll
    for (int jj = 0; jj < 8; ++jj)
        o[jj] = (short)__bfloat16_as_ushort(__float2bfloat16(acc[jj]));
    *(bhalf8*)&h1[(size_t)n * HC1 + c0] = o;
}

// ------------------------------------------------------------------
// node2: fused alpha2 + softmax + aggregation + relu. 1 wave/node.
// ------------------------------------------------------------------
__global__ __launch_bounds__(64) void node2_kernel(
    const float* __restrict__ qkvs2, const float* __restrict__ E2s,
    const int* __restrict__ ei, const int* __restrict__ rowptr,
    const int* __restrict__ elist, float* __restrict__ out)
{
    __shared__ float s_at[256];
    __shared__ int   s_src[256];
    __shared__ int   s_em[256];
    const int n = blockIdx.x;
    const int s0 = rowptr[n];
    const int deg = rowptr[n + 1] - s0;
    const int c = threadIdx.x;
    const float q = qkvs2[(size_t)n * 256 + c];

    for (int j = 0; j < deg; ++j) {
        const int e = elist[s0 + j];
        const int src = ei[e];
        const int em = e % EAP;
        float s = q * (qkvs2[(size_t)src * 256 + 64 + c] + E2s[(size_t)em * 64 + c]);
        #pragma unroll
        for (int off = 32; off; off >>= 1) s += __shfl_xor(s, off);
        if (c == 0) { s_at[j] = s * 0.125f; s_src[j] = src; s_em[j] = em; }
    }
    __syncthreads();
    float m = -1e30f;
    for (int j = 0; j < deg; ++j) m = fmaxf(m, s_at[j]);
    float sum = 0.f;
    for (int j = 0; j < deg; ++j) sum += __expf(s_at[j] - m);
    const float inv = 1.f / (sum + 1e-16f);

    float acc = qkvs2[(size_t)n * 256 + 192 + c];
    for (int j = 0; j < deg; ++j) {
        const float at = __expf(s_at[j] - m) * inv;
        acc += at * (qkvs2[(size_t)s_src[j] * 256 + 128 + c] + E2s[(size_t)s_em[j] * 64 + c]);
    }
    out[(size_t)n * 64 + c] = fmaxf(acc, 0.f);
}

// ------------------------------------------------------------------
extern "C" void kernel_launch(void* const* d_in, const int* in_sizes, int n_in,
                              void* d_out, int out_size, void* d_ws, size_t ws_size,
                              hipStream_t stream)
{
    const float* x   = (const float*)d_in[0];
    const int*   ei  = (const int*)d_in[1];
    const float* ea  = (const float*)d_in[2];
    const float* q1w = (const float*)d_in[3];
    const float* q1b = (const float*)d_in[4];
    const float* k1w = (const float*)d_in[5];
    const float* k1b = (const float*)d_in[6];
    const float* v1w = (const float*)d_in[7];
    const float* v1b = (const float*)d_in[8];
    const float* e1w = (const float*)d_in[9];
    const float* s1w = (const float*)d_in[10];
    const float* s1b = (const float*)d_in[11];
    const float* q2w = (const float*)d_in[12];
    const float* q2b = (const float*)d_in[13];
    const float* k2w = (const float*)d_in[14];
    const float* k2b = (const float*)d_in[15];
    const float* v2w = (const float*)d_in[16];
    const float* v2b = (const float*)d_in[17];
    const float* e2w = (const float*)d_in[18];
    const float* s2w = (const float*)d_in[19];
    const float* s2b = (const float*)d_in[20];
    float* out = (float*)d_out;

    char* base = (char*)d_ws;
    size_t off = 0;
    auto alloc = [&](size_t nbytes) {
        size_t o = off; off += (nbytes + 255) & ~(size_t)255; return o;
    };
    const size_t xb_off   = alloc((size_t)MPAD * KDIM * 2);      // bf16 input
    const size_t wcat_off = alloc((size_t)4 * KDIM * KDIM * 2);  // fused weights (reused: Cpart)
    __hip_bfloat16* xb    = (__hip_bfloat16*)(base + xb_off);
    __hip_bfloat16* wcat  = (__hip_bfloat16*)(base + wcat_off);
    float*          Cpart = (float*)(base + wcat_off);            // alias (wcat dead after fused gemm)

    __hip_bfloat16* q1bb  = (__hip_bfloat16*)(base + alloc((size_t)MPAD * HC1 * 2));
    __hip_bfloat16* k1bb  = (__hip_bfloat16*)(base + alloc((size_t)MPAD * HC1 * 2));
    __hip_bfloat16* v1bb  = (__hip_bfloat16*)(base + alloc((size_t)MPAD * HC1 * 2));
    __hip_bfloat16* h1bf  = (__hip_bfloat16*)(base + alloc((size_t)MPAD * HC1 * 2));  // bf16 h1
    float*          bcat  = (float*)(base + alloc((size_t)4 * KDIM * 4));
    float*          P1    = (float*)(base + alloc((size_t)MPAD * 128 * 4));
    __hip_bfloat16* R1b   = (__hip_bfloat16*)(base + alloc((size_t)MPAD * 128 * 2));
    __hip_bfloat16* w1pp  = (__hip_bfloat16*)(base + alloc((size_t)128 * KDIM * 2));
    __hip_bfloat16* w1ppT = (__hip_bfloat16*)(base + alloc((size_t)KDIM * 128 * 2));
    __hip_bfloat16* w2t   = (__hip_bfloat16*)(base + alloc((size_t)256 * KDIM * 2));
    float*          b2    = (float*)(base + alloc(256 * 4));
    float*          qkvs2 = (float*)(base + alloc((size_t)MPAD * 256 * 4));
    float*          E2s   = (float*)(base + alloc((size_t)2112 * 64 * 4));
    int* deg    = (int*)(base + alloc((size_t)NN * 4));
    int* fill   = (int*)(base + alloc((size_t)NN * 4));
    int* rowptr = (int*)(base + alloc((size_t)(NN + 1) * 4));
    int* elist  = (int*)(base + alloc((size_t)NE * 4));

    // --- CSR build ---
    hipMemsetAsync(deg, 0, sizeof(int) * 2 * NN, stream);
    count_deg<<<(NE + 255) / 256, 256, 0, stream>>>(ei, deg);
    scan_kernel<<<1, 1024, 0, stream>>>(deg, rowptr);
    fill_csr<<<(NE + 255) / 256, 256, 0, stream>>>(ei, rowptr, fill, elist);
    sort_csr<<<(NN + 255) / 256, 256, 0, stream>>>(rowptr, elist);

    // --- input conversion + weight prep ---
    const int cvblk = (MPAD * KDIM / 4) / 256;
    cvt_pad_bf16<<<cvblk, 256, 0, stream>>>(x, xb, 0);
    transpose_cvt4<<<dim3(KDIM / 32, KDIM / 32, 4), 256, 0, stream>>>(q1w, k1w, v1w, s1w, wcat);
    build_misc<<<4128, 256, 0, stream>>>(q1b, k1b, v1b, s1b, e1w,
                                         q2w, k2w, v2w, s2w, q2b, k2b, v2b, s2b,
                                         bcat, w1pp, w1ppT, w2t, b2);
    gemm_tile<<<dim3(1, 33), 256, 0, stream>>>(ea, e2w, nullptr, E2s, 2112, 64, 64, 0);

    // --- fused layer-1 projections (q,k,v,skip all bf16) ---
    gemm256x128_fused<<<1728, 256, 0, stream>>>(xb, wcat, bcat, q1bb, k1bb, v1bb, h1bf);

    // --- P1 = q1 @ W1p (split-K 4) ---
    gemm_bf16<<<dim3(1, MPAD / 128, 4), 256, 0, stream>>>(q1bb, w1pp, nullptr, Cpart, nullptr,
                                                          MPAD, 128, KDIM, 0);
    reduce4<<<(MPAD * 128) / 256, 256, 0, stream>>>(Cpart, (size_t)MPAD * 128, nullptr, 0,
                                                    P1, MPAD * 128);

    // --- fused layer-1 attention (bf16 h1 rmw) ---
    node1_kernel<<<NN, 256, 0, stream>>>(q1bb, k1bb, v1bb, P1, ea, ei, rowptr, elist, h1bf, R1b);
    // h1 = relu(h1 + R1 @ W1pp)  -- bf16 in-place accumulate
    gemm_bf16<<<dim3(HC1 / 128, MPAD / 128), 256, 0, stream>>>(R1b, w1ppT, nullptr, nullptr,
                                                               h1bf, MPAD, HC1, 128, 16 | 4);

    // --- layer 2 projections (split-K 4) ---
    gemm_bf16<<<dim3(2, MPAD / 128, 4), 256, 0, stream>>>(h1bf, w2t, nullptr, Cpart, nullptr,
                                                          MPAD, 256, KDIM, 0);
    reduce4<<<(MPAD * 256) / 256, 256, 0, stream>>>(Cpart, (size_t)MPAD * 256, b2, 255,
                                                    qkvs2, MPAD * 256);

    // --- fused layer-2 attention ---
    node2_kernel<<<NN, 64, 0, stream>>>(qkvs2, E2s, ei, rowptr, elist, out);

    (void)in_sizes; (void)n_in; (void)out_size; (void)ws_size;
}